// Round 5
// baseline (1239.691 us; speedup 1.0000x reference)
//
#include <hip/hip_runtime.h>

#define NN 50000
#define NE 800000
#define DD 128

typedef unsigned int u32;
typedef unsigned short u16;
typedef unsigned long long u64;

__device__ __forceinline__ float bf2f(u16 u) {
    union { float f; u32 i; } v; v.i = ((u32)u) << 16; return v.f;
}

// ---------------- K0: dtype detect ----------------
// flags[0]=1 if float data is bf16 (else f32); flags[1]=1 if edge_index int64.
__global__ __launch_bounds__(64) void gin_detect(const u32* __restrict__ xw,
                                                 const u32* __restrict__ ew,
                                                 int* __restrict__ flags) {
    int lane = threadIdx.x;
    u32 w = xw[lane];
    u32 e8 = (w >> 7) & 0xFFu;
    bool bfOK = (e8 >= 100u && e8 <= 150u) || ((w & 0xFFFFu) == 0u);
    u64 m1 = __ballot(bfOK);
    bool oddZero = (ew[2 * lane + 1] == 0u);
    u64 m2 = __ballot(oddZero);
    if (lane == 0) {
        flags[0] = (__popcll(m1) >= 56) ? 1 : 0;
        flags[1] = (__popcll(m2) >= 60) ? 1 : 0;
    }
}

// ---------------- CSR build ----------------
__global__ __launch_bounds__(256) void gin_zero(u32* __restrict__ deg) {
    int i = blockIdx.x * 256 + threadIdx.x;
    if (i < NN) deg[i] = 0u;
}

__global__ __launch_bounds__(256) void gin_hist(const int* __restrict__ ei,
                                                u32* __restrict__ deg,
                                                const int* __restrict__ flags) {
    int e = blockIdx.x * 256 + threadIdx.x;
    if (e >= NE) return;
    int d = flags[1] ? ei[2 * (NE + e)] : ei[NE + e];
    atomicAdd(&deg[d], 1u);
}

// ---- hierarchical exclusive scan of deg[NN] -> row_start / cursor ----
#define SCAN_CHUNK 2048
#define NSB ((NN + SCAN_CHUNK - 1) / SCAN_CHUNK)   // 25 blocks

__global__ __launch_bounds__(1024) void gin_scan1(const u32* __restrict__ deg,
                                                  u32* __restrict__ partials) {
    __shared__ u32 red[1024];
    int tid = threadIdx.x;
    int base = blockIdx.x * SCAN_CHUNK + tid * 2;
    u32 a = (base < NN) ? deg[base] : 0u;
    u32 b = (base + 1 < NN) ? deg[base + 1] : 0u;
    red[tid] = a + b;
    __syncthreads();
    for (int off = 512; off > 0; off >>= 1) {
        if (tid < off) red[tid] += red[tid + off];
        __syncthreads();
    }
    if (tid == 0) partials[blockIdx.x] = red[0];
}

__global__ __launch_bounds__(64) void gin_scan2(u32* __restrict__ partials) {
    int lane = threadIdx.x;
    u32 orig = (lane < NSB) ? partials[lane] : 0u;
    u32 v = orig;
    for (int off = 1; off < 64; off <<= 1) {
        u32 t = __shfl_up(v, off);
        if (lane >= off) v += t;
    }
    if (lane < NSB) partials[lane] = v - orig;  // exclusive
}

__global__ __launch_bounds__(1024) void gin_scan3(const u32* __restrict__ deg,
                                                  const u32* __restrict__ partials,
                                                  u32* __restrict__ row_start,
                                                  u32* __restrict__ cursor) {
    __shared__ u32 sc[1024];
    int tid = threadIdx.x;
    int base = blockIdx.x * SCAN_CHUNK + tid * 2;
    u32 a = (base < NN) ? deg[base] : 0u;
    u32 b = (base + 1 < NN) ? deg[base + 1] : 0u;
    u32 ts = a + b;
    sc[tid] = ts;
    __syncthreads();
    for (int off = 1; off < 1024; off <<= 1) {
        u32 v = (tid >= off) ? sc[tid - off] : 0u;
        __syncthreads();
        sc[tid] += v;
        __syncthreads();
    }
    u32 excl = sc[tid] - ts + partials[blockIdx.x];
    if (base < NN) { row_start[base] = excl; cursor[base] = excl; }
    if (base + 1 < NN) { row_start[base + 1] = excl + a; cursor[base + 1] = excl + a; }
}

__global__ __launch_bounds__(256) void gin_fill(const int* __restrict__ ei,
                                                u32* __restrict__ cursor,
                                                u32* __restrict__ bs,
                                                const int* __restrict__ flags) {
    int e = blockIdx.x * 256 + threadIdx.x;
    if (e >= NE) return;
    int s, d;
    if (flags[1]) { s = ei[2 * e]; d = ei[2 * (NE + e)]; }
    else          { s = ei[e];     d = ei[NE + e]; }
    u32 pos = atomicAdd(&cursor[d], 1u);
    bs[pos] = (u32)s;
}

// ---------------- gather-sum (+init) : z = (1+eta)x + sum_{src->n} x[src] ----
__global__ __launch_bounds__(256) void gin_gather(const void* __restrict__ xv,
                                                  const u32* __restrict__ bs,
                                                  const u32* __restrict__ row_start,
                                                  const u32* __restrict__ row_end,
                                                  const void* __restrict__ etav,
                                                  float* __restrict__ z,
                                                  const int* __restrict__ flags) {
    int node = blockIdx.x * 4 + (threadIdx.x >> 6);
    if (node >= NN) return;
    const int lane = threadIdx.x & 63;
    const int fbf = flags[0];
    float s = 1.0f + (fbf ? bf2f(((const u16*)etav)[0]) : ((const float*)etav)[0]);
    float ax, ay;
    if (fbf) {
        u32 p = ((const u32*)((const u16*)xv + (size_t)node * DD))[lane];
        ax = bf2f((u16)(p & 0xffffu)) * s;
        ay = bf2f((u16)(p >> 16)) * s;
    } else {
        float2 p = ((const float2*)((const float*)xv + (size_t)node * DD))[lane];
        ax = p.x * s; ay = p.y * s;
    }
    u32 jb = row_start[node], je = row_end[node];
    if (fbf) {
        for (u32 j = jb; j < je; ++j) {
            u32 src = bs[j];
            u32 p = ((const u32*)((const u16*)xv + (size_t)src * DD))[lane];
            ax += bf2f((u16)(p & 0xffffu));
            ay += bf2f((u16)(p >> 16));
        }
    } else {
        for (u32 j = jb; j < je; ++j) {
            u32 src = bs[j];
            float2 p = ((const float2*)((const float*)xv + (size_t)src * DD))[lane];
            ax += p.x; ay += p.y;
        }
    }
    float2 o; o.x = ax; o.y = ay;
    ((float2*)(z + (size_t)node * DD))[lane] = o;
}

// ---------------- fallback: init + atomic scatter (if ws too small) ---------
__global__ __launch_bounds__(256) void gin_init(const void* __restrict__ xv,
                                                const void* __restrict__ etav,
                                                float* __restrict__ z,
                                                const int* __restrict__ flags) {
    int i = blockIdx.x * 256 + threadIdx.x;
    const int n8 = NN * DD / 8;
    if (i >= n8) return;
    const int fbf = flags[0];
    float s = 1.0f + (fbf ? bf2f(((const u16*)etav)[0]) : ((const float*)etav)[0]);
    float4 a, b;
    if (fbf) {
        uint4 p = ((const uint4*)xv)[i];
        a.x = bf2f((u16)(p.x & 0xffffu)); a.y = bf2f((u16)(p.x >> 16));
        a.z = bf2f((u16)(p.y & 0xffffu)); a.w = bf2f((u16)(p.y >> 16));
        b.x = bf2f((u16)(p.z & 0xffffu)); b.y = bf2f((u16)(p.z >> 16));
        b.z = bf2f((u16)(p.w & 0xffffu)); b.w = bf2f((u16)(p.w >> 16));
    } else {
        a = ((const float4*)xv)[2 * i + 0];
        b = ((const float4*)xv)[2 * i + 1];
    }
    a.x *= s; a.y *= s; a.z *= s; a.w *= s;
    b.x *= s; b.y *= s; b.z *= s; b.w *= s;
    ((float4*)z)[2 * i + 0] = a;
    ((float4*)z)[2 * i + 1] = b;
}

__global__ __launch_bounds__(256) void gin_scatter(const void* __restrict__ xv,
                                                   const int* __restrict__ ei,
                                                   float* __restrict__ z,
                                                   const int* __restrict__ flags) {
    int e = blockIdx.x * 4 + (threadIdx.x >> 6);
    if (e >= NE) return;
    const int fbf = flags[0];
    const int f64 = flags[1];
    int lane = threadIdx.x & 63;
    int s, d;
    if (f64) { s = ei[2 * e]; d = ei[2 * (NE + e)]; }
    else     { s = ei[e];     d = ei[NE + e]; }
    float v0, v1;
    if (fbf) {
        u32 p = ((const u32*)((const u16*)xv + (size_t)s * DD))[lane];
        v0 = bf2f((u16)(p & 0xffffu));
        v1 = bf2f((u16)(p >> 16));
    } else {
        float2 p = ((const float2*)((const float*)xv + (size_t)s * DD))[lane];
        v0 = p.x; v1 = p.y;
    }
    float* dst = z + (size_t)d * DD + 2 * lane;
    atomicAdd(dst + 0, v0);
    atomicAdd(dst + 1, v1);
}

// ---------------- fused MLP + LN + skip (template on dtype) ----------------
#define TRM 64   // rows per tile
#define NTM ((NN + TRM - 1) / TRM)

template <int FBF>
__global__ __launch_bounds__(512, 1) void gin_mlp(
    const float* __restrict__ z, const void* __restrict__ x0,
    const void* __restrict__ W1, const void* __restrict__ b1,
    const void* __restrict__ W2, const void* __restrict__ b2,
    const void* __restrict__ gamma, const void* __restrict__ beta,
    float* __restrict__ out, const int* __restrict__ flags) {
    if (flags[0] != FBF) return;  // wave-uniform early exit (dud variant)

    __shared__ float w1t[DD * DD];   // 64 KB, [k][j]
    __shared__ float w2t[DD * DD];   // 64 KB
    __shared__ float tile[TRM * DD]; // 32 KB

    const int tid = threadIdx.x;

    // ---- stage transposed weights (once per block) ----
    if (FBF) {
        for (int q = 0; q < 4; ++q) {            // 2048 uint4 per matrix
            int idx = tid + q * 512;
            int j = idx >> 4;                    // 16 uint4 per row
            int k = (idx & 15) * 8;
            uint4 a = ((const uint4*)W1)[idx];
            uint4 c = ((const uint4*)W2)[idx];
            u32 aw[4] = {a.x, a.y, a.z, a.w};
            u32 cw[4] = {c.x, c.y, c.z, c.w};
#pragma unroll
            for (int t = 0; t < 4; ++t) {
                w1t[(k + 2 * t + 0) * DD + j] = bf2f((u16)(aw[t] & 0xffffu));
                w1t[(k + 2 * t + 1) * DD + j] = bf2f((u16)(aw[t] >> 16));
                w2t[(k + 2 * t + 0) * DD + j] = bf2f((u16)(cw[t] & 0xffffu));
                w2t[(k + 2 * t + 1) * DD + j] = bf2f((u16)(cw[t] >> 16));
            }
        }
    } else {
        for (int q = 0; q < 8; ++q) {            // 4096 float4 per matrix
            int idx = tid + q * 512;
            int j = idx >> 5;                    // 32 float4 per row
            int k = (idx & 31) * 4;
            float4 a = ((const float4*)W1)[idx];
            float4 c = ((const float4*)W2)[idx];
            w1t[(k + 0) * DD + j] = a.x; w1t[(k + 1) * DD + j] = a.y;
            w1t[(k + 2) * DD + j] = a.z; w1t[(k + 3) * DD + j] = a.w;
            w2t[(k + 0) * DD + j] = c.x; w2t[(k + 1) * DD + j] = c.y;
            w2t[(k + 2) * DD + j] = c.z; w2t[(k + 3) * DD + j] = c.w;
        }
    }

    const int cg = tid & 31;        // col group: j0 = 4*cg
    const int rg = tid >> 5;        // row group: r0 = 4*rg (0..15)
    const int j0 = cg * 4;
    const int r0 = rg * 4;

    float b1v[4], b2v[4], gv[4], bev[4];
    if (FBF) {
        uint2 pb1 = ((const uint2*)b1)[cg];
        uint2 pb2 = ((const uint2*)b2)[cg];
        uint2 pg = ((const uint2*)gamma)[cg];
        uint2 pe = ((const uint2*)beta)[cg];
        b1v[0] = bf2f((u16)(pb1.x & 0xffffu)); b1v[1] = bf2f((u16)(pb1.x >> 16));
        b1v[2] = bf2f((u16)(pb1.y & 0xffffu)); b1v[3] = bf2f((u16)(pb1.y >> 16));
        b2v[0] = bf2f((u16)(pb2.x & 0xffffu)); b2v[1] = bf2f((u16)(pb2.x >> 16));
        b2v[2] = bf2f((u16)(pb2.y & 0xffffu)); b2v[3] = bf2f((u16)(pb2.y >> 16));
        gv[0] = bf2f((u16)(pg.x & 0xffffu)); gv[1] = bf2f((u16)(pg.x >> 16));
        gv[2] = bf2f((u16)(pg.y & 0xffffu)); gv[3] = bf2f((u16)(pg.y >> 16));
        bev[0] = bf2f((u16)(pe.x & 0xffffu)); bev[1] = bf2f((u16)(pe.x >> 16));
        bev[2] = bf2f((u16)(pe.y & 0xffffu)); bev[3] = bf2f((u16)(pe.y >> 16));
    } else {
        float4 t1 = ((const float4*)b1)[cg];
        float4 t2 = ((const float4*)b2)[cg];
        float4 t3 = ((const float4*)gamma)[cg];
        float4 t4 = ((const float4*)beta)[cg];
        b1v[0] = t1.x; b1v[1] = t1.y; b1v[2] = t1.z; b1v[3] = t1.w;
        b2v[0] = t2.x; b2v[1] = t2.y; b2v[2] = t2.z; b2v[3] = t2.w;
        gv[0] = t3.x; gv[1] = t3.y; gv[2] = t3.z; gv[3] = t3.w;
        bev[0] = t4.x; bev[1] = t4.y; bev[2] = t4.z; bev[3] = t4.w;
    }

    for (int t = blockIdx.x; t < NTM; t += gridDim.x) {
        const int row0 = t * TRM;
        __syncthreads();  // previous iteration's readers done
#pragma unroll
        for (int q = 0; q < 4; ++q) {
            int idx = tid + q * 512;
            int lr = idx >> 5;
            int grow = row0 + lr;
            float4 v;
            if (grow < NN)
                v = ((const float4*)z)[(size_t)grow * (DD / 4) + (idx & 31)];
            else
                v = float4{0.f, 0.f, 0.f, 0.f};
            ((float4*)tile)[idx] = v;
        }
        __syncthreads();

        float acc[4][4];
        // ---- layer 1 ----
#pragma unroll
        for (int r = 0; r < 4; ++r) {
            acc[r][0] = b1v[0]; acc[r][1] = b1v[1];
            acc[r][2] = b1v[2]; acc[r][3] = b1v[3];
        }
        for (int k0 = 0; k0 < DD; k0 += 4) {
            float4 zv[4];
#pragma unroll
            for (int r = 0; r < 4; ++r)
                zv[r] = *(const float4*)&tile[(r0 + r) * DD + k0];
#pragma unroll
            for (int kk = 0; kk < 4; ++kk) {
                float4 w4 = *(const float4*)&w1t[(k0 + kk) * DD + j0];
#pragma unroll
                for (int r = 0; r < 4; ++r) {
                    float zz = kk == 0 ? zv[r].x : kk == 1 ? zv[r].y
                              : kk == 2 ? zv[r].z : zv[r].w;
                    acc[r][0] += zz * w4.x;
                    acc[r][1] += zz * w4.y;
                    acc[r][2] += zz * w4.z;
                    acc[r][3] += zz * w4.w;
                }
            }
        }
        __syncthreads();
#pragma unroll
        for (int r = 0; r < 4; ++r) {
            float4 h;
            h.x = fmaxf(acc[r][0], 0.f);
            h.y = fmaxf(acc[r][1], 0.f);
            h.z = fmaxf(acc[r][2], 0.f);
            h.w = fmaxf(acc[r][3], 0.f);
            *(float4*)&tile[(r0 + r) * DD + j0] = h;
        }
        __syncthreads();
        // ---- layer 2 ----
#pragma unroll
        for (int r = 0; r < 4; ++r) {
            acc[r][0] = b2v[0]; acc[r][1] = b2v[1];
            acc[r][2] = b2v[2]; acc[r][3] = b2v[3];
        }
        for (int k0 = 0; k0 < DD; k0 += 4) {
            float4 zv[4];
#pragma unroll
            for (int r = 0; r < 4; ++r)
                zv[r] = *(const float4*)&tile[(r0 + r) * DD + k0];
#pragma unroll
            for (int kk = 0; kk < 4; ++kk) {
                float4 w4 = *(const float4*)&w2t[(k0 + kk) * DD + j0];
#pragma unroll
                for (int r = 0; r < 4; ++r) {
                    float zz = kk == 0 ? zv[r].x : kk == 1 ? zv[r].y
                              : kk == 2 ? zv[r].z : zv[r].w;
                    acc[r][0] += zz * w4.x;
                    acc[r][1] += zz * w4.y;
                    acc[r][2] += zz * w4.z;
                    acc[r][3] += zz * w4.w;
                }
            }
        }
        // ---- relu + LN + skip + store ----
#pragma unroll
        for (int r = 0; r < 4; ++r) {
            float h0 = fmaxf(acc[r][0], 0.f);
            float h1 = fmaxf(acc[r][1], 0.f);
            float h2 = fmaxf(acc[r][2], 0.f);
            float h3 = fmaxf(acc[r][3], 0.f);
            float s1 = h0 + h1 + h2 + h3;
            float s2 = h0 * h0 + h1 * h1 + h2 * h2 + h3 * h3;
#pragma unroll
            for (int m = 1; m <= 16; m <<= 1) {
                s1 += __shfl_xor(s1, m);
                s2 += __shfl_xor(s2, m);
            }
            float mean = s1 * (1.0f / DD);
            float var = s2 * (1.0f / DD) - mean * mean;
            float rs = rsqrtf(var + 1e-5f);
            int grow = row0 + r0 + r;
            if (grow < NN) {
                float xi[4];
                if (FBF) {
                    uint2 px = ((const uint2*)((const u16*)x0 + (size_t)grow * DD))[cg];
                    xi[0] = bf2f((u16)(px.x & 0xffffu)); xi[1] = bf2f((u16)(px.x >> 16));
                    xi[2] = bf2f((u16)(px.y & 0xffffu)); xi[3] = bf2f((u16)(px.y >> 16));
                } else {
                    float4 px = ((const float4*)((const float*)x0 + (size_t)grow * DD))[cg];
                    xi[0] = px.x; xi[1] = px.y; xi[2] = px.z; xi[3] = px.w;
                }
                float4 o;
                o.x = (h0 - mean) * rs * gv[0] + bev[0] + xi[0];
                o.y = (h1 - mean) * rs * gv[1] + bev[1] + xi[1];
                o.z = (h2 - mean) * rs * gv[2] + bev[2] + xi[2];
                o.w = (h3 - mean) * rs * gv[3] + bev[3] + xi[3];
                ((float4*)(out + (size_t)grow * DD))[cg] = o;
            }
        }
    }
}

extern "C" void kernel_launch(void* const* d_in, const int* in_sizes, int n_in,
                              void* d_out, int out_size, void* d_ws, size_t ws_size,
                              hipStream_t stream) {
    const void* x = d_in[0];
    const int* ei = (const int*)d_in[1];
    const void* W1 = d_in[2];
    const void* b1 = d_in[3];
    const void* W2 = d_in[4];
    const void* b2 = d_in[5];
    const void* eta = d_in[6];
    const void* gamma = d_in[7];
    const void* beta = d_in[8];
    float* out = (float*)d_out;

    // workspace layout (256B aligned)
    const size_t FLAGS_OFF = 0;                          // 64B flags + 192B partials
    const size_t PART_OFF = 64;                          // NSB u32 partials
    const size_t Z_OFF = 256;
    const size_t ZB = (size_t)NN * DD * sizeof(float);   // 25,600,000
    const size_t DEG_OFF = Z_OFF + ZB;
    const size_t DEGB = 200192;                          // NN u32, padded
    const size_t RS_OFF = DEG_OFF + DEGB;
    const size_t RSB = 200448;                           // NN+1 u32, padded
    const size_t BS_OFF = RS_OFF + RSB;
    const size_t BSB = (size_t)NE * sizeof(u32);         // 3,200,000
    const size_t TOT = BS_OFF + BSB;                     // ~29.2 MB

    if (ws_size < Z_OFF + ZB) return;
    int* flags = (int*)((char*)d_ws + FLAGS_OFF);
    u32* partials = (u32*)((char*)d_ws + PART_OFF);
    float* z = (float*)((char*)d_ws + Z_OFF);

    gin_detect<<<1, 64, 0, stream>>>((const u32*)x, (const u32*)ei, flags);

    if (ws_size >= TOT) {
        u32* deg = (u32*)((char*)d_ws + DEG_OFF);        // becomes cursor/row_end
        u32* row_start = (u32*)((char*)d_ws + RS_OFF);
        u32* bs = (u32*)((char*)d_ws + BS_OFF);
        gin_zero<<<(NN + 255) / 256, 256, 0, stream>>>(deg);
        gin_hist<<<(NE + 255) / 256, 256, 0, stream>>>(ei, deg, flags);
        gin_scan1<<<NSB, 1024, 0, stream>>>(deg, partials);
        gin_scan2<<<1, 64, 0, stream>>>(partials);
        gin_scan3<<<NSB, 1024, 0, stream>>>(deg, partials, row_start, deg);
        gin_fill<<<(NE + 255) / 256, 256, 0, stream>>>(ei, deg, bs, flags);
        // after fill: deg[n] == row_end[n]
        gin_gather<<<(NN + 3) / 4, 256, 0, stream>>>(x, bs, row_start, deg, eta, z, flags);
    } else {
        gin_init<<<(NN * DD / 8 + 255) / 256, 256, 0, stream>>>(x, eta, z, flags);
        gin_scatter<<<NE / 4, 256, 0, stream>>>(x, ei, z, flags);
    }

    gin_mlp<0><<<256, 512, 0, stream>>>(z, x, W1, b1, W2, b2, gamma, beta, out, flags);
    gin_mlp<1><<<256, 512, 0, stream>>>(z, x, W1, b1, W2, b2, gamma, beta, out, flags);
}

// Round 6
// 296.299 us; speedup vs baseline: 4.1839x; 4.1839x over previous
//
#include <hip/hip_runtime.h>

#define NN 50000
#define NE 800000
#define DD 128

typedef unsigned int u32;
typedef unsigned short u16;
typedef unsigned long long u64;

__device__ __forceinline__ float bf2f(u16 u) {
    union { float f; u32 i; } v; v.i = ((u32)u) << 16; return v.f;
}

// ---------------- K0: dtype detect ----------------
// flags[0]=1 if float data is bf16 (else f32); flags[1]=1 if edge_index int64.
__global__ __launch_bounds__(64) void gin_detect(const u32* __restrict__ xw,
                                                 const u32* __restrict__ ew,
                                                 int* __restrict__ flags) {
    int lane = threadIdx.x;
    u32 w = xw[lane];
    u32 e8 = (w >> 7) & 0xFFu;
    bool bfOK = (e8 >= 100u && e8 <= 150u) || ((w & 0xFFFFu) == 0u);
    u64 m1 = __ballot(bfOK);
    bool oddZero = (ew[2 * lane + 1] == 0u);
    u64 m2 = __ballot(oddZero);
    if (lane == 0) {
        flags[0] = (__popcll(m1) >= 56) ? 1 : 0;
        flags[1] = (__popcll(m2) >= 60) ? 1 : 0;
    }
}

// ---------------- CSR build ----------------
__global__ __launch_bounds__(256) void gin_zero(u32* __restrict__ deg) {
    int i = blockIdx.x * 256 + threadIdx.x;
    if (i < NN) deg[i] = 0u;
}

__global__ __launch_bounds__(256) void gin_hist(const int* __restrict__ ei,
                                                u32* __restrict__ deg,
                                                const int* __restrict__ flags) {
    int e = blockIdx.x * 256 + threadIdx.x;
    if (e >= NE) return;
    int d = flags[1] ? ei[2 * (NE + e)] : ei[NE + e];
    atomicAdd(&deg[d], 1u);
}

// ---- hierarchical exclusive scan of deg[NN] -> row_start / cursor ----
#define SCAN_CHUNK 2048
#define NSB ((NN + SCAN_CHUNK - 1) / SCAN_CHUNK)   // 25 blocks

__global__ __launch_bounds__(1024) void gin_scan1(const u32* __restrict__ deg,
                                                  u32* __restrict__ partials) {
    __shared__ u32 red[1024];
    int tid = threadIdx.x;
    int base = blockIdx.x * SCAN_CHUNK + tid * 2;
    u32 a = (base < NN) ? deg[base] : 0u;
    u32 b = (base + 1 < NN) ? deg[base + 1] : 0u;
    red[tid] = a + b;
    __syncthreads();
    for (int off = 512; off > 0; off >>= 1) {
        if (tid < off) red[tid] += red[tid + off];
        __syncthreads();
    }
    if (tid == 0) partials[blockIdx.x] = red[0];
}

__global__ __launch_bounds__(64) void gin_scan2(u32* __restrict__ partials) {
    int lane = threadIdx.x;
    u32 orig = (lane < NSB) ? partials[lane] : 0u;
    u32 v = orig;
    for (int off = 1; off < 64; off <<= 1) {
        u32 t = __shfl_up(v, off);
        if (lane >= off) v += t;
    }
    if (lane < NSB) partials[lane] = v - orig;  // exclusive
}

__global__ __launch_bounds__(1024) void gin_scan3(const u32* __restrict__ deg,
                                                  const u32* __restrict__ partials,
                                                  u32* __restrict__ row_start,
                                                  u32* __restrict__ cursor) {
    __shared__ u32 sc[1024];
    int tid = threadIdx.x;
    int base = blockIdx.x * SCAN_CHUNK + tid * 2;
    u32 a = (base < NN) ? deg[base] : 0u;
    u32 b = (base + 1 < NN) ? deg[base + 1] : 0u;
    u32 ts = a + b;
    sc[tid] = ts;
    __syncthreads();
    for (int off = 1; off < 1024; off <<= 1) {
        u32 v = (tid >= off) ? sc[tid - off] : 0u;
        __syncthreads();
        sc[tid] += v;
        __syncthreads();
    }
    u32 excl = sc[tid] - ts + partials[blockIdx.x];
    if (base < NN) { row_start[base] = excl; cursor[base] = excl; }
    if (base + 1 < NN) { row_start[base + 1] = excl + a; cursor[base + 1] = excl + a; }
}

__global__ __launch_bounds__(256) void gin_fill(const int* __restrict__ ei,
                                                u32* __restrict__ cursor,
                                                u32* __restrict__ bs,
                                                const int* __restrict__ flags) {
    int e = blockIdx.x * 256 + threadIdx.x;
    if (e >= NE) return;
    int s, d;
    if (flags[1]) { s = ei[2 * e]; d = ei[2 * (NE + e)]; }
    else          { s = ei[e];     d = ei[NE + e]; }
    u32 pos = atomicAdd(&cursor[d], 1u);
    bs[pos] = (u32)s;
}

// ---------------- gather-sum (+init) : z = (1+eta)x + sum_{src->n} x[src] ----
__global__ __launch_bounds__(256) void gin_gather(const void* __restrict__ xv,
                                                  const u32* __restrict__ bs,
                                                  const u32* __restrict__ row_start,
                                                  const u32* __restrict__ row_end,
                                                  const void* __restrict__ etav,
                                                  float* __restrict__ z,
                                                  const int* __restrict__ flags) {
    int node = blockIdx.x * 4 + (threadIdx.x >> 6);
    if (node >= NN) return;
    const int lane = threadIdx.x & 63;
    const int fbf = flags[0];
    float s = 1.0f + (fbf ? bf2f(((const u16*)etav)[0]) : ((const float*)etav)[0]);
    float ax, ay;
    if (fbf) {
        u32 p = ((const u32*)((const u16*)xv + (size_t)node * DD))[lane];
        ax = bf2f((u16)(p & 0xffffu)) * s;
        ay = bf2f((u16)(p >> 16)) * s;
    } else {
        float2 p = ((const float2*)((const float*)xv + (size_t)node * DD))[lane];
        ax = p.x * s; ay = p.y * s;
    }
    u32 jb = row_start[node], je = row_end[node];
    if (fbf) {
        for (u32 j = jb; j < je; ++j) {
            u32 src = bs[j];
            u32 p = ((const u32*)((const u16*)xv + (size_t)src * DD))[lane];
            ax += bf2f((u16)(p & 0xffffu));
            ay += bf2f((u16)(p >> 16));
        }
    } else {
        for (u32 j = jb; j < je; ++j) {
            u32 src = bs[j];
            float2 p = ((const float2*)((const float*)xv + (size_t)src * DD))[lane];
            ax += p.x; ay += p.y;
        }
    }
    float2 o; o.x = ax; o.y = ay;
    ((float2*)(z + (size_t)node * DD))[lane] = o;
}

// ---------------- fallback: init + atomic scatter (if ws too small) ---------
__global__ __launch_bounds__(256) void gin_init(const void* __restrict__ xv,
                                                const void* __restrict__ etav,
                                                float* __restrict__ z,
                                                const int* __restrict__ flags) {
    int i = blockIdx.x * 256 + threadIdx.x;
    const int n8 = NN * DD / 8;
    if (i >= n8) return;
    const int fbf = flags[0];
    float s = 1.0f + (fbf ? bf2f(((const u16*)etav)[0]) : ((const float*)etav)[0]);
    float4 a, b;
    if (fbf) {
        uint4 p = ((const uint4*)xv)[i];
        a.x = bf2f((u16)(p.x & 0xffffu)); a.y = bf2f((u16)(p.x >> 16));
        a.z = bf2f((u16)(p.y & 0xffffu)); a.w = bf2f((u16)(p.y >> 16));
        b.x = bf2f((u16)(p.z & 0xffffu)); b.y = bf2f((u16)(p.z >> 16));
        b.z = bf2f((u16)(p.w & 0xffffu)); b.w = bf2f((u16)(p.w >> 16));
    } else {
        a = ((const float4*)xv)[2 * i + 0];
        b = ((const float4*)xv)[2 * i + 1];
    }
    a.x *= s; a.y *= s; a.z *= s; a.w *= s;
    b.x *= s; b.y *= s; b.z *= s; b.w *= s;
    ((float4*)z)[2 * i + 0] = a;
    ((float4*)z)[2 * i + 1] = b;
}

__global__ __launch_bounds__(256) void gin_scatter(const void* __restrict__ xv,
                                                   const int* __restrict__ ei,
                                                   float* __restrict__ z,
                                                   const int* __restrict__ flags) {
    int e = blockIdx.x * 4 + (threadIdx.x >> 6);
    if (e >= NE) return;
    const int fbf = flags[0];
    const int f64 = flags[1];
    int lane = threadIdx.x & 63;
    int s, d;
    if (f64) { s = ei[2 * e]; d = ei[2 * (NE + e)]; }
    else     { s = ei[e];     d = ei[NE + e]; }
    float v0, v1;
    if (fbf) {
        u32 p = ((const u32*)((const u16*)xv + (size_t)s * DD))[lane];
        v0 = bf2f((u16)(p & 0xffffu));
        v1 = bf2f((u16)(p >> 16));
    } else {
        float2 p = ((const float2*)((const float*)xv + (size_t)s * DD))[lane];
        v0 = p.x; v1 = p.y;
    }
    float* dst = z + (size_t)d * DD + 2 * lane;
    atomicAdd(dst + 0, v0);
    atomicAdd(dst + 1, v1);
}

// ---------------- fused MLP + LN + skip (template on dtype) ----------------
// NOTE: inner loops MUST use scalar tile reads (broadcast across lanes).
// The float4 zv[4] + ternary-select variant spills (round 3: 795MB, round 5:
// 2.3GB scratch traffic, 10x slowdown). Do not reintroduce it.
#define TRM 64   // rows per tile
#define NTM ((NN + TRM - 1) / TRM)

template <int FBF>
__global__ __launch_bounds__(512, 1) void gin_mlp(
    const float* __restrict__ z, const void* __restrict__ x0,
    const void* __restrict__ W1, const void* __restrict__ b1,
    const void* __restrict__ W2, const void* __restrict__ b2,
    const void* __restrict__ gamma, const void* __restrict__ beta,
    float* __restrict__ out, const int* __restrict__ flags) {
    if (flags[0] != FBF) return;  // wave-uniform early exit (dud variant)

    __shared__ float w1t[DD * DD];   // 64 KB, [k][j]
    __shared__ float w2t[DD * DD];   // 64 KB
    __shared__ float tile[TRM * DD]; // 32 KB

    const int tid = threadIdx.x;

    // ---- stage transposed weights (once per block) ----
    if (FBF) {
        for (int q = 0; q < 4; ++q) {            // 2048 uint4 per matrix
            int idx = tid + q * 512;
            int j = idx >> 4;                    // 16 uint4 per row
            int k = (idx & 15) * 8;
            uint4 a = ((const uint4*)W1)[idx];
            uint4 c = ((const uint4*)W2)[idx];
            u32 aw[4] = {a.x, a.y, a.z, a.w};
            u32 cw[4] = {c.x, c.y, c.z, c.w};
#pragma unroll
            for (int t = 0; t < 4; ++t) {
                w1t[(k + 2 * t + 0) * DD + j] = bf2f((u16)(aw[t] & 0xffffu));
                w1t[(k + 2 * t + 1) * DD + j] = bf2f((u16)(aw[t] >> 16));
                w2t[(k + 2 * t + 0) * DD + j] = bf2f((u16)(cw[t] & 0xffffu));
                w2t[(k + 2 * t + 1) * DD + j] = bf2f((u16)(cw[t] >> 16));
            }
        }
    } else {
        for (int q = 0; q < 8; ++q) {            // 4096 float4 per matrix
            int idx = tid + q * 512;
            int j = idx >> 5;                    // 32 float4 per row
            int k = (idx & 31) * 4;
            float4 a = ((const float4*)W1)[idx];
            float4 c = ((const float4*)W2)[idx];
            w1t[(k + 0) * DD + j] = a.x; w1t[(k + 1) * DD + j] = a.y;
            w1t[(k + 2) * DD + j] = a.z; w1t[(k + 3) * DD + j] = a.w;
            w2t[(k + 0) * DD + j] = c.x; w2t[(k + 1) * DD + j] = c.y;
            w2t[(k + 2) * DD + j] = c.z; w2t[(k + 3) * DD + j] = c.w;
        }
    }

    const int cg = tid & 31;        // col group: j0 = 4*cg
    const int rg = tid >> 5;        // row group: r0 = 4*rg (0..15)
    const int j0 = cg * 4;
    const int r0 = rg * 4;

    float b1v[4], b2v[4], gv[4], bev[4];
    if (FBF) {
        uint2 pb1 = ((const uint2*)b1)[cg];
        uint2 pb2 = ((const uint2*)b2)[cg];
        uint2 pg = ((const uint2*)gamma)[cg];
        uint2 pe = ((const uint2*)beta)[cg];
        b1v[0] = bf2f((u16)(pb1.x & 0xffffu)); b1v[1] = bf2f((u16)(pb1.x >> 16));
        b1v[2] = bf2f((u16)(pb1.y & 0xffffu)); b1v[3] = bf2f((u16)(pb1.y >> 16));
        b2v[0] = bf2f((u16)(pb2.x & 0xffffu)); b2v[1] = bf2f((u16)(pb2.x >> 16));
        b2v[2] = bf2f((u16)(pb2.y & 0xffffu)); b2v[3] = bf2f((u16)(pb2.y >> 16));
        gv[0] = bf2f((u16)(pg.x & 0xffffu)); gv[1] = bf2f((u16)(pg.x >> 16));
        gv[2] = bf2f((u16)(pg.y & 0xffffu)); gv[3] = bf2f((u16)(pg.y >> 16));
        bev[0] = bf2f((u16)(pe.x & 0xffffu)); bev[1] = bf2f((u16)(pe.x >> 16));
        bev[2] = bf2f((u16)(pe.y & 0xffffu)); bev[3] = bf2f((u16)(pe.y >> 16));
    } else {
        float4 t1 = ((const float4*)b1)[cg];
        float4 t2 = ((const float4*)b2)[cg];
        float4 t3 = ((const float4*)gamma)[cg];
        float4 t4 = ((const float4*)beta)[cg];
        b1v[0] = t1.x; b1v[1] = t1.y; b1v[2] = t1.z; b1v[3] = t1.w;
        b2v[0] = t2.x; b2v[1] = t2.y; b2v[2] = t2.z; b2v[3] = t2.w;
        gv[0] = t3.x; gv[1] = t3.y; gv[2] = t3.z; gv[3] = t3.w;
        bev[0] = t4.x; bev[1] = t4.y; bev[2] = t4.z; bev[3] = t4.w;
    }

    for (int t = blockIdx.x; t < NTM; t += gridDim.x) {
        const int row0 = t * TRM;
        __syncthreads();  // previous iteration's readers done
#pragma unroll
        for (int q = 0; q < 4; ++q) {
            int idx = tid + q * 512;
            int lr = idx >> 5;
            int grow = row0 + lr;
            float4 v;
            if (grow < NN)
                v = ((const float4*)z)[(size_t)grow * (DD / 4) + (idx & 31)];
            else
                v = float4{0.f, 0.f, 0.f, 0.f};
            ((float4*)tile)[idx] = v;
        }
        __syncthreads();

        float acc[4][4];
        // ---- layer 1 (scalar tile reads: lane-broadcast, no spills) ----
#pragma unroll
        for (int r = 0; r < 4; ++r) {
            acc[r][0] = b1v[0]; acc[r][1] = b1v[1];
            acc[r][2] = b1v[2]; acc[r][3] = b1v[3];
        }
        for (int k0 = 0; k0 < DD; k0 += 4) {
#pragma unroll
            for (int kk = 0; kk < 4; ++kk) {
                float4 w4 = *(const float4*)&w1t[(k0 + kk) * DD + j0];
#pragma unroll
                for (int r = 0; r < 4; ++r) {
                    float zz = tile[(r0 + r) * DD + k0 + kk];
                    acc[r][0] += zz * w4.x;
                    acc[r][1] += zz * w4.y;
                    acc[r][2] += zz * w4.z;
                    acc[r][3] += zz * w4.w;
                }
            }
        }
        __syncthreads();
#pragma unroll
        for (int r = 0; r < 4; ++r) {
            float4 h;
            h.x = fmaxf(acc[r][0], 0.f);
            h.y = fmaxf(acc[r][1], 0.f);
            h.z = fmaxf(acc[r][2], 0.f);
            h.w = fmaxf(acc[r][3], 0.f);
            *(float4*)&tile[(r0 + r) * DD + j0] = h;
        }
        __syncthreads();
        // ---- layer 2 ----
#pragma unroll
        for (int r = 0; r < 4; ++r) {
            acc[r][0] = b2v[0]; acc[r][1] = b2v[1];
            acc[r][2] = b2v[2]; acc[r][3] = b2v[3];
        }
        for (int k0 = 0; k0 < DD; k0 += 4) {
#pragma unroll
            for (int kk = 0; kk < 4; ++kk) {
                float4 w4 = *(const float4*)&w2t[(k0 + kk) * DD + j0];
#pragma unroll
                for (int r = 0; r < 4; ++r) {
                    float zz = tile[(r0 + r) * DD + k0 + kk];
                    acc[r][0] += zz * w4.x;
                    acc[r][1] += zz * w4.y;
                    acc[r][2] += zz * w4.z;
                    acc[r][3] += zz * w4.w;
                }
            }
        }
        // ---- relu + LN + skip + store ----
#pragma unroll
        for (int r = 0; r < 4; ++r) {
            float h0 = fmaxf(acc[r][0], 0.f);
            float h1 = fmaxf(acc[r][1], 0.f);
            float h2 = fmaxf(acc[r][2], 0.f);
            float h3 = fmaxf(acc[r][3], 0.f);
            float s1 = h0 + h1 + h2 + h3;
            float s2 = h0 * h0 + h1 * h1 + h2 * h2 + h3 * h3;
#pragma unroll
            for (int m = 1; m <= 16; m <<= 1) {
                s1 += __shfl_xor(s1, m);
                s2 += __shfl_xor(s2, m);
            }
            float mean = s1 * (1.0f / DD);
            float var = s2 * (1.0f / DD) - mean * mean;
            float rs = rsqrtf(var + 1e-5f);
            int grow = row0 + r0 + r;
            if (grow < NN) {
                float xi[4];
                if (FBF) {
                    uint2 px = ((const uint2*)((const u16*)x0 + (size_t)grow * DD))[cg];
                    xi[0] = bf2f((u16)(px.x & 0xffffu)); xi[1] = bf2f((u16)(px.x >> 16));
                    xi[2] = bf2f((u16)(px.y & 0xffffu)); xi[3] = bf2f((u16)(px.y >> 16));
                } else {
                    float4 px = ((const float4*)((const float*)x0 + (size_t)grow * DD))[cg];
                    xi[0] = px.x; xi[1] = px.y; xi[2] = px.z; xi[3] = px.w;
                }
                float4 o;
                o.x = (h0 - mean) * rs * gv[0] + bev[0] + xi[0];
                o.y = (h1 - mean) * rs * gv[1] + bev[1] + xi[1];
                o.z = (h2 - mean) * rs * gv[2] + bev[2] + xi[2];
                o.w = (h3 - mean) * rs * gv[3] + bev[3] + xi[3];
                ((float4*)(out + (size_t)grow * DD))[cg] = o;
            }
        }
    }
}

extern "C" void kernel_launch(void* const* d_in, const int* in_sizes, int n_in,
                              void* d_out, int out_size, void* d_ws, size_t ws_size,
                              hipStream_t stream) {
    const void* x = d_in[0];
    const int* ei = (const int*)d_in[1];
    const void* W1 = d_in[2];
    const void* b1 = d_in[3];
    const void* W2 = d_in[4];
    const void* b2 = d_in[5];
    const void* eta = d_in[6];
    const void* gamma = d_in[7];
    const void* beta = d_in[8];
    float* out = (float*)d_out;

    // workspace layout (256B aligned)
    const size_t FLAGS_OFF = 0;                          // 64B flags + partials
    const size_t PART_OFF = 64;                          // NSB u32 partials
    const size_t Z_OFF = 256;
    const size_t ZB = (size_t)NN * DD * sizeof(float);   // 25,600,000
    const size_t DEG_OFF = Z_OFF + ZB;
    const size_t DEGB = 200192;                          // NN u32, padded
    const size_t RS_OFF = DEG_OFF + DEGB;
    const size_t RSB = 200448;                           // NN+1 u32, padded
    const size_t BS_OFF = RS_OFF + RSB;
    const size_t BSB = (size_t)NE * sizeof(u32);         // 3,200,000
    const size_t TOT = BS_OFF + BSB;                     // ~29.2 MB

    if (ws_size < Z_OFF + ZB) return;
    int* flags = (int*)((char*)d_ws + FLAGS_OFF);
    u32* partials = (u32*)((char*)d_ws + PART_OFF);
    float* z = (float*)((char*)d_ws + Z_OFF);

    gin_detect<<<1, 64, 0, stream>>>((const u32*)x, (const u32*)ei, flags);

    if (ws_size >= TOT) {
        u32* deg = (u32*)((char*)d_ws + DEG_OFF);        // becomes cursor/row_end
        u32* row_start = (u32*)((char*)d_ws + RS_OFF);
        u32* bs = (u32*)((char*)d_ws + BS_OFF);
        gin_zero<<<(NN + 255) / 256, 256, 0, stream>>>(deg);
        gin_hist<<<(NE + 255) / 256, 256, 0, stream>>>(ei, deg, flags);
        gin_scan1<<<NSB, 1024, 0, stream>>>(deg, partials);
        gin_scan2<<<1, 64, 0, stream>>>(partials);
        gin_scan3<<<NSB, 1024, 0, stream>>>(deg, partials, row_start, deg);
        gin_fill<<<(NE + 255) / 256, 256, 0, stream>>>(ei, deg, bs, flags);
        // after fill: deg[n] == row_end[n]
        gin_gather<<<(NN + 3) / 4, 256, 0, stream>>>(x, bs, row_start, deg, eta, z, flags);
    } else {
        gin_init<<<(NN * DD / 8 + 255) / 256, 256, 0, stream>>>(x, eta, z, flags);
        gin_scatter<<<NE / 4, 256, 0, stream>>>(x, ei, z, flags);
    }

    gin_mlp<0><<<256, 512, 0, stream>>>(z, x, W1, b1, W2, b2, gamma, beta, out, flags);
    gin_mlp<1><<<256, 512, 0, stream>>>(z, x, W1, b1, W2, b2, gamma, beta, out, flags);
}

// Round 7
// 218.067 us; speedup vs baseline: 5.6849x; 1.3588x over previous
//
#include <hip/hip_runtime.h>

#define NN 50000
#define NE 800000
#define DD 128

typedef unsigned int u32;
typedef unsigned short u16;
typedef unsigned long long u64;
typedef __attribute__((ext_vector_type(8))) short bf16x8;
typedef __attribute__((ext_vector_type(4))) float f32x4;

__device__ __forceinline__ float bf2f(u16 u) {
    union { float f; u32 i; } v; v.i = ((u32)u) << 16; return v.f;
}
__device__ __forceinline__ u16 f2bf(float f) {
    u32 x = __float_as_uint(f);
    x += 0x7fffu + ((x >> 16) & 1u);
    return (u16)(x >> 16);
}

// ---------------- K0: dtype detect ----------------
// flags[0]=1 if float data is bf16 (else f32); flags[1]=1 if edge_index int64.
__global__ __launch_bounds__(64) void gin_detect(const u32* __restrict__ xw,
                                                 const u32* __restrict__ ew,
                                                 int* __restrict__ flags) {
    int lane = threadIdx.x;
    u32 w = xw[lane];
    u32 e8 = (w >> 7) & 0xFFu;
    bool bfOK = (e8 >= 100u && e8 <= 150u) || ((w & 0xFFFFu) == 0u);
    u64 m1 = __ballot(bfOK);
    bool oddZero = (ew[2 * lane + 1] == 0u);
    u64 m2 = __ballot(oddZero);
    if (lane == 0) {
        flags[0] = (__popcll(m1) >= 56) ? 1 : 0;
        flags[1] = (__popcll(m2) >= 60) ? 1 : 0;
    }
}

// ---------------- CSR build ----------------
__global__ __launch_bounds__(256) void gin_zero(u32* __restrict__ deg) {
    int i = blockIdx.x * 256 + threadIdx.x;
    if (i < NN) deg[i] = 0u;
}

__global__ __launch_bounds__(256) void gin_hist(const int* __restrict__ ei,
                                                u32* __restrict__ deg,
                                                const int* __restrict__ flags) {
    int e = blockIdx.x * 256 + threadIdx.x;
    if (e >= NE) return;
    int d = flags[1] ? ei[2 * (NE + e)] : ei[NE + e];
    atomicAdd(&deg[d], 1u);
}

#define SCAN_CHUNK 2048
#define NSB ((NN + SCAN_CHUNK - 1) / SCAN_CHUNK)   // 25 blocks

__global__ __launch_bounds__(1024) void gin_scan1(const u32* __restrict__ deg,
                                                  u32* __restrict__ partials) {
    __shared__ u32 red[1024];
    int tid = threadIdx.x;
    int base = blockIdx.x * SCAN_CHUNK + tid * 2;
    u32 a = (base < NN) ? deg[base] : 0u;
    u32 b = (base + 1 < NN) ? deg[base + 1] : 0u;
    red[tid] = a + b;
    __syncthreads();
    for (int off = 512; off > 0; off >>= 1) {
        if (tid < off) red[tid] += red[tid + off];
        __syncthreads();
    }
    if (tid == 0) partials[blockIdx.x] = red[0];
}

__global__ __launch_bounds__(64) void gin_scan2(u32* __restrict__ partials) {
    int lane = threadIdx.x;
    u32 orig = (lane < NSB) ? partials[lane] : 0u;
    u32 v = orig;
    for (int off = 1; off < 64; off <<= 1) {
        u32 t = __shfl_up(v, off);
        if (lane >= off) v += t;
    }
    if (lane < NSB) partials[lane] = v - orig;  // exclusive
}

__global__ __launch_bounds__(1024) void gin_scan3(const u32* __restrict__ deg,
                                                  const u32* __restrict__ partials,
                                                  u32* __restrict__ row_start,
                                                  u32* __restrict__ cursor) {
    __shared__ u32 sc[1024];
    int tid = threadIdx.x;
    int base = blockIdx.x * SCAN_CHUNK + tid * 2;
    u32 a = (base < NN) ? deg[base] : 0u;
    u32 b = (base + 1 < NN) ? deg[base + 1] : 0u;
    u32 ts = a + b;
    sc[tid] = ts;
    __syncthreads();
    for (int off = 1; off < 1024; off <<= 1) {
        u32 v = (tid >= off) ? sc[tid - off] : 0u;
        __syncthreads();
        sc[tid] += v;
        __syncthreads();
    }
    u32 excl = sc[tid] - ts + partials[blockIdx.x];
    if (base < NN) { row_start[base] = excl; cursor[base] = excl; }
    if (base + 1 < NN) { row_start[base + 1] = excl + a; cursor[base + 1] = excl + a; }
}

__global__ __launch_bounds__(256) void gin_fill(const int* __restrict__ ei,
                                                u32* __restrict__ cursor,
                                                u32* __restrict__ bs,
                                                const int* __restrict__ flags) {
    int e = blockIdx.x * 256 + threadIdx.x;
    if (e >= NE) return;
    int s, d;
    if (flags[1]) { s = ei[2 * e]; d = ei[2 * (NE + e)]; }
    else          { s = ei[e];     d = ei[NE + e]; }
    u32 pos = atomicAdd(&cursor[d], 1u);
    bs[pos] = (u32)s;
}

// ---------------- gather-sum (+init) ----------------
__global__ __launch_bounds__(256) void gin_gather(const void* __restrict__ xv,
                                                  const u32* __restrict__ bs,
                                                  const u32* __restrict__ row_start,
                                                  const u32* __restrict__ row_end,
                                                  const void* __restrict__ etav,
                                                  float* __restrict__ z,
                                                  const int* __restrict__ flags) {
    int node = blockIdx.x * 4 + (threadIdx.x >> 6);
    if (node >= NN) return;
    const int lane = threadIdx.x & 63;
    const int fbf = flags[0];
    float s = 1.0f + (fbf ? bf2f(((const u16*)etav)[0]) : ((const float*)etav)[0]);
    float ax, ay;
    if (fbf) {
        u32 p = ((const u32*)((const u16*)xv + (size_t)node * DD))[lane];
        ax = bf2f((u16)(p & 0xffffu)) * s;
        ay = bf2f((u16)(p >> 16)) * s;
    } else {
        float2 p = ((const float2*)((const float*)xv + (size_t)node * DD))[lane];
        ax = p.x * s; ay = p.y * s;
    }
    u32 jb = row_start[node], je = row_end[node];
    if (fbf) {
        for (u32 j = jb; j < je; ++j) {
            u32 src = bs[j];
            u32 p = ((const u32*)((const u16*)xv + (size_t)src * DD))[lane];
            ax += bf2f((u16)(p & 0xffffu));
            ay += bf2f((u16)(p >> 16));
        }
    } else {
        for (u32 j = jb; j < je; ++j) {
            u32 src = bs[j];
            float2 p = ((const float2*)((const float*)xv + (size_t)src * DD))[lane];
            ax += p.x; ay += p.y;
        }
    }
    float2 o; o.x = ax; o.y = ay;
    ((float2*)(z + (size_t)node * DD))[lane] = o;
}

// ---------------- fallback: init + atomic scatter ----------------
__global__ __launch_bounds__(256) void gin_init(const void* __restrict__ xv,
                                                const void* __restrict__ etav,
                                                float* __restrict__ z,
                                                const int* __restrict__ flags) {
    int i = blockIdx.x * 256 + threadIdx.x;
    const int n8 = NN * DD / 8;
    if (i >= n8) return;
    const int fbf = flags[0];
    float s = 1.0f + (fbf ? bf2f(((const u16*)etav)[0]) : ((const float*)etav)[0]);
    float4 a, b;
    if (fbf) {
        uint4 p = ((const uint4*)xv)[i];
        a.x = bf2f((u16)(p.x & 0xffffu)); a.y = bf2f((u16)(p.x >> 16));
        a.z = bf2f((u16)(p.y & 0xffffu)); a.w = bf2f((u16)(p.y >> 16));
        b.x = bf2f((u16)(p.z & 0xffffu)); b.y = bf2f((u16)(p.z >> 16));
        b.z = bf2f((u16)(p.w & 0xffffu)); b.w = bf2f((u16)(p.w >> 16));
    } else {
        a = ((const float4*)xv)[2 * i + 0];
        b = ((const float4*)xv)[2 * i + 1];
    }
    a.x *= s; a.y *= s; a.z *= s; a.w *= s;
    b.x *= s; b.y *= s; b.z *= s; b.w *= s;
    ((float4*)z)[2 * i + 0] = a;
    ((float4*)z)[2 * i + 1] = b;
}

__global__ __launch_bounds__(256) void gin_scatter(const void* __restrict__ xv,
                                                   const int* __restrict__ ei,
                                                   float* __restrict__ z,
                                                   const int* __restrict__ flags) {
    int e = blockIdx.x * 4 + (threadIdx.x >> 6);
    if (e >= NE) return;
    const int fbf = flags[0];
    const int f64 = flags[1];
    int lane = threadIdx.x & 63;
    int s, d;
    if (f64) { s = ei[2 * e]; d = ei[2 * (NE + e)]; }
    else     { s = ei[e];     d = ei[NE + e]; }
    float v0, v1;
    if (fbf) {
        u32 p = ((const u32*)((const u16*)xv + (size_t)s * DD))[lane];
        v0 = bf2f((u16)(p & 0xffffu));
        v1 = bf2f((u16)(p >> 16));
    } else {
        float2 p = ((const float2*)((const float*)xv + (size_t)s * DD))[lane];
        v0 = p.x; v1 = p.y;
    }
    float* dst = z + (size_t)d * DD + 2 * lane;
    atomicAdd(dst + 0, v0);
    atomicAdd(dst + 1, v1);
}

// ---------------- MFMA MLP + LN + skip ----------------
// bf16 MFMA (16x16x32), f32 accumulate. A/B fragments use the SAME
// (hi,reg)->k convention on both operands (any consistent bijection is
// correct); C/D layout is the m89-verified col=lane&15,row=(lane>>4)*4+reg.
// LDS tiles are 256B-row bf16 with 16B-unit XOR swizzle (unit ^= row&7) to
// kill the 16-way bank conflict on fragment reads (write & read both swz).
#define TRM 64
#define NTM ((NN + TRM - 1) / TRM)

template <int FBF>
__global__ __launch_bounds__(512, 1) void gin_mlp(
    const float* __restrict__ z, const void* __restrict__ x0,
    const void* __restrict__ W1, const void* __restrict__ b1,
    const void* __restrict__ W2, const void* __restrict__ b2,
    const void* __restrict__ gamma, const void* __restrict__ beta,
    float* __restrict__ out, const int* __restrict__ flags) {
    if (flags[0] != FBF) return;  // wave-uniform early exit (dud variant)

    __shared__ short s_w1[DD * DD];    // 32 KB bf16, row-major, swizzled
    __shared__ short s_w2[DD * DD];    // 32 KB
    __shared__ short s_zt[TRM * DD];   // 16 KB
    __shared__ short s_h1[TRM * DD];   // 16 KB
    __shared__ float s_h2[TRM * 132];  // 33 KB (stride 132 spreads banks)

    const int tid = threadIdx.x;
    char* w1c = (char*)s_w1;
    char* w2c = (char*)s_w2;
    char* ztc = (char*)s_zt;
    char* h1c = (char*)s_h1;

    // ---- stage weights -> bf16 LDS (once per block) ----
    if (FBF) {
#pragma unroll
        for (int q = 0; q < 4; ++q) {
            int u = tid + q * 512;            // 16B unit: 2048 per matrix
            int row = u >> 4, cu = u & 15;
            uint4 a = ((const uint4*)W1)[u];
            uint4 c = ((const uint4*)W2)[u];
            int off = row * 256 + ((cu ^ (row & 7)) << 4);
            *(uint4*)(w1c + off) = a;
            *(uint4*)(w2c + off) = c;
        }
    } else {
#pragma unroll
        for (int q = 0; q < 4; ++q) {
            int u = tid + q * 512;
            int row = u >> 4, cu = u & 15;
            float4 a0 = ((const float4*)W1)[u * 2 + 0];
            float4 a1 = ((const float4*)W1)[u * 2 + 1];
            float4 c0 = ((const float4*)W2)[u * 2 + 0];
            float4 c1 = ((const float4*)W2)[u * 2 + 1];
            uint4 pa, pc;
            pa.x = (u32)f2bf(a0.x) | ((u32)f2bf(a0.y) << 16);
            pa.y = (u32)f2bf(a0.z) | ((u32)f2bf(a0.w) << 16);
            pa.z = (u32)f2bf(a1.x) | ((u32)f2bf(a1.y) << 16);
            pa.w = (u32)f2bf(a1.z) | ((u32)f2bf(a1.w) << 16);
            pc.x = (u32)f2bf(c0.x) | ((u32)f2bf(c0.y) << 16);
            pc.y = (u32)f2bf(c0.z) | ((u32)f2bf(c0.w) << 16);
            pc.z = (u32)f2bf(c1.x) | ((u32)f2bf(c1.y) << 16);
            pc.w = (u32)f2bf(c1.z) | ((u32)f2bf(c1.w) << 16);
            int off = row * 256 + ((cu ^ (row & 7)) << 4);
            *(uint4*)(w1c + off) = pa;
            *(uint4*)(w2c + off) = pc;
        }
    }

    const int lane = tid & 63;
    const int wid = tid >> 6;          // 0..7
    const int lrow = lane & 15;
    const int hi = lane >> 4;          // 0..3
    const int rstrip = wid & 3;        // row-strip (16 rows)
    const int nb = (wid >> 2) * 64;    // col base (4 tiles of 16)
    const int arow = rstrip * 16 + lrow;

    float b1v[4], b2v[4];
#pragma unroll
    for (int tt = 0; tt < 4; ++tt) {
        int j = nb + tt * 16 + lrow;
        b1v[tt] = FBF ? bf2f(((const u16*)b1)[j]) : ((const float*)b1)[j];
        b2v[tt] = FBF ? bf2f(((const u16*)b2)[j]) : ((const float*)b2)[j];
    }

    // LN phase params
    const int cg = tid & 31;
    const int rg = tid >> 5;
    const int r0 = rg * 4;
    float gv[4], bev[4];
    if (FBF) {
        uint2 pg = ((const uint2*)gamma)[cg];
        uint2 pe = ((const uint2*)beta)[cg];
        gv[0] = bf2f((u16)(pg.x & 0xffffu)); gv[1] = bf2f((u16)(pg.x >> 16));
        gv[2] = bf2f((u16)(pg.y & 0xffffu)); gv[3] = bf2f((u16)(pg.y >> 16));
        bev[0] = bf2f((u16)(pe.x & 0xffffu)); bev[1] = bf2f((u16)(pe.x >> 16));
        bev[2] = bf2f((u16)(pe.y & 0xffffu)); bev[3] = bf2f((u16)(pe.y >> 16));
    } else {
        float4 t3 = ((const float4*)gamma)[cg];
        float4 t4 = ((const float4*)beta)[cg];
        gv[0] = t3.x; gv[1] = t3.y; gv[2] = t3.z; gv[3] = t3.w;
        bev[0] = t4.x; bev[1] = t4.y; bev[2] = t4.z; bev[3] = t4.w;
    }

    for (int t = blockIdx.x; t < NTM; t += gridDim.x) {
        const int row0 = t * TRM;
        __syncthreads();  // prev iteration fully done (incl. weight staging 1st iter)
        // ---- stage z tile: f32 global -> bf16 swizzled LDS ----
#pragma unroll
        for (int q = 0; q < 2; ++q) {
            int u = tid + q * 512;           // 1024 units
            int row = u >> 4, cu = u & 15;
            int grow = row0 + row;
            float4 a0 = {0.f, 0.f, 0.f, 0.f}, a1 = {0.f, 0.f, 0.f, 0.f};
            if (grow < NN) {
                a0 = ((const float4*)z)[(size_t)grow * 32 + cu * 2 + 0];
                a1 = ((const float4*)z)[(size_t)grow * 32 + cu * 2 + 1];
            }
            uint4 p;
            p.x = (u32)f2bf(a0.x) | ((u32)f2bf(a0.y) << 16);
            p.y = (u32)f2bf(a0.z) | ((u32)f2bf(a0.w) << 16);
            p.z = (u32)f2bf(a1.x) | ((u32)f2bf(a1.y) << 16);
            p.w = (u32)f2bf(a1.z) | ((u32)f2bf(a1.w) << 16);
            *(uint4*)(ztc + row * 256 + ((cu ^ (row & 7)) << 4)) = p;
        }
        __syncthreads();

        f32x4 acc[4];
        // ---- layer 1: h1 = relu(z @ W1^T + b1) ----
#pragma unroll
        for (int tt = 0; tt < 4; ++tt)
            acc[tt] = (f32x4){b1v[tt], b1v[tt], b1v[tt], b1v[tt]};
#pragma unroll
        for (int c = 0; c < 4; ++c) {
            bf16x8 af = *(const bf16x8*)(ztc + arow * 256 + (((c * 4 + hi) ^ (arow & 7)) << 4));
#pragma unroll
            for (int tt = 0; tt < 4; ++tt) {
                int brow = nb + tt * 16 + lrow;
                bf16x8 bfv = *(const bf16x8*)(w1c + brow * 256 + (((c * 4 + hi) ^ (brow & 7)) << 4));
                acc[tt] = __builtin_amdgcn_mfma_f32_16x16x32_bf16(af, bfv, acc[tt], 0, 0, 0);
            }
        }
        // epilogue 1: relu -> bf16 -> s_h1 (swizzled scalar writes)
#pragma unroll
        for (int tt = 0; tt < 4; ++tt) {
            int j = nb + tt * 16 + lrow;
            int jb2 = j * 2;
            int unit = jb2 >> 4, within = jb2 & 15;
#pragma unroll
            for (int qq = 0; qq < 4; ++qq) {
                int row = rstrip * 16 + hi * 4 + qq;
                u16 hb = f2bf(fmaxf(acc[tt][qq], 0.f));
                *(u16*)(h1c + row * 256 + ((unit ^ (row & 7)) << 4) + within) = hb;
            }
        }
        __syncthreads();
        // ---- layer 2: h2 = relu(h1 @ W2^T + b2) ----
#pragma unroll
        for (int tt = 0; tt < 4; ++tt)
            acc[tt] = (f32x4){b2v[tt], b2v[tt], b2v[tt], b2v[tt]};
#pragma unroll
        for (int c = 0; c < 4; ++c) {
            bf16x8 af = *(const bf16x8*)(h1c + arow * 256 + (((c * 4 + hi) ^ (arow & 7)) << 4));
#pragma unroll
            for (int tt = 0; tt < 4; ++tt) {
                int brow = nb + tt * 16 + lrow;
                bf16x8 bfv = *(const bf16x8*)(w2c + brow * 256 + (((c * 4 + hi) ^ (brow & 7)) << 4));
                acc[tt] = __builtin_amdgcn_mfma_f32_16x16x32_bf16(af, bfv, acc[tt], 0, 0, 0);
            }
        }
        // epilogue 2: relu -> f32 s_h2
#pragma unroll
        for (int tt = 0; tt < 4; ++tt) {
            int j = nb + tt * 16 + lrow;
#pragma unroll
            for (int qq = 0; qq < 4; ++qq) {
                int row = rstrip * 16 + hi * 4 + qq;
                s_h2[row * 132 + j] = fmaxf(acc[tt][qq], 0.f);
            }
        }
        __syncthreads();
        // ---- LN + skip + store ----
#pragma unroll
        for (int r = 0; r < 4; ++r) {
            const float* hp = &s_h2[(r0 + r) * 132 + 4 * cg];
            float h0 = hp[0], h1 = hp[1], h2 = hp[2], h3 = hp[3];
            float s1 = h0 + h1 + h2 + h3;
            float s2 = h0 * h0 + h1 * h1 + h2 * h2 + h3 * h3;
#pragma unroll
            for (int m = 1; m <= 16; m <<= 1) {
                s1 += __shfl_xor(s1, m);
                s2 += __shfl_xor(s2, m);
            }
            float mean = s1 * (1.0f / DD);
            float var = s2 * (1.0f / DD) - mean * mean;
            float rs = rsqrtf(var + 1e-5f);
            int grow = row0 + r0 + r;
            if (grow < NN) {
                float xi[4];
                if (FBF) {
                    uint2 px = ((const uint2*)((const u16*)x0 + (size_t)grow * DD))[cg];
                    xi[0] = bf2f((u16)(px.x & 0xffffu)); xi[1] = bf2f((u16)(px.x >> 16));
                    xi[2] = bf2f((u16)(px.y & 0xffffu)); xi[3] = bf2f((u16)(px.y >> 16));
                } else {
                    float4 px = ((const float4*)((const float*)x0 + (size_t)grow * DD))[cg];
                    xi[0] = px.x; xi[1] = px.y; xi[2] = px.z; xi[3] = px.w;
                }
                float4 o;
                o.x = (h0 - mean) * rs * gv[0] + bev[0] + xi[0];
                o.y = (h1 - mean) * rs * gv[1] + bev[1] + xi[1];
                o.z = (h2 - mean) * rs * gv[2] + bev[2] + xi[2];
                o.w = (h3 - mean) * rs * gv[3] + bev[3] + xi[3];
                ((float4*)(out + (size_t)grow * DD))[cg] = o;
            }
        }
    }
}

extern "C" void kernel_launch(void* const* d_in, const int* in_sizes, int n_in,
                              void* d_out, int out_size, void* d_ws, size_t ws_size,
                              hipStream_t stream) {
    const void* x = d_in[0];
    const int* ei = (const int*)d_in[1];
    const void* W1 = d_in[2];
    const void* b1 = d_in[3];
    const void* W2 = d_in[4];
    const void* b2 = d_in[5];
    const void* eta = d_in[6];
    const void* gamma = d_in[7];
    const void* beta = d_in[8];
    float* out = (float*)d_out;

    // workspace layout (256B aligned)
    const size_t FLAGS_OFF = 0;                          // 64B flags + partials
    const size_t PART_OFF = 64;
    const size_t Z_OFF = 256;
    const size_t ZB = (size_t)NN * DD * sizeof(float);   // 25,600,000
    const size_t DEG_OFF = Z_OFF + ZB;
    const size_t DEGB = 200192;
    const size_t RS_OFF = DEG_OFF + DEGB;
    const size_t RSB = 200448;
    const size_t BS_OFF = RS_OFF + RSB;
    const size_t BSB = (size_t)NE * sizeof(u32);
    const size_t TOT = BS_OFF + BSB;                     // ~29.2 MB

    if (ws_size < Z_OFF + ZB) return;
    int* flags = (int*)((char*)d_ws + FLAGS_OFF);
    u32* partials = (u32*)((char*)d_ws + PART_OFF);
    float* z = (float*)((char*)d_ws + Z_OFF);

    gin_detect<<<1, 64, 0, stream>>>((const u32*)x, (const u32*)ei, flags);

    if (ws_size >= TOT) {
        u32* deg = (u32*)((char*)d_ws + DEG_OFF);        // becomes cursor/row_end
        u32* row_start = (u32*)((char*)d_ws + RS_OFF);
        u32* bs = (u32*)((char*)d_ws + BS_OFF);
        gin_zero<<<(NN + 255) / 256, 256, 0, stream>>>(deg);
        gin_hist<<<(NE + 255) / 256, 256, 0, stream>>>(ei, deg, flags);
        gin_scan1<<<NSB, 1024, 0, stream>>>(deg, partials);
        gin_scan2<<<1, 64, 0, stream>>>(partials);
        gin_scan3<<<NSB, 1024, 0, stream>>>(deg, partials, row_start, deg);
        gin_fill<<<(NE + 255) / 256, 256, 0, stream>>>(ei, deg, bs, flags);
        gin_gather<<<(NN + 3) / 4, 256, 0, stream>>>(x, bs, row_start, deg, eta, z, flags);
    } else {
        gin_init<<<(NN * DD / 8 + 255) / 256, 256, 0, stream>>>(x, eta, z, flags);
        gin_scatter<<<NE / 4, 256, 0, stream>>>(x, ei, z, flags);
    }

    gin_mlp<0><<<256, 512, 0, stream>>>(z, x, W1, b1, W2, b2, gamma, beta, out, flags);
    gin_mlp<1><<<256, 512, 0, stream>>>(z, x, W1, b1, W2, b2, gamma, beta, out, flags);
}

// Round 9
// 186.545 us; speedup vs baseline: 6.6455x; 1.1690x over previous
//
#include <hip/hip_runtime.h>

#define NN 50000
#define NE 800000
#define DD 128

typedef unsigned int u32;
typedef unsigned short u16;
typedef unsigned long long u64;
typedef __attribute__((ext_vector_type(8))) short bf16x8;
typedef __attribute__((ext_vector_type(4))) float f32x4;

__device__ __forceinline__ float bf2f(u16 u) {
    union { float f; u32 i; } v; v.i = ((u32)u) << 16; return v.f;
}
__device__ __forceinline__ u16 f2bf(float f) {
    u32 x = __float_as_uint(f);
    x += 0x7fffu + ((x >> 16) & 1u);
    return (u16)(x >> 16);
}

// ---------------- K0: dtype detect ----------------
// flags[0]=1 if float data is bf16 (else f32); flags[1]=1 if edge_index int64.
__global__ __launch_bounds__(64) void gin_detect(const u32* __restrict__ xw,
                                                 const u32* __restrict__ ew,
                                                 int* __restrict__ flags) {
    int lane = threadIdx.x;
    u32 w = xw[lane];
    u32 e8 = (w >> 7) & 0xFFu;
    bool bfOK = (e8 >= 100u && e8 <= 150u) || ((w & 0xFFFFu) == 0u);
    u64 m1 = __ballot(bfOK);
    bool oddZero = (ew[2 * lane + 1] == 0u);
    u64 m2 = __ballot(oddZero);
    if (lane == 0) {
        flags[0] = (__popcll(m1) >= 56) ? 1 : 0;
        flags[1] = (__popcll(m2) >= 60) ? 1 : 0;
    }
}

// ---------------- x -> bf16 workspace copy ----------------
__global__ __launch_bounds__(256) void gin_tobf(const void* __restrict__ xv,
                                                uint4* __restrict__ xb,
                                                const int* __restrict__ flags) {
    int i = blockIdx.x * 256 + threadIdx.x;     // 16B unit (8 bf16)
    const int nu = NN * DD / 8;                 // 800,000
    if (i >= nu) return;
    if (flags[0]) {
        xb[i] = ((const uint4*)xv)[i];
    } else {
        float4 a0 = ((const float4*)xv)[2 * i + 0];
        float4 a1 = ((const float4*)xv)[2 * i + 1];
        uint4 p;
        p.x = (u32)f2bf(a0.x) | ((u32)f2bf(a0.y) << 16);
        p.y = (u32)f2bf(a0.z) | ((u32)f2bf(a0.w) << 16);
        p.z = (u32)f2bf(a1.x) | ((u32)f2bf(a1.y) << 16);
        p.w = (u32)f2bf(a1.z) | ((u32)f2bf(a1.w) << 16);
        xb[i] = p;
    }
}

// ---------------- CSR build ----------------
__global__ __launch_bounds__(256) void gin_zero(u32* __restrict__ deg) {
    int i = blockIdx.x * 256 + threadIdx.x;
    if (i < NN) deg[i] = 0u;
}

__global__ __launch_bounds__(256) void gin_hist(const int* __restrict__ ei,
                                                u32* __restrict__ deg,
                                                const int* __restrict__ flags) {
    int e = blockIdx.x * 256 + threadIdx.x;
    if (e >= NE) return;
    int d = flags[1] ? ei[2 * (NE + e)] : ei[NE + e];
    atomicAdd(&deg[d], 1u);
}

#define SCAN_CHUNK 2048
#define NSB ((NN + SCAN_CHUNK - 1) / SCAN_CHUNK)   // 25 blocks

__global__ __launch_bounds__(1024) void gin_scan1(const u32* __restrict__ deg,
                                                  u32* __restrict__ partials) {
    __shared__ u32 red[1024];
    int tid = threadIdx.x;
    int base = blockIdx.x * SCAN_CHUNK + tid * 2;
    u32 a = (base < NN) ? deg[base] : 0u;
    u32 b = (base + 1 < NN) ? deg[base + 1] : 0u;
    red[tid] = a + b;
    __syncthreads();
    for (int off = 512; off > 0; off >>= 1) {
        if (tid < off) red[tid] += red[tid + off];
        __syncthreads();
    }
    if (tid == 0) partials[blockIdx.x] = red[0];
}

__global__ __launch_bounds__(64) void gin_scan2(u32* __restrict__ partials) {
    int lane = threadIdx.x;
    u32 orig = (lane < NSB) ? partials[lane] : 0u;
    u32 v = orig;
    for (int off = 1; off < 64; off <<= 1) {
        u32 t = __shfl_up(v, off);
        if (lane >= off) v += t;
    }
    if (lane < NSB) partials[lane] = v - orig;  // exclusive
}

__global__ __launch_bounds__(1024) void gin_scan3(const u32* __restrict__ deg,
                                                  const u32* __restrict__ partials,
                                                  u32* __restrict__ row_start,
                                                  u32* __restrict__ cursor) {
    __shared__ u32 sc[1024];
    int tid = threadIdx.x;
    int base = blockIdx.x * SCAN_CHUNK + tid * 2;
    u32 a = (base < NN) ? deg[base] : 0u;
    u32 b = (base + 1 < NN) ? deg[base + 1] : 0u;
    u32 ts = a + b;
    sc[tid] = ts;
    __syncthreads();
    for (int off = 1; off < 1024; off <<= 1) {
        u32 v = (tid >= off) ? sc[tid - off] : 0u;
        __syncthreads();
        sc[tid] += v;
        __syncthreads();
    }
    u32 excl = sc[tid] - ts + partials[blockIdx.x];
    if (base < NN) { row_start[base] = excl; cursor[base] = excl; }
    if (base + 1 < NN) { row_start[base + 1] = excl + a; cursor[base + 1] = excl + a; }
}

__global__ __launch_bounds__(256) void gin_fill(const int* __restrict__ ei,
                                                u32* __restrict__ cursor,
                                                u32* __restrict__ bs,
                                                const int* __restrict__ flags) {
    int e = blockIdx.x * 256 + threadIdx.x;
    if (e >= NE) return;
    int s, d;
    if (flags[1]) { s = ei[2 * e]; d = ei[2 * (NE + e)]; }
    else          { s = ei[e];     d = ei[NE + e]; }
    u32 pos = atomicAdd(&cursor[d], 1u);
    bs[pos] = (u32)s;
}

// ---------------- gather-sum (+init), bf16 rows ----------------
// Reads 4B/lane/edge from xb (256B per bf16 row), f32 accumulate,
// writes bf16 z. 2-edge unroll for load ILP.
__global__ __launch_bounds__(256) void gin_gather(const u32* __restrict__ xb,
                                                  const u32* __restrict__ bs,
                                                  const u32* __restrict__ row_start,
                                                  const u32* __restrict__ row_end,
                                                  const void* __restrict__ etav,
                                                  u32* __restrict__ zb,
                                                  const int* __restrict__ flags) {
    int node = blockIdx.x * 4 + (threadIdx.x >> 6);
    if (node >= NN) return;
    const int lane = threadIdx.x & 63;
    float s = 1.0f + (flags[0] ? bf2f(((const u16*)etav)[0]) : ((const float*)etav)[0]);
    u32 p = xb[(size_t)node * 64 + lane];
    float ax = bf2f((u16)(p & 0xffffu)) * s;
    float ay = bf2f((u16)(p >> 16)) * s;
    u32 jb = row_start[node], je = row_end[node];
    u32 j = jb;
    for (; j + 1 < je; j += 2) {
        u32 s0 = bs[j], s1 = bs[j + 1];
        u32 p0 = xb[(size_t)s0 * 64 + lane];
        u32 p1 = xb[(size_t)s1 * 64 + lane];
        ax += bf2f((u16)(p0 & 0xffffu)) + bf2f((u16)(p1 & 0xffffu));
        ay += bf2f((u16)(p0 >> 16)) + bf2f((u16)(p1 >> 16));
    }
    if (j < je) {
        u32 p0 = xb[(size_t)bs[j] * 64 + lane];
        ax += bf2f((u16)(p0 & 0xffffu));
        ay += bf2f((u16)(p0 >> 16));
    }
    zb[(size_t)node * 64 + lane] = (u32)f2bf(ax) | ((u32)f2bf(ay) << 16);
}

// ---------------- fallback: init + atomic scatter (f32 z) ----------------
__global__ __launch_bounds__(256) void gin_init(const void* __restrict__ xv,
                                                const void* __restrict__ etav,
                                                float* __restrict__ z,
                                                const int* __restrict__ flags) {
    int i = blockIdx.x * 256 + threadIdx.x;
    const int n8 = NN * DD / 8;
    if (i >= n8) return;
    const int fbf = flags[0];
    float s = 1.0f + (fbf ? bf2f(((const u16*)etav)[0]) : ((const float*)etav)[0]);
    float4 a, b;
    if (fbf) {
        uint4 p = ((const uint4*)xv)[i];
        a.x = bf2f((u16)(p.x & 0xffffu)); a.y = bf2f((u16)(p.x >> 16));
        a.z = bf2f((u16)(p.y & 0xffffu)); a.w = bf2f((u16)(p.y >> 16));
        b.x = bf2f((u16)(p.z & 0xffffu)); b.y = bf2f((u16)(p.z >> 16));
        b.z = bf2f((u16)(p.w & 0xffffu)); b.w = bf2f((u16)(p.w >> 16));
    } else {
        a = ((const float4*)xv)[2 * i + 0];
        b = ((const float4*)xv)[2 * i + 1];
    }
    a.x *= s; a.y *= s; a.z *= s; a.w *= s;
    b.x *= s; b.y *= s; b.z *= s; b.w *= s;
    ((float4*)z)[2 * i + 0] = a;
    ((float4*)z)[2 * i + 1] = b;
}

__global__ __launch_bounds__(256) void gin_scatter(const void* __restrict__ xv,
                                                   const int* __restrict__ ei,
                                                   float* __restrict__ z,
                                                   const int* __restrict__ flags) {
    int e = blockIdx.x * 4 + (threadIdx.x >> 6);
    if (e >= NE) return;
    const int fbf = flags[0];
    const int f64 = flags[1];
    int lane = threadIdx.x & 63;
    int s, d;
    if (f64) { s = ei[2 * e]; d = ei[2 * (NE + e)]; }
    else     { s = ei[e];     d = ei[NE + e]; }
    float v0, v1;
    if (fbf) {
        u32 p = ((const u32*)((const u16*)xv + (size_t)s * DD))[lane];
        v0 = bf2f((u16)(p & 0xffffu));
        v1 = bf2f((u16)(p >> 16));
    } else {
        float2 p = ((const float2*)((const float*)xv + (size_t)s * DD))[lane];
        v0 = p.x; v1 = p.y;
    }
    float* dst = z + (size_t)d * DD + 2 * lane;
    atomicAdd(dst + 0, v0);
    atomicAdd(dst + 1, v1);
}

// ---------------- MFMA MLP + LN + skip ----------------
// bf16 MFMA (16x16x32), f32 accumulate. C/D layout: col=lane&15,
// row=(lane>>4)*4+reg (m89-verified). LDS tiles 256B-row bf16 with 16B-unit
// XOR swizzle (unit ^= row&7), write & read both swizzled.
// ZBF=1: z workspace is bf16 (CSR path). ZBF=0: f32 z (fallback path).
#define TRM 64
#define NTM ((NN + TRM - 1) / TRM)

template <int FBF, int ZBF>
__global__ __launch_bounds__(512, 1) void gin_mlp(
    const void* __restrict__ zv, const void* __restrict__ x0,
    const void* __restrict__ W1, const void* __restrict__ b1,
    const void* __restrict__ W2, const void* __restrict__ b2,
    const void* __restrict__ gamma, const void* __restrict__ beta,
    float* __restrict__ out, const int* __restrict__ flags) {
    if (flags[0] != FBF) return;  // wave-uniform early exit (dud variant)

    __shared__ short s_w1[DD * DD];    // 32 KB bf16, row-major, swizzled
    __shared__ short s_w2[DD * DD];    // 32 KB
    __shared__ short s_zt[TRM * DD];   // 16 KB
    __shared__ short s_h1[TRM * DD];   // 16 KB
    __shared__ float s_h2[TRM * 132];  // 33 KB (stride 132 spreads banks)

    const int tid = threadIdx.x;
    char* w1c = (char*)s_w1;
    char* w2c = (char*)s_w2;
    char* ztc = (char*)s_zt;
    char* h1c = (char*)s_h1;

    // ---- stage weights -> bf16 LDS (once per block) ----
    if (FBF) {
#pragma unroll
        for (int q = 0; q < 4; ++q) {
            int u = tid + q * 512;            // 16B unit: 2048 per matrix
            int row = u >> 4, cu = u & 15;
            uint4 a = ((const uint4*)W1)[u];
            uint4 c = ((const uint4*)W2)[u];
            int off = row * 256 + ((cu ^ (row & 7)) << 4);
            *(uint4*)(w1c + off) = a;
            *(uint4*)(w2c + off) = c;
        }
    } else {
#pragma unroll
        for (int q = 0; q < 4; ++q) {
            int u = tid + q * 512;
            int row = u >> 4, cu = u & 15;
            float4 a0 = ((const float4*)W1)[u * 2 + 0];
            float4 a1 = ((const float4*)W1)[u * 2 + 1];
            float4 c0 = ((const float4*)W2)[u * 2 + 0];
            float4 c1 = ((const float4*)W2)[u * 2 + 1];
            uint4 pa, pc;
            pa.x = (u32)f2bf(a0.x) | ((u32)f2bf(a0.y) << 16);
            pa.y = (u32)f2bf(a0.z) | ((u32)f2bf(a0.w) << 16);
            pa.z = (u32)f2bf(a1.x) | ((u32)f2bf(a1.y) << 16);
            pa.w = (u32)f2bf(a1.z) | ((u32)f2bf(a1.w) << 16);
            pc.x = (u32)f2bf(c0.x) | ((u32)f2bf(c0.y) << 16);
            pc.y = (u32)f2bf(c0.z) | ((u32)f2bf(c0.w) << 16);
            pc.z = (u32)f2bf(c1.x) | ((u32)f2bf(c1.y) << 16);
            pc.w = (u32)f2bf(c1.z) | ((u32)f2bf(c1.w) << 16);
            int off = row * 256 + ((cu ^ (row & 7)) << 4);
            *(uint4*)(w1c + off) = pa;
            *(uint4*)(w2c + off) = pc;
        }
    }

    const int lane = tid & 63;
    const int wid = tid >> 6;          // 0..7
    const int lrow = lane & 15;
    const int hi = lane >> 4;          // 0..3
    const int rstrip = wid & 3;        // row-strip (16 rows)
    const int nb = (wid >> 2) * 64;    // col base (4 tiles of 16)
    const int arow = rstrip * 16 + lrow;

    float b1v[4], b2v[4];
#pragma unroll
    for (int tt = 0; tt < 4; ++tt) {
        int j = nb + tt * 16 + lrow;
        b1v[tt] = FBF ? bf2f(((const u16*)b1)[j]) : ((const float*)b1)[j];
        b2v[tt] = FBF ? bf2f(((const u16*)b2)[j]) : ((const float*)b2)[j];
    }

    // LN phase params
    const int cg = tid & 31;
    const int rg = tid >> 5;
    const int r0 = rg * 4;
    float gv[4], bev[4];
    if (FBF) {
        uint2 pg = ((const uint2*)gamma)[cg];
        uint2 pe = ((const uint2*)beta)[cg];
        gv[0] = bf2f((u16)(pg.x & 0xffffu)); gv[1] = bf2f((u16)(pg.x >> 16));
        gv[2] = bf2f((u16)(pg.y & 0xffffu)); gv[3] = bf2f((u16)(pg.y >> 16));
        bev[0] = bf2f((u16)(pe.x & 0xffffu)); bev[1] = bf2f((u16)(pe.x >> 16));
        bev[2] = bf2f((u16)(pe.y & 0xffffu)); bev[3] = bf2f((u16)(pe.y >> 16));
    } else {
        float4 t3 = ((const float4*)gamma)[cg];
        float4 t4 = ((const float4*)beta)[cg];
        gv[0] = t3.x; gv[1] = t3.y; gv[2] = t3.z; gv[3] = t3.w;
        bev[0] = t4.x; bev[1] = t4.y; bev[2] = t4.z; bev[3] = t4.w;
    }

    for (int t = blockIdx.x; t < NTM; t += gridDim.x) {
        const int row0 = t * TRM;
        __syncthreads();  // prev iteration fully done
        // ---- stage z tile -> bf16 swizzled LDS ----
        if (ZBF) {
#pragma unroll
            for (int q = 0; q < 2; ++q) {
                int u = tid + q * 512;           // 1024 units
                int row = u >> 4, cu = u & 15;
                int grow = row0 + row;
                uint4 p = {0u, 0u, 0u, 0u};
                if (grow < NN) p = ((const uint4*)zv)[(size_t)grow * 16 + cu];
                *(uint4*)(ztc + row * 256 + ((cu ^ (row & 7)) << 4)) = p;
            }
        } else {
#pragma unroll
            for (int q = 0; q < 2; ++q) {
                int u = tid + q * 512;
                int row = u >> 4, cu = u & 15;
                int grow = row0 + row;
                float4 a0 = {0.f, 0.f, 0.f, 0.f}, a1 = {0.f, 0.f, 0.f, 0.f};
                if (grow < NN) {
                    a0 = ((const float4*)zv)[(size_t)grow * 32 + cu * 2 + 0];
                    a1 = ((const float4*)zv)[(size_t)grow * 32 + cu * 2 + 1];
                }
                uint4 p;
                p.x = (u32)f2bf(a0.x) | ((u32)f2bf(a0.y) << 16);
                p.y = (u32)f2bf(a0.z) | ((u32)f2bf(a0.w) << 16);
                p.z = (u32)f2bf(a1.x) | ((u32)f2bf(a1.y) << 16);
                p.w = (u32)f2bf(a1.z) | ((u32)f2bf(a1.w) << 16);
                *(uint4*)(ztc + row * 256 + ((cu ^ (row & 7)) << 4)) = p;
            }
        }
        __syncthreads();

        f32x4 acc[4];
        // ---- layer 1: h1 = relu(z @ W1^T + b1) ----
#pragma unroll
        for (int tt = 0; tt < 4; ++tt)
            acc[tt] = (f32x4){b1v[tt], b1v[tt], b1v[tt], b1v[tt]};
#pragma unroll
        for (int c = 0; c < 4; ++c) {
            bf16x8 af = *(const bf16x8*)(ztc + arow * 256 + (((c * 4 + hi) ^ (arow & 7)) << 4));
#pragma unroll
            for (int tt = 0; tt < 4; ++tt) {
                int brow = nb + tt * 16 + lrow;
                bf16x8 bfv = *(const bf16x8*)(w1c + brow * 256 + (((c * 4 + hi) ^ (brow & 7)) << 4));
                acc[tt] = __builtin_amdgcn_mfma_f32_16x16x32_bf16(af, bfv, acc[tt], 0, 0, 0);
            }
        }
        // epilogue 1: relu -> bf16 -> s_h1 (swizzled scalar writes)
#pragma unroll
        for (int tt = 0; tt < 4; ++tt) {
            int j = nb + tt * 16 + lrow;
            int jb2 = j * 2;
            int unit = jb2 >> 4, within = jb2 & 15;
#pragma unroll
            for (int qq = 0; qq < 4; ++qq) {
                int row = rstrip * 16 + hi * 4 + qq;
                u16 hb = f2bf(fmaxf(acc[tt][qq], 0.f));
                *(u16*)(h1c + row * 256 + ((unit ^ (row & 7)) << 4) + within) = hb;
            }
        }
        __syncthreads();
        // ---- layer 2: h2 = relu(h1 @ W2^T + b2) ----
#pragma unroll
        for (int tt = 0; tt < 4; ++tt)
            acc[tt] = (f32x4){b2v[tt], b2v[tt], b2v[tt], b2v[tt]};
#pragma unroll
        for (int c = 0; c < 4; ++c) {
            bf16x8 af = *(const bf16x8*)(h1c + arow * 256 + (((c * 4 + hi) ^ (arow & 7)) << 4));
#pragma unroll
            for (int tt = 0; tt < 4; ++tt) {
                int brow = nb + tt * 16 + lrow;
                bf16x8 bfv = *(const bf16x8*)(w2c + brow * 256 + (((c * 4 + hi) ^ (brow & 7)) << 4));
                acc[tt] = __builtin_amdgcn_mfma_f32_16x16x32_bf16(af, bfv, acc[tt], 0, 0, 0);
            }
        }
        // epilogue 2: relu -> f32 s_h2
#pragma unroll
        for (int tt = 0; tt < 4; ++tt) {
            int j = nb + tt * 16 + lrow;
#pragma unroll
            for (int qq = 0; qq < 4; ++qq) {
                int row = rstrip * 16 + hi * 4 + qq;
                s_h2[row * 132 + j] = fmaxf(acc[tt][qq], 0.f);
            }
        }
        __syncthreads();
        // ---- LN + skip + store ----
#pragma unroll
        for (int r = 0; r < 4; ++r) {
            const float* hp = &s_h2[(r0 + r) * 132 + 4 * cg];
            float h0 = hp[0], h1 = hp[1], h2 = hp[2], h3 = hp[3];
            float s1 = h0 + h1 + h2 + h3;
            float s2 = h0 * h0 + h1 * h1 + h2 * h2 + h3 * h3;
#pragma unroll
            for (int m = 1; m <= 16; m <<= 1) {
                s1 += __shfl_xor(s1, m);
                s2 += __shfl_xor(s2, m);
            }
            float mean = s1 * (1.0f / DD);
            float var = s2 * (1.0f / DD) - mean * mean;
            float rs = rsqrtf(var + 1e-5f);
            int grow = row0 + r0 + r;
            if (grow < NN) {
                float xi[4];
                if (FBF) {
                    uint2 px = ((const uint2*)((const u16*)x0 + (size_t)grow * DD))[cg];
                    xi[0] = bf2f((u16)(px.x & 0xffffu)); xi[1] = bf2f((u16)(px.x >> 16));
                    xi[2] = bf2f((u16)(px.y & 0xffffu)); xi[3] = bf2f((u16)(px.y >> 16));
                } else {
                    float4 px = ((const float4*)((const float*)x0 + (size_t)grow * DD))[cg];
                    xi[0] = px.x; xi[1] = px.y; xi[2] = px.z; xi[3] = px.w;
                }
                float4 o;
                o.x = (h0 - mean) * rs * gv[0] + bev[0] + xi[0];
                o.y = (h1 - mean) * rs * gv[1] + bev[1] + xi[1];
                o.z = (h2 - mean) * rs * gv[2] + bev[2] + xi[2];
                o.w = (h3 - mean) * rs * gv[3] + bev[3] + xi[3];
                ((float4*)(out + (size_t)grow * DD))[cg] = o;
            }
        }
    }
}

extern "C" void kernel_launch(void* const* d_in, const int* in_sizes, int n_in,
                              void* d_out, int out_size, void* d_ws, size_t ws_size,
                              hipStream_t stream) {
    const void* x = d_in[0];
    const int* ei = (const int*)d_in[1];
    const void* W1 = d_in[2];
    const void* b1 = d_in[3];
    const void* W2 = d_in[4];
    const void* b2 = d_in[5];
    const void* eta = d_in[6];
    const void* gamma = d_in[7];
    const void* beta = d_in[8];
    float* out = (float*)d_out;

    // workspace layout (256B aligned). CSR path packs xb+zb (bf16, 12.8MB
    // each) into the 25.6MB z region; fallback uses it as one f32 z.
    const size_t FLAGS_OFF = 0;
    const size_t PART_OFF = 64;
    const size_t Z_OFF = 256;
    const size_t ZB = (size_t)NN * DD * sizeof(float);   // 25,600,000
    const size_t XB_OFF = Z_OFF;                          // bf16 x copy
    const size_t ZBF_OFF = Z_OFF + (size_t)NN * DD * 2;   // bf16 z
    const size_t DEG_OFF = Z_OFF + ZB;
    const size_t DEGB = 200192;
    const size_t RS_OFF = DEG_OFF + DEGB;
    const size_t RSB = 200448;
    const size_t BS_OFF = RS_OFF + RSB;
    const size_t BSB = (size_t)NE * sizeof(u32);
    const size_t TOT = BS_OFF + BSB;                     // ~29.2 MB

    if (ws_size < Z_OFF + ZB) return;
    int* flags = (int*)((char*)d_ws + FLAGS_OFF);
    u32* partials = (u32*)((char*)d_ws + PART_OFF);

    gin_detect<<<1, 64, 0, stream>>>((const u32*)x, (const u32*)ei, flags);

    if (ws_size >= TOT) {
        u32* xb = (u32*)((char*)d_ws + XB_OFF);
        u32* zb = (u32*)((char*)d_ws + ZBF_OFF);
        u32* deg = (u32*)((char*)d_ws + DEG_OFF);        // becomes cursor/row_end
        u32* row_start = (u32*)((char*)d_ws + RS_OFF);
        u32* bs = (u32*)((char*)d_ws + BS_OFF);
        gin_tobf<<<(NN * DD / 8 + 255) / 256, 256, 0, stream>>>(x, (uint4*)xb, flags);
        gin_zero<<<(NN + 255) / 256, 256, 0, stream>>>(deg);
        gin_hist<<<(NE + 255) / 256, 256, 0, stream>>>(ei, deg, flags);
        gin_scan1<<<NSB, 1024, 0, stream>>>(deg, partials);
        gin_scan2<<<1, 64, 0, stream>>>(partials);
        gin_scan3<<<NSB, 1024, 0, stream>>>(deg, partials, row_start, deg);
        gin_fill<<<(NE + 255) / 256, 256, 0, stream>>>(ei, deg, bs, flags);
        gin_gather<<<(NN + 3) / 4, 256, 0, stream>>>(xb, bs, row_start, deg, eta, zb, flags);
        gin_mlp<0, 1><<<256, 512, 0, stream>>>(zb, x, W1, b1, W2, b2, gamma, beta, out, flags);
        gin_mlp<1, 1><<<256, 512, 0, stream>>>(zb, x, W1, b1, W2, b2, gamma, beta, out, flags);
    } else {
        float* z = (float*)((char*)d_ws + Z_OFF);
        gin_init<<<(NN * DD / 8 + 255) / 256, 256, 0, stream>>>(x, eta, z, flags);
        gin_scatter<<<NE / 4, 256, 0, stream>>>(x, ei, z, flags);
        gin_mlp<0, 0><<<256, 512, 0, stream>>>(z, x, W1, b1, W2, b2, gamma, beta, out, flags);
        gin_mlp<1, 0><<<256, 512, 0, stream>>>(z, x, W1, b1, W2, b2, gamma, beta, out, flags);
    }
}

// Round 10
// 178.857 us; speedup vs baseline: 6.9312x; 1.0430x over previous
//
#include <hip/hip_runtime.h>

#define NN 50000
#define NE 800000
#define DD 128

typedef unsigned int u32;
typedef unsigned short u16;
typedef unsigned long long u64;
typedef __attribute__((ext_vector_type(8))) short bf16x8;
typedef __attribute__((ext_vector_type(4))) float f32x4;

__device__ __forceinline__ float bf2f(u16 u) {
    union { float f; u32 i; } v; v.i = ((u32)u) << 16; return v.f;
}
__device__ __forceinline__ u16 f2bf(float f) {
    u32 x = __float_as_uint(f);
    x += 0x7fffu + ((x >> 16) & 1u);
    return (u16)(x >> 16);
}

// ---------------- K0: dtype detect ----------------
// flags[0]=1 if float data is bf16 (else f32); flags[1]=1 if edge_index int64.
__global__ __launch_bounds__(64) void gin_detect(const u32* __restrict__ xw,
                                                 const u32* __restrict__ ew,
                                                 int* __restrict__ flags) {
    int lane = threadIdx.x;
    u32 w = xw[lane];
    u32 e8 = (w >> 7) & 0xFFu;
    bool bfOK = (e8 >= 100u && e8 <= 150u) || ((w & 0xFFFFu) == 0u);
    u64 m1 = __ballot(bfOK);
    bool oddZero = (ew[2 * lane + 1] == 0u);
    u64 m2 = __ballot(oddZero);
    if (lane == 0) {
        flags[0] = (__popcll(m1) >= 56) ? 1 : 0;
        flags[1] = (__popcll(m2) >= 60) ? 1 : 0;
    }
}

// ---------------- x -> bf16 workspace copy ----------------
__global__ __launch_bounds__(256) void gin_tobf(const void* __restrict__ xv,
                                                uint4* __restrict__ xb,
                                                const int* __restrict__ flags) {
    int i = blockIdx.x * 256 + threadIdx.x;     // 16B unit (8 bf16)
    const int nu = NN * DD / 8;                 // 800,000
    if (i >= nu) return;
    if (flags[0]) {
        xb[i] = ((const uint4*)xv)[i];
    } else {
        float4 a0 = ((const float4*)xv)[2 * i + 0];
        float4 a1 = ((const float4*)xv)[2 * i + 1];
        uint4 p;
        p.x = (u32)f2bf(a0.x) | ((u32)f2bf(a0.y) << 16);
        p.y = (u32)f2bf(a0.z) | ((u32)f2bf(a0.w) << 16);
        p.z = (u32)f2bf(a1.x) | ((u32)f2bf(a1.y) << 16);
        p.w = (u32)f2bf(a1.z) | ((u32)f2bf(a1.w) << 16);
        xb[i] = p;
    }
}

// ---------------- CSR build ----------------
__global__ __launch_bounds__(256) void gin_zero(u32* __restrict__ deg) {
    int i = blockIdx.x * 256 + threadIdx.x;
    if (i < NN) deg[i] = 0u;
}

__global__ __launch_bounds__(256) void gin_hist(const int* __restrict__ ei,
                                                u32* __restrict__ deg,
                                                const int* __restrict__ flags) {
    int e = blockIdx.x * 256 + threadIdx.x;
    if (e >= NE) return;
    int d = flags[1] ? ei[2 * (NE + e)] : ei[NE + e];
    atomicAdd(&deg[d], 1u);
}

#define SCAN_CHUNK 2048
#define NSB ((NN + SCAN_CHUNK - 1) / SCAN_CHUNK)   // 25 blocks

__global__ __launch_bounds__(1024) void gin_scan1(const u32* __restrict__ deg,
                                                  u32* __restrict__ partials) {
    __shared__ u32 red[1024];
    int tid = threadIdx.x;
    int base = blockIdx.x * SCAN_CHUNK + tid * 2;
    u32 a = (base < NN) ? deg[base] : 0u;
    u32 b = (base + 1 < NN) ? deg[base + 1] : 0u;
    red[tid] = a + b;
    __syncthreads();
    for (int off = 512; off > 0; off >>= 1) {
        if (tid < off) red[tid] += red[tid + off];
        __syncthreads();
    }
    if (tid == 0) partials[blockIdx.x] = red[0];
}

__global__ __launch_bounds__(64) void gin_scan2(u32* __restrict__ partials) {
    int lane = threadIdx.x;
    u32 orig = (lane < NSB) ? partials[lane] : 0u;
    u32 v = orig;
    for (int off = 1; off < 64; off <<= 1) {
        u32 t = __shfl_up(v, off);
        if (lane >= off) v += t;
    }
    if (lane < NSB) partials[lane] = v - orig;  // exclusive
}

__global__ __launch_bounds__(1024) void gin_scan3(const u32* __restrict__ deg,
                                                  const u32* __restrict__ partials,
                                                  u32* __restrict__ row_start,
                                                  u32* __restrict__ cursor) {
    __shared__ u32 sc[1024];
    int tid = threadIdx.x;
    int base = blockIdx.x * SCAN_CHUNK + tid * 2;
    u32 a = (base < NN) ? deg[base] : 0u;
    u32 b = (base + 1 < NN) ? deg[base + 1] : 0u;
    u32 ts = a + b;
    sc[tid] = ts;
    __syncthreads();
    for (int off = 1; off < 1024; off <<= 1) {
        u32 v = (tid >= off) ? sc[tid - off] : 0u;
        __syncthreads();
        sc[tid] += v;
        __syncthreads();
    }
    u32 excl = sc[tid] - ts + partials[blockIdx.x];
    if (base < NN) { row_start[base] = excl; cursor[base] = excl; }
    if (base + 1 < NN) { row_start[base + 1] = excl + a; cursor[base + 1] = excl + a; }
}

// fill: 2 edges/thread, u16 bucket entries (NN < 65536).
__global__ __launch_bounds__(256) void gin_fill(const int* __restrict__ ei,
                                                u32* __restrict__ cursor,
                                                u16* __restrict__ bs,
                                                const int* __restrict__ flags) {
    int e0 = (blockIdx.x * 256 + threadIdx.x) * 2;
    const int f64 = flags[1];
#pragma unroll
    for (int k = 0; k < 2; ++k) {
        int e = e0 + k;
        if (e >= NE) return;
        int s, d;
        if (f64) { s = ei[2 * e]; d = ei[2 * (NE + e)]; }
        else     { s = ei[e];     d = ei[NE + e]; }
        u32 pos = atomicAdd(&cursor[d], 1u);
        bs[pos] = (u16)s;
    }
}

// ---------------- gather-sum (+init), bf16 rows, u16 indices ----------------
__global__ __launch_bounds__(256) void gin_gather(const u32* __restrict__ xb,
                                                  const u16* __restrict__ bs,
                                                  const u32* __restrict__ row_start,
                                                  const u32* __restrict__ row_end,
                                                  const void* __restrict__ etav,
                                                  u32* __restrict__ zb,
                                                  const int* __restrict__ flags) {
    int node = blockIdx.x * 4 + (threadIdx.x >> 6);
    if (node >= NN) return;
    const int lane = threadIdx.x & 63;
    float s = 1.0f + (flags[0] ? bf2f(((const u16*)etav)[0]) : ((const float*)etav)[0]);
    u32 p = xb[(size_t)node * 64 + lane];
    float ax = bf2f((u16)(p & 0xffffu)) * s;
    float ay = bf2f((u16)(p >> 16)) * s;
    u32 jb = row_start[node], je = row_end[node];
    u32 j = jb;
    for (; j + 1 < je; j += 2) {
        u32 s0 = bs[j], s1 = bs[j + 1];
        u32 p0 = xb[(size_t)s0 * 64 + lane];
        u32 p1 = xb[(size_t)s1 * 64 + lane];
        ax += bf2f((u16)(p0 & 0xffffu)) + bf2f((u16)(p1 & 0xffffu));
        ay += bf2f((u16)(p0 >> 16)) + bf2f((u16)(p1 >> 16));
    }
    if (j < je) {
        u32 p0 = xb[(size_t)bs[j] * 64 + lane];
        ax += bf2f((u16)(p0 & 0xffffu));
        ay += bf2f((u16)(p0 >> 16));
    }
    zb[(size_t)node * 64 + lane] = (u32)f2bf(ax) | ((u32)f2bf(ay) << 16);
}

// ---------------- fallback: init + atomic scatter (f32 z) ----------------
__global__ __launch_bounds__(256) void gin_init(const void* __restrict__ xv,
                                                const void* __restrict__ etav,
                                                float* __restrict__ z,
                                                const int* __restrict__ flags) {
    int i = blockIdx.x * 256 + threadIdx.x;
    const int n8 = NN * DD / 8;
    if (i >= n8) return;
    const int fbf = flags[0];
    float s = 1.0f + (fbf ? bf2f(((const u16*)etav)[0]) : ((const float*)etav)[0]);
    float4 a, b;
    if (fbf) {
        uint4 p = ((const uint4*)xv)[i];
        a.x = bf2f((u16)(p.x & 0xffffu)); a.y = bf2f((u16)(p.x >> 16));
        a.z = bf2f((u16)(p.y & 0xffffu)); a.w = bf2f((u16)(p.y >> 16));
        b.x = bf2f((u16)(p.z & 0xffffu)); b.y = bf2f((u16)(p.z >> 16));
        b.z = bf2f((u16)(p.w & 0xffffu)); b.w = bf2f((u16)(p.w >> 16));
    } else {
        a = ((const float4*)xv)[2 * i + 0];
        b = ((const float4*)xv)[2 * i + 1];
    }
    a.x *= s; a.y *= s; a.z *= s; a.w *= s;
    b.x *= s; b.y *= s; b.z *= s; b.w *= s;
    ((float4*)z)[2 * i + 0] = a;
    ((float4*)z)[2 * i + 1] = b;
}

__global__ __launch_bounds__(256) void gin_scatter(const void* __restrict__ xv,
                                                   const int* __restrict__ ei,
                                                   float* __restrict__ z,
                                                   const int* __restrict__ flags) {
    int e = blockIdx.x * 4 + (threadIdx.x >> 6);
    if (e >= NE) return;
    const int fbf = flags[0];
    const int f64 = flags[1];
    int lane = threadIdx.x & 63;
    int s, d;
    if (f64) { s = ei[2 * e]; d = ei[2 * (NE + e)]; }
    else     { s = ei[e];     d = ei[NE + e]; }
    float v0, v1;
    if (fbf) {
        u32 p = ((const u32*)((const u16*)xv + (size_t)s * DD))[lane];
        v0 = bf2f((u16)(p & 0xffffu));
        v1 = bf2f((u16)(p >> 16));
    } else {
        float2 p = ((const float2*)((const float*)xv + (size_t)s * DD))[lane];
        v0 = p.x; v1 = p.y;
    }
    float* dst = z + (size_t)d * DD + 2 * lane;
    atomicAdd(dst + 0, v0);
    atomicAdd(dst + 1, v1);
}

// ---------------- MFMA MLP + LN + skip ----------------
// bf16 MFMA (16x16x32), f32 accumulate. C/D layout: col=lane&15,
// row=(lane>>4)*4+reg (m89-verified). LDS tiles 256B-row bf16 with 16B-unit
// XOR swizzle (unit ^= row&7), write & read both swizzled.
// ZBF=1: z workspace is bf16 (CSR path). ZBF=0: f32 z (fallback path).
#define TRM 64
#define NTM ((NN + TRM - 1) / TRM)

template <int FBF, int ZBF>
__global__ __launch_bounds__(512, 1) void gin_mlp(
    const void* __restrict__ zv, const void* __restrict__ x0,
    const void* __restrict__ W1, const void* __restrict__ b1,
    const void* __restrict__ W2, const void* __restrict__ b2,
    const void* __restrict__ gamma, const void* __restrict__ beta,
    float* __restrict__ out, const int* __restrict__ flags) {
    if (flags[0] != FBF) return;  // wave-uniform early exit (dud variant)

    __shared__ short s_w1[DD * DD];    // 32 KB bf16, row-major, swizzled
    __shared__ short s_w2[DD * DD];    // 32 KB
    __shared__ short s_zt[TRM * DD];   // 16 KB
    __shared__ short s_h1[TRM * DD];   // 16 KB
    __shared__ float s_h2[TRM * 132];  // 33 KB (stride 132 spreads banks)

    const int tid = threadIdx.x;
    char* w1c = (char*)s_w1;
    char* w2c = (char*)s_w2;
    char* ztc = (char*)s_zt;
    char* h1c = (char*)s_h1;

    // ---- stage weights -> bf16 LDS (once per block) ----
    if (FBF) {
#pragma unroll
        for (int q = 0; q < 4; ++q) {
            int u = tid + q * 512;            // 16B unit: 2048 per matrix
            int row = u >> 4, cu = u & 15;
            uint4 a = ((const uint4*)W1)[u];
            uint4 c = ((const uint4*)W2)[u];
            int off = row * 256 + ((cu ^ (row & 7)) << 4);
            *(uint4*)(w1c + off) = a;
            *(uint4*)(w2c + off) = c;
        }
    } else {
#pragma unroll
        for (int q = 0; q < 4; ++q) {
            int u = tid + q * 512;
            int row = u >> 4, cu = u & 15;
            float4 a0 = ((const float4*)W1)[u * 2 + 0];
            float4 a1 = ((const float4*)W1)[u * 2 + 1];
            float4 c0 = ((const float4*)W2)[u * 2 + 0];
            float4 c1 = ((const float4*)W2)[u * 2 + 1];
            uint4 pa, pc;
            pa.x = (u32)f2bf(a0.x) | ((u32)f2bf(a0.y) << 16);
            pa.y = (u32)f2bf(a0.z) | ((u32)f2bf(a0.w) << 16);
            pa.z = (u32)f2bf(a1.x) | ((u32)f2bf(a1.y) << 16);
            pa.w = (u32)f2bf(a1.z) | ((u32)f2bf(a1.w) << 16);
            pc.x = (u32)f2bf(c0.x) | ((u32)f2bf(c0.y) << 16);
            pc.y = (u32)f2bf(c0.z) | ((u32)f2bf(c0.w) << 16);
            pc.z = (u32)f2bf(c1.x) | ((u32)f2bf(c1.y) << 16);
            pc.w = (u32)f2bf(c1.z) | ((u32)f2bf(c1.w) << 16);
            int off = row * 256 + ((cu ^ (row & 7)) << 4);
            *(uint4*)(w1c + off) = pa;
            *(uint4*)(w2c + off) = pc;
        }
    }

    const int lane = tid & 63;
    const int wid = tid >> 6;          // 0..7
    const int lrow = lane & 15;
    const int hi = lane >> 4;          // 0..3
    const int rstrip = wid & 3;        // row-strip (16 rows)
    const int nb = (wid >> 2) * 64;    // col base (4 tiles of 16)
    const int arow = rstrip * 16 + lrow;

    float b1v[4], b2v[4];
#pragma unroll
    for (int tt = 0; tt < 4; ++tt) {
        int j = nb + tt * 16 + lrow;
        b1v[tt] = FBF ? bf2f(((const u16*)b1)[j]) : ((const float*)b1)[j];
        b2v[tt] = FBF ? bf2f(((const u16*)b2)[j]) : ((const float*)b2)[j];
    }

    // LN phase params
    const int cg = tid & 31;
    const int rg = tid >> 5;
    const int r0 = rg * 4;
    float gv[4], bev[4];
    if (FBF) {
        uint2 pg = ((const uint2*)gamma)[cg];
        uint2 pe = ((const uint2*)beta)[cg];
        gv[0] = bf2f((u16)(pg.x & 0xffffu)); gv[1] = bf2f((u16)(pg.x >> 16));
        gv[2] = bf2f((u16)(pg.y & 0xffffu)); gv[3] = bf2f((u16)(pg.y >> 16));
        bev[0] = bf2f((u16)(pe.x & 0xffffu)); bev[1] = bf2f((u16)(pe.x >> 16));
        bev[2] = bf2f((u16)(pe.y & 0xffffu)); bev[3] = bf2f((u16)(pe.y >> 16));
    } else {
        float4 t3 = ((const float4*)gamma)[cg];
        float4 t4 = ((const float4*)beta)[cg];
        gv[0] = t3.x; gv[1] = t3.y; gv[2] = t3.z; gv[3] = t3.w;
        bev[0] = t4.x; bev[1] = t4.y; bev[2] = t4.z; bev[3] = t4.w;
    }

    for (int t = blockIdx.x; t < NTM; t += gridDim.x) {
        const int row0 = t * TRM;
        __syncthreads();  // prev iteration fully done
        // ---- stage z tile -> bf16 swizzled LDS ----
        if (ZBF) {
#pragma unroll
            for (int q = 0; q < 2; ++q) {
                int u = tid + q * 512;           // 1024 units
                int row = u >> 4, cu = u & 15;
                int grow = row0 + row;
                uint4 p = {0u, 0u, 0u, 0u};
                if (grow < NN) p = ((const uint4*)zv)[(size_t)grow * 16 + cu];
                *(uint4*)(ztc + row * 256 + ((cu ^ (row & 7)) << 4)) = p;
            }
        } else {
#pragma unroll
            for (int q = 0; q < 2; ++q) {
                int u = tid + q * 512;
                int row = u >> 4, cu = u & 15;
                int grow = row0 + row;
                float4 a0 = {0.f, 0.f, 0.f, 0.f}, a1 = {0.f, 0.f, 0.f, 0.f};
                if (grow < NN) {
                    a0 = ((const float4*)zv)[(size_t)grow * 32 + cu * 2 + 0];
                    a1 = ((const float4*)zv)[(size_t)grow * 32 + cu * 2 + 1];
                }
                uint4 p;
                p.x = (u32)f2bf(a0.x) | ((u32)f2bf(a0.y) << 16);
                p.y = (u32)f2bf(a0.z) | ((u32)f2bf(a0.w) << 16);
                p.z = (u32)f2bf(a1.x) | ((u32)f2bf(a1.y) << 16);
                p.w = (u32)f2bf(a1.z) | ((u32)f2bf(a1.w) << 16);
                *(uint4*)(ztc + row * 256 + ((cu ^ (row & 7)) << 4)) = p;
            }
        }
        __syncthreads();

        f32x4 acc[4];
        // ---- layer 1: h1 = relu(z @ W1^T + b1) ----
#pragma unroll
        for (int tt = 0; tt < 4; ++tt)
            acc[tt] = (f32x4){b1v[tt], b1v[tt], b1v[tt], b1v[tt]};
#pragma unroll
        for (int c = 0; c < 4; ++c) {
            bf16x8 af = *(const bf16x8*)(ztc + arow * 256 + (((c * 4 + hi) ^ (arow & 7)) << 4));
#pragma unroll
            for (int tt = 0; tt < 4; ++tt) {
                int brow = nb + tt * 16 + lrow;
                bf16x8 bfv = *(const bf16x8*)(w1c + brow * 256 + (((c * 4 + hi) ^ (brow & 7)) << 4));
                acc[tt] = __builtin_amdgcn_mfma_f32_16x16x32_bf16(af, bfv, acc[tt], 0, 0, 0);
            }
        }
        // epilogue 1: relu -> bf16 -> s_h1 (swizzled scalar writes)
#pragma unroll
        for (int tt = 0; tt < 4; ++tt) {
            int j = nb + tt * 16 + lrow;
            int jb2 = j * 2;
            int unit = jb2 >> 4, within = jb2 & 15;
#pragma unroll
            for (int qq = 0; qq < 4; ++qq) {
                int row = rstrip * 16 + hi * 4 + qq;
                u16 hb = f2bf(fmaxf(acc[tt][qq], 0.f));
                *(u16*)(h1c + row * 256 + ((unit ^ (row & 7)) << 4) + within) = hb;
            }
        }
        __syncthreads();
        // ---- layer 2: h2 = relu(h1 @ W2^T + b2) ----
#pragma unroll
        for (int tt = 0; tt < 4; ++tt)
            acc[tt] = (f32x4){b2v[tt], b2v[tt], b2v[tt], b2v[tt]};
#pragma unroll
        for (int c = 0; c < 4; ++c) {
            bf16x8 af = *(const bf16x8*)(h1c + arow * 256 + (((c * 4 + hi) ^ (arow & 7)) << 4));
#pragma unroll
            for (int tt = 0; tt < 4; ++tt) {
                int brow = nb + tt * 16 + lrow;
                bf16x8 bfv = *(const bf16x8*)(w2c + brow * 256 + (((c * 4 + hi) ^ (brow & 7)) << 4));
                acc[tt] = __builtin_amdgcn_mfma_f32_16x16x32_bf16(af, bfv, acc[tt], 0, 0, 0);
            }
        }
        // epilogue 2: relu -> f32 s_h2
#pragma unroll
        for (int tt = 0; tt < 4; ++tt) {
            int j = nb + tt * 16 + lrow;
#pragma unroll
            for (int qq = 0; qq < 4; ++qq) {
                int row = rstrip * 16 + hi * 4 + qq;
                s_h2[row * 132 + j] = fmaxf(acc[tt][qq], 0.f);
            }
        }
        __syncthreads();
        // ---- LN + skip + store ----
#pragma unroll
        for (int r = 0; r < 4; ++r) {
            const float* hp = &s_h2[(r0 + r) * 132 + 4 * cg];
            float h0 = hp[0], h1 = hp[1], h2 = hp[2], h3 = hp[3];
            float s1 = h0 + h1 + h2 + h3;
            float s2 = h0 * h0 + h1 * h1 + h2 * h2 + h3 * h3;
#pragma unroll
            for (int m = 1; m <= 16; m <<= 1) {
                s1 += __shfl_xor(s1, m);
                s2 += __shfl_xor(s2, m);
            }
            float mean = s1 * (1.0f / DD);
            float var = s2 * (1.0f / DD) - mean * mean;
            float rs = rsqrtf(var + 1e-5f);
            int grow = row0 + r0 + r;
            if (grow < NN) {
                float xi[4];
                if (FBF) {
                    uint2 px = ((const uint2*)((const u16*)x0 + (size_t)grow * DD))[cg];
                    xi[0] = bf2f((u16)(px.x & 0xffffu)); xi[1] = bf2f((u16)(px.x >> 16));
                    xi[2] = bf2f((u16)(px.y & 0xffffu)); xi[3] = bf2f((u16)(px.y >> 16));
                } else {
                    float4 px = ((const float4*)((const float*)x0 + (size_t)grow * DD))[cg];
                    xi[0] = px.x; xi[1] = px.y; xi[2] = px.z; xi[3] = px.w;
                }
                float4 o;
                o.x = (h0 - mean) * rs * gv[0] + bev[0] + xi[0];
                o.y = (h1 - mean) * rs * gv[1] + bev[1] + xi[1];
                o.z = (h2 - mean) * rs * gv[2] + bev[2] + xi[2];
                o.w = (h3 - mean) * rs * gv[3] + bev[3] + xi[3];
                ((float4*)(out + (size_t)grow * DD))[cg] = o;
            }
        }
    }
}

extern "C" void kernel_launch(void* const* d_in, const int* in_sizes, int n_in,
                              void* d_out, int out_size, void* d_ws, size_t ws_size,
                              hipStream_t stream) {
    const void* x = d_in[0];
    const int* ei = (const int*)d_in[1];
    const void* W1 = d_in[2];
    const void* b1 = d_in[3];
    const void* W2 = d_in[4];
    const void* b2 = d_in[5];
    const void* eta = d_in[6];
    const void* gamma = d_in[7];
    const void* beta = d_in[8];
    float* out = (float*)d_out;

    // workspace layout (256B aligned). CSR path packs xb+zb (bf16, 12.8MB
    // each) into the 25.6MB z region; fallback uses it as one f32 z.
    const size_t FLAGS_OFF = 0;
    const size_t PART_OFF = 64;
    const size_t Z_OFF = 256;
    const size_t ZB = (size_t)NN * DD * sizeof(float);   // 25,600,000
    const size_t XB_OFF = Z_OFF;                          // bf16 x copy
    const size_t ZBF_OFF = Z_OFF + (size_t)NN * DD * 2;   // bf16 z
    const size_t DEG_OFF = Z_OFF + ZB;
    const size_t DEGB = 200192;
    const size_t RS_OFF = DEG_OFF + DEGB;
    const size_t RSB = 200448;
    const size_t BS_OFF = RS_OFF + RSB;
    const size_t BSB = (size_t)NE * sizeof(u16);         // 1,600,000 (u16 entries)
    const size_t TOT = BS_OFF + BSB;                     // ~27.6 MB

    if (ws_size < Z_OFF + ZB) return;
    int* flags = (int*)((char*)d_ws + FLAGS_OFF);
    u32* partials = (u32*)((char*)d_ws + PART_OFF);

    gin_detect<<<1, 64, 0, stream>>>((const u32*)x, (const u32*)ei, flags);

    if (ws_size >= TOT) {
        u32* xb = (u32*)((char*)d_ws + XB_OFF);
        u32* zb = (u32*)((char*)d_ws + ZBF_OFF);
        u32* deg = (u32*)((char*)d_ws + DEG_OFF);        // becomes cursor/row_end
        u32* row_start = (u32*)((char*)d_ws + RS_OFF);
        u16* bs = (u16*)((char*)d_ws + BS_OFF);
        gin_tobf<<<(NN * DD / 8 + 255) / 256, 256, 0, stream>>>(x, (uint4*)xb, flags);
        gin_zero<<<(NN + 255) / 256, 256, 0, stream>>>(deg);
        gin_hist<<<(NE + 255) / 256, 256, 0, stream>>>(ei, deg, flags);
        gin_scan1<<<NSB, 1024, 0, stream>>>(deg, partials);
        gin_scan2<<<1, 64, 0, stream>>>(partials);
        gin_scan3<<<NSB, 1024, 0, stream>>>(deg, partials, row_start, deg);
        gin_fill<<<(NE / 2 + 255) / 256, 256, 0, stream>>>(ei, deg, bs, flags);
        gin_gather<<<(NN + 3) / 4, 256, 0, stream>>>(xb, bs, row_start, deg, eta, zb, flags);
        gin_mlp<0, 1><<<256, 512, 0, stream>>>(zb, x, W1, b1, W2, b2, gamma, beta, out, flags);
        gin_mlp<1, 1><<<256, 512, 0, stream>>>(zb, x, W1, b1, W2, b2, gamma, beta, out, flags);
    } else {
        float* z = (float*)((char*)d_ws + Z_OFF);
        gin_init<<<(NN * DD / 8 + 255) / 256, 256, 0, stream>>>(x, eta, z, flags);
        gin_scatter<<<NE / 4, 256, 0, stream>>>(x, ei, z, flags);
        gin_mlp<0, 0><<<256, 512, 0, stream>>>(z, x, W1, b1, W2, b2, gamma, beta, out, flags);
        gin_mlp<1, 0><<<256, 512, 0, stream>>>(z, x, W1, b1, W2, b2, gamma, beta, out, flags);
    }
}

// Round 11
// 149.527 us; speedup vs baseline: 8.2908x; 1.1962x over previous
//
#include <hip/hip_runtime.h>

#define NN 50000
#define NE 800000
#define DD 128

typedef unsigned int u32;
typedef unsigned short u16;
typedef unsigned long long u64;
typedef __attribute__((ext_vector_type(8))) short bf16x8;
typedef __attribute__((ext_vector_type(4))) float f32x4;

__device__ __forceinline__ float bf2f(u16 u) {
    union { float f; u32 i; } v; v.i = ((u32)u) << 16; return v.f;
}
__device__ __forceinline__ u16 f2bf(float f) {
    u32 x = __float_as_uint(f);
    x += 0x7fffu + ((x >> 16) & 1u);
    return (u16)(x >> 16);
}

// ---------------- K0: dtype detect ----------------
// flags[0]=1 if float data is bf16 (else f32); flags[1]=1 if edge_index int64.
__global__ __launch_bounds__(64) void gin_detect(const u32* __restrict__ xw,
                                                 const u32* __restrict__ ew,
                                                 int* __restrict__ flags) {
    int lane = threadIdx.x;
    u32 w = xw[lane];
    u32 e8 = (w >> 7) & 0xFFu;
    bool bfOK = (e8 >= 100u && e8 <= 150u) || ((w & 0xFFFFu) == 0u);
    u64 m1 = __ballot(bfOK);
    bool oddZero = (ew[2 * lane + 1] == 0u);
    u64 m2 = __ballot(oddZero);
    if (lane == 0) {
        flags[0] = (__popcll(m1) >= 56) ? 1 : 0;
        flags[1] = (__popcll(m2) >= 60) ? 1 : 0;
    }
}

// ---------------- x -> bf16 workspace copy ----------------
__global__ __launch_bounds__(256) void gin_tobf(const void* __restrict__ xv,
                                                uint4* __restrict__ xb,
                                                const int* __restrict__ flags) {
    int i = blockIdx.x * 256 + threadIdx.x;     // 16B unit (8 bf16)
    const int nu = NN * DD / 8;                 // 800,000
    if (i >= nu) return;
    if (flags[0]) {
        xb[i] = ((const uint4*)xv)[i];
    } else {
        float4 a0 = ((const float4*)xv)[2 * i + 0];
        float4 a1 = ((const float4*)xv)[2 * i + 1];
        uint4 p;
        p.x = (u32)f2bf(a0.x) | ((u32)f2bf(a0.y) << 16);
        p.y = (u32)f2bf(a0.z) | ((u32)f2bf(a0.w) << 16);
        p.z = (u32)f2bf(a1.x) | ((u32)f2bf(a1.y) << 16);
        p.w = (u32)f2bf(a1.z) | ((u32)f2bf(a1.w) << 16);
        xb[i] = p;
    }
}

// ---------------- CSR build ----------------
__global__ __launch_bounds__(256) void gin_zero(u32* __restrict__ deg) {
    int i = blockIdx.x * 256 + threadIdx.x;
    if (i < NN) deg[i] = 0u;
}

// hist: count degree AND record each edge's arrival rank (u16; max degree
// of this random graph ~50). The rank makes gin_fill atomic-free.
__global__ __launch_bounds__(256) void gin_hist(const int* __restrict__ ei,
                                                u32* __restrict__ deg,
                                                u16* __restrict__ rank,
                                                const int* __restrict__ flags) {
    int e = blockIdx.x * 256 + threadIdx.x;
    if (e >= NE) return;
    int d = flags[1] ? ei[2 * (NE + e)] : ei[NE + e];
    rank[e] = (u16)atomicAdd(&deg[d], 1u);
}

#define SCAN_CHUNK 2048
#define NSB ((NN + SCAN_CHUNK - 1) / SCAN_CHUNK)   // 25 blocks

__global__ __launch_bounds__(1024) void gin_scan1(const u32* __restrict__ deg,
                                                  u32* __restrict__ partials) {
    __shared__ u32 red[1024];
    int tid = threadIdx.x;
    int base = blockIdx.x * SCAN_CHUNK + tid * 2;
    u32 a = (base < NN) ? deg[base] : 0u;
    u32 b = (base + 1 < NN) ? deg[base + 1] : 0u;
    red[tid] = a + b;
    __syncthreads();
    for (int off = 512; off > 0; off >>= 1) {
        if (tid < off) red[tid] += red[tid + off];
        __syncthreads();
    }
    if (tid == 0) partials[blockIdx.x] = red[0];
}

__global__ __launch_bounds__(64) void gin_scan2(u32* __restrict__ partials) {
    int lane = threadIdx.x;
    u32 orig = (lane < NSB) ? partials[lane] : 0u;
    u32 v = orig;
    for (int off = 1; off < 64; off <<= 1) {
        u32 t = __shfl_up(v, off);
        if (lane >= off) v += t;
    }
    if (lane < NSB) partials[lane] = v - orig;  // exclusive
}

__global__ __launch_bounds__(1024) void gin_scan3(const u32* __restrict__ deg,
                                                  const u32* __restrict__ partials,
                                                  u32* __restrict__ row_start) {
    __shared__ u32 sc[1024];
    int tid = threadIdx.x;
    int base = blockIdx.x * SCAN_CHUNK + tid * 2;
    u32 a = (base < NN) ? deg[base] : 0u;
    u32 b = (base + 1 < NN) ? deg[base + 1] : 0u;
    u32 ts = a + b;
    sc[tid] = ts;
    __syncthreads();
    for (int off = 1; off < 1024; off <<= 1) {
        u32 v = (tid >= off) ? sc[tid - off] : 0u;
        __syncthreads();
        sc[tid] += v;
        __syncthreads();
    }
    u32 excl = sc[tid] - ts + partials[blockIdx.x];
    if (base < NN) row_start[base] = excl;
    if (base + 1 < NN) row_start[base + 1] = excl + a;
}

// fill: atomic-free. pos = row_start[dst] + rank[e].
__global__ __launch_bounds__(256) void gin_fill(const int* __restrict__ ei,
                                                const u32* __restrict__ row_start,
                                                const u16* __restrict__ rank,
                                                u16* __restrict__ bs,
                                                const int* __restrict__ flags) {
    int e = blockIdx.x * 256 + threadIdx.x;
    if (e >= NE) return;
    int s, d;
    if (flags[1]) { s = ei[2 * e]; d = ei[2 * (NE + e)]; }
    else          { s = ei[e];     d = ei[NE + e]; }
    bs[row_start[d] + (u32)rank[e]] = (u16)s;
}

// ---------------- gather-sum (+init), bf16 rows, u16 indices ----------------
__global__ __launch_bounds__(256) void gin_gather(const u32* __restrict__ xb,
                                                  const u16* __restrict__ bs,
                                                  const u32* __restrict__ row_start,
                                                  const u32* __restrict__ deg,
                                                  const void* __restrict__ etav,
                                                  u32* __restrict__ zb,
                                                  const int* __restrict__ flags) {
    int node = blockIdx.x * 4 + (threadIdx.x >> 6);
    if (node >= NN) return;
    const int lane = threadIdx.x & 63;
    float s = 1.0f + (flags[0] ? bf2f(((const u16*)etav)[0]) : ((const float*)etav)[0]);
    u32 p = xb[(size_t)node * 64 + lane];
    float ax = bf2f((u16)(p & 0xffffu)) * s;
    float ay = bf2f((u16)(p >> 16)) * s;
    u32 jb = row_start[node], je = jb + deg[node];
    u32 j = jb;
    for (; j + 1 < je; j += 2) {
        u32 s0 = bs[j], s1 = bs[j + 1];
        u32 p0 = xb[(size_t)s0 * 64 + lane];
        u32 p1 = xb[(size_t)s1 * 64 + lane];
        ax += bf2f((u16)(p0 & 0xffffu)) + bf2f((u16)(p1 & 0xffffu));
        ay += bf2f((u16)(p0 >> 16)) + bf2f((u16)(p1 >> 16));
    }
    if (j < je) {
        u32 p0 = xb[(size_t)bs[j] * 64 + lane];
        ax += bf2f((u16)(p0 & 0xffffu));
        ay += bf2f((u16)(p0 >> 16));
    }
    zb[(size_t)node * 64 + lane] = (u32)f2bf(ax) | ((u32)f2bf(ay) << 16);
}

// ---------------- fallback: init + atomic scatter (f32 z) ----------------
__global__ __launch_bounds__(256) void gin_init(const void* __restrict__ xv,
                                                const void* __restrict__ etav,
                                                float* __restrict__ z,
                                                const int* __restrict__ flags) {
    int i = blockIdx.x * 256 + threadIdx.x;
    const int n8 = NN * DD / 8;
    if (i >= n8) return;
    const int fbf = flags[0];
    float s = 1.0f + (fbf ? bf2f(((const u16*)etav)[0]) : ((const float*)etav)[0]);
    float4 a, b;
    if (fbf) {
        uint4 p = ((const uint4*)xv)[i];
        a.x = bf2f((u16)(p.x & 0xffffu)); a.y = bf2f((u16)(p.x >> 16));
        a.z = bf2f((u16)(p.y & 0xffffu)); a.w = bf2f((u16)(p.y >> 16));
        b.x = bf2f((u16)(p.z & 0xffffu)); b.y = bf2f((u16)(p.z >> 16));
        b.z = bf2f((u16)(p.w & 0xffffu)); b.w = bf2f((u16)(p.w >> 16));
    } else {
        a = ((const float4*)xv)[2 * i + 0];
        b = ((const float4*)xv)[2 * i + 1];
    }
    a.x *= s; a.y *= s; a.z *= s; a.w *= s;
    b.x *= s; b.y *= s; b.z *= s; b.w *= s;
    ((float4*)z)[2 * i + 0] = a;
    ((float4*)z)[2 * i + 1] = b;
}

__global__ __launch_bounds__(256) void gin_scatter(const void* __restrict__ xv,
                                                   const int* __restrict__ ei,
                                                   float* __restrict__ z,
                                                   const int* __restrict__ flags) {
    int e = blockIdx.x * 4 + (threadIdx.x >> 6);
    if (e >= NE) return;
    const int fbf = flags[0];
    const int f64 = flags[1];
    int lane = threadIdx.x & 63;
    int s, d;
    if (f64) { s = ei[2 * e]; d = ei[2 * (NE + e)]; }
    else     { s = ei[e];     d = ei[NE + e]; }
    float v0, v1;
    if (fbf) {
        u32 p = ((const u32*)((const u16*)xv + (size_t)s * DD))[lane];
        v0 = bf2f((u16)(p & 0xffffu));
        v1 = bf2f((u16)(p >> 16));
    } else {
        float2 p = ((const float2*)((const float*)xv + (size_t)s * DD))[lane];
        v0 = p.x; v1 = p.y;
    }
    float* dst = z + (size_t)d * DD + 2 * lane;
    atomicAdd(dst + 0, v0);
    atomicAdd(dst + 1, v1);
}

// ---------------- MFMA MLP + LN + skip ----------------
// bf16 MFMA (16x16x32), f32 accumulate. C/D layout: col=lane&15,
// row=(lane>>4)*4+reg (m89-verified). LDS tiles 256B-row bf16 with 16B-unit
// XOR swizzle (unit ^= row&7), write & read both swizzled.
// ZBF=1: z workspace is bf16 (CSR path). ZBF=0: f32 z (fallback path).
#define TRM 64
#define NTM ((NN + TRM - 1) / TRM)

template <int FBF, int ZBF>
__global__ __launch_bounds__(512, 1) void gin_mlp(
    const void* __restrict__ zv, const void* __restrict__ x0,
    const void* __restrict__ W1, const void* __restrict__ b1,
    const void* __restrict__ W2, const void* __restrict__ b2,
    const void* __restrict__ gamma, const void* __restrict__ beta,
    float* __restrict__ out, const int* __restrict__ flags) {
    if (flags[0] != FBF) return;  // wave-uniform early exit (dud variant)

    __shared__ short s_w1[DD * DD];    // 32 KB bf16, row-major, swizzled
    __shared__ short s_w2[DD * DD];    // 32 KB
    __shared__ short s_zt[TRM * DD];   // 16 KB
    __shared__ short s_h1[TRM * DD];   // 16 KB
    __shared__ float s_h2[TRM * 132];  // 33 KB (stride 132 spreads banks)

    const int tid = threadIdx.x;
    char* w1c = (char*)s_w1;
    char* w2c = (char*)s_w2;
    char* ztc = (char*)s_zt;
    char* h1c = (char*)s_h1;

    // ---- stage weights -> bf16 LDS (once per block) ----
    if (FBF) {
#pragma unroll
        for (int q = 0; q < 4; ++q) {
            int u = tid + q * 512;            // 16B unit: 2048 per matrix
            int row = u >> 4, cu = u & 15;
            uint4 a = ((const uint4*)W1)[u];
            uint4 c = ((const uint4*)W2)[u];
            int off = row * 256 + ((cu ^ (row & 7)) << 4);
            *(uint4*)(w1c + off) = a;
            *(uint4*)(w2c + off) = c;
        }
    } else {
#pragma unroll
        for (int q = 0; q < 4; ++q) {
            int u = tid + q * 512;
            int row = u >> 4, cu = u & 15;
            float4 a0 = ((const float4*)W1)[u * 2 + 0];
            float4 a1 = ((const float4*)W1)[u * 2 + 1];
            float4 c0 = ((const float4*)W2)[u * 2 + 0];
            float4 c1 = ((const float4*)W2)[u * 2 + 1];
            uint4 pa, pc;
            pa.x = (u32)f2bf(a0.x) | ((u32)f2bf(a0.y) << 16);
            pa.y = (u32)f2bf(a0.z) | ((u32)f2bf(a0.w) << 16);
            pa.z = (u32)f2bf(a1.x) | ((u32)f2bf(a1.y) << 16);
            pa.w = (u32)f2bf(a1.z) | ((u32)f2bf(a1.w) << 16);
            pc.x = (u32)f2bf(c0.x) | ((u32)f2bf(c0.y) << 16);
            pc.y = (u32)f2bf(c0.z) | ((u32)f2bf(c0.w) << 16);
            pc.z = (u32)f2bf(c1.x) | ((u32)f2bf(c1.y) << 16);
            pc.w = (u32)f2bf(c1.z) | ((u32)f2bf(c1.w) << 16);
            int off = row * 256 + ((cu ^ (row & 7)) << 4);
            *(uint4*)(w1c + off) = pa;
            *(uint4*)(w2c + off) = pc;
        }
    }

    const int lane = tid & 63;
    const int wid = tid >> 6;          // 0..7
    const int lrow = lane & 15;
    const int hi = lane >> 4;          // 0..3
    const int rstrip = wid & 3;        // row-strip (16 rows)
    const int nb = (wid >> 2) * 64;    // col base (4 tiles of 16)
    const int arow = rstrip * 16 + lrow;

    float b1v[4], b2v[4];
#pragma unroll
    for (int tt = 0; tt < 4; ++tt) {
        int j = nb + tt * 16 + lrow;
        b1v[tt] = FBF ? bf2f(((const u16*)b1)[j]) : ((const float*)b1)[j];
        b2v[tt] = FBF ? bf2f(((const u16*)b2)[j]) : ((const float*)b2)[j];
    }

    // LN phase params
    const int cg = tid & 31;
    const int rg = tid >> 5;
    const int r0 = rg * 4;
    float gv[4], bev[4];
    if (FBF) {
        uint2 pg = ((const uint2*)gamma)[cg];
        uint2 pe = ((const uint2*)beta)[cg];
        gv[0] = bf2f((u16)(pg.x & 0xffffu)); gv[1] = bf2f((u16)(pg.x >> 16));
        gv[2] = bf2f((u16)(pg.y & 0xffffu)); gv[3] = bf2f((u16)(pg.y >> 16));
        bev[0] = bf2f((u16)(pe.x & 0xffffu)); bev[1] = bf2f((u16)(pe.x >> 16));
        bev[2] = bf2f((u16)(pe.y & 0xffffu)); bev[3] = bf2f((u16)(pe.y >> 16));
    } else {
        float4 t3 = ((const float4*)gamma)[cg];
        float4 t4 = ((const float4*)beta)[cg];
        gv[0] = t3.x; gv[1] = t3.y; gv[2] = t3.z; gv[3] = t3.w;
        bev[0] = t4.x; bev[1] = t4.y; bev[2] = t4.z; bev[3] = t4.w;
    }

    for (int t = blockIdx.x; t < NTM; t += gridDim.x) {
        const int row0 = t * TRM;
        __syncthreads();  // prev iteration fully done
        // ---- stage z tile -> bf16 swizzled LDS ----
        if (ZBF) {
#pragma unroll
            for (int q = 0; q < 2; ++q) {
                int u = tid + q * 512;           // 1024 units
                int row = u >> 4, cu = u & 15;
                int grow = row0 + row;
                uint4 p = {0u, 0u, 0u, 0u};
                if (grow < NN) p = ((const uint4*)zv)[(size_t)grow * 16 + cu];
                *(uint4*)(ztc + row * 256 + ((cu ^ (row & 7)) << 4)) = p;
            }
        } else {
#pragma unroll
            for (int q = 0; q < 2; ++q) {
                int u = tid + q * 512;
                int row = u >> 4, cu = u & 15;
                int grow = row0 + row;
                float4 a0 = {0.f, 0.f, 0.f, 0.f}, a1 = {0.f, 0.f, 0.f, 0.f};
                if (grow < NN) {
                    a0 = ((const float4*)zv)[(size_t)grow * 32 + cu * 2 + 0];
                    a1 = ((const float4*)zv)[(size_t)grow * 32 + cu * 2 + 1];
                }
                uint4 p;
                p.x = (u32)f2bf(a0.x) | ((u32)f2bf(a0.y) << 16);
                p.y = (u32)f2bf(a0.z) | ((u32)f2bf(a0.w) << 16);
                p.z = (u32)f2bf(a1.x) | ((u32)f2bf(a1.y) << 16);
                p.w = (u32)f2bf(a1.z) | ((u32)f2bf(a1.w) << 16);
                *(uint4*)(ztc + row * 256 + ((cu ^ (row & 7)) << 4)) = p;
            }
        }
        __syncthreads();

        f32x4 acc[4];
        // ---- layer 1: h1 = relu(z @ W1^T + b1) ----
#pragma unroll
        for (int tt = 0; tt < 4; ++tt)
            acc[tt] = (f32x4){b1v[tt], b1v[tt], b1v[tt], b1v[tt]};
#pragma unroll
        for (int c = 0; c < 4; ++c) {
            bf16x8 af = *(const bf16x8*)(ztc + arow * 256 + (((c * 4 + hi) ^ (arow & 7)) << 4));
#pragma unroll
            for (int tt = 0; tt < 4; ++tt) {
                int brow = nb + tt * 16 + lrow;
                bf16x8 bfv = *(const bf16x8*)(w1c + brow * 256 + (((c * 4 + hi) ^ (brow & 7)) << 4));
                acc[tt] = __builtin_amdgcn_mfma_f32_16x16x32_bf16(af, bfv, acc[tt], 0, 0, 0);
            }
        }
        // epilogue 1: relu -> bf16 -> s_h1 (swizzled scalar writes)
#pragma unroll
        for (int tt = 0; tt < 4; ++tt) {
            int j = nb + tt * 16 + lrow;
            int jb2 = j * 2;
            int unit = jb2 >> 4, within = jb2 & 15;
#pragma unroll
            for (int qq = 0; qq < 4; ++qq) {
                int row = rstrip * 16 + hi * 4 + qq;
                u16 hb = f2bf(fmaxf(acc[tt][qq], 0.f));
                *(u16*)(h1c + row * 256 + ((unit ^ (row & 7)) << 4) + within) = hb;
            }
        }
        __syncthreads();
        // ---- layer 2: h2 = relu(h1 @ W2^T + b2) ----
#pragma unroll
        for (int tt = 0; tt < 4; ++tt)
            acc[tt] = (f32x4){b2v[tt], b2v[tt], b2v[tt], b2v[tt]};
#pragma unroll
        for (int c = 0; c < 4; ++c) {
            bf16x8 af = *(const bf16x8*)(h1c + arow * 256 + (((c * 4 + hi) ^ (arow & 7)) << 4));
#pragma unroll
            for (int tt = 0; tt < 4; ++tt) {
                int brow = nb + tt * 16 + lrow;
                bf16x8 bfv = *(const bf16x8*)(w2c + brow * 256 + (((c * 4 + hi) ^ (brow & 7)) << 4));
                acc[tt] = __builtin_amdgcn_mfma_f32_16x16x32_bf16(af, bfv, acc[tt], 0, 0, 0);
            }
        }
        // epilogue 2: relu -> f32 s_h2
#pragma unroll
        for (int tt = 0; tt < 4; ++tt) {
            int j = nb + tt * 16 + lrow;
#pragma unroll
            for (int qq = 0; qq < 4; ++qq) {
                int row = rstrip * 16 + hi * 4 + qq;
                s_h2[row * 132 + j] = fmaxf(acc[tt][qq], 0.f);
            }
        }
        __syncthreads();
        // ---- LN + skip + store ----
#pragma unroll
        for (int r = 0; r < 4; ++r) {
            const float* hp = &s_h2[(r0 + r) * 132 + 4 * cg];
            float h0 = hp[0], h1 = hp[1], h2 = hp[2], h3 = hp[3];
            float s1 = h0 + h1 + h2 + h3;
            float s2 = h0 * h0 + h1 * h1 + h2 * h2 + h3 * h3;
#pragma unroll
            for (int m = 1; m <= 16; m <<= 1) {
                s1 += __shfl_xor(s1, m);
                s2 += __shfl_xor(s2, m);
            }
            float mean = s1 * (1.0f / DD);
            float var = s2 * (1.0f / DD) - mean * mean;
            float rs = rsqrtf(var + 1e-5f);
            int grow = row0 + r0 + r;
            if (grow < NN) {
                float xi[4];
                if (FBF) {
                    uint2 px = ((const uint2*)((const u16*)x0 + (size_t)grow * DD))[cg];
                    xi[0] = bf2f((u16)(px.x & 0xffffu)); xi[1] = bf2f((u16)(px.x >> 16));
                    xi[2] = bf2f((u16)(px.y & 0xffffu)); xi[3] = bf2f((u16)(px.y >> 16));
                } else {
                    float4 px = ((const float4*)((const float*)x0 + (size_t)grow * DD))[cg];
                    xi[0] = px.x; xi[1] = px.y; xi[2] = px.z; xi[3] = px.w;
                }
                float4 o;
                o.x = (h0 - mean) * rs * gv[0] + bev[0] + xi[0];
                o.y = (h1 - mean) * rs * gv[1] + bev[1] + xi[1];
                o.z = (h2 - mean) * rs * gv[2] + bev[2] + xi[2];
                o.w = (h3 - mean) * rs * gv[3] + bev[3] + xi[3];
                ((float4*)(out + (size_t)grow * DD))[cg] = o;
            }
        }
    }
}

extern "C" void kernel_launch(void* const* d_in, const int* in_sizes, int n_in,
                              void* d_out, int out_size, void* d_ws, size_t ws_size,
                              hipStream_t stream) {
    const void* x = d_in[0];
    const int* ei = (const int*)d_in[1];
    const void* W1 = d_in[2];
    const void* b1 = d_in[3];
    const void* W2 = d_in[4];
    const void* b2 = d_in[5];
    const void* eta = d_in[6];
    const void* gamma = d_in[7];
    const void* beta = d_in[8];
    float* out = (float*)d_out;

    // workspace layout (256B aligned). CSR path packs xb+zb (bf16, 12.8MB
    // each) into the 25.6MB z region; fallback uses it as one f32 z.
    const size_t FLAGS_OFF = 0;
    const size_t PART_OFF = 64;
    const size_t Z_OFF = 256;
    const size_t ZB = (size_t)NN * DD * sizeof(float);   // 25,600,000
    const size_t XB_OFF = Z_OFF;                          // bf16 x copy
    const size_t ZBF_OFF = Z_OFF + (size_t)NN * DD * 2;   // bf16 z
    const size_t DEG_OFF = Z_OFF + ZB;
    const size_t DEGB = 200192;
    const size_t RS_OFF = DEG_OFF + DEGB;
    const size_t RSB = 200448;
    const size_t BS_OFF = RS_OFF + RSB;
    const size_t BSB = (size_t)NE * sizeof(u16);         // 1,600,000 (u16 entries)
    const size_t RK_OFF = BS_OFF + BSB;
    const size_t RKB = (size_t)NE * sizeof(u16);         // 1,600,000 (u16 ranks)
    const size_t TOT = RK_OFF + RKB;                     // 29,200,896 (== proven r4-7 size)

    if (ws_size < Z_OFF + ZB) return;
    int* flags = (int*)((char*)d_ws + FLAGS_OFF);
    u32* partials = (u32*)((char*)d_ws + PART_OFF);

    gin_detect<<<1, 64, 0, stream>>>((const u32*)x, (const u32*)ei, flags);

    if (ws_size >= TOT) {
        u32* xb = (u32*)((char*)d_ws + XB_OFF);
        u32* zb = (u32*)((char*)d_ws + ZBF_OFF);
        u32* deg = (u32*)((char*)d_ws + DEG_OFF);
        u32* row_start = (u32*)((char*)d_ws + RS_OFF);
        u16* bs = (u16*)((char*)d_ws + BS_OFF);
        u16* rank = (u16*)((char*)d_ws + RK_OFF);
        gin_tobf<<<(NN * DD / 8 + 255) / 256, 256, 0, stream>>>(x, (uint4*)xb, flags);
        gin_zero<<<(NN + 255) / 256, 256, 0, stream>>>(deg);
        gin_hist<<<(NE + 255) / 256, 256, 0, stream>>>(ei, deg, rank, flags);
        gin_scan1<<<NSB, 1024, 0, stream>>>(deg, partials);
        gin_scan2<<<1, 64, 0, stream>>>(partials);
        gin_scan3<<<NSB, 1024, 0, stream>>>(deg, partials, row_start);
        gin_fill<<<(NE + 255) / 256, 256, 0, stream>>>(ei, row_start, rank, bs, flags);
        gin_gather<<<(NN + 3) / 4, 256, 0, stream>>>(xb, bs, row_start, deg, eta, zb, flags);
        gin_mlp<0, 1><<<256, 512, 0, stream>>>(zb, x, W1, b1, W2, b2, gamma, beta, out, flags);
        gin_mlp<1, 1><<<256, 512, 0, stream>>>(zb, x, W1, b1, W2, b2, gamma, beta, out, flags);
    } else {
        float* z = (float*)((char*)d_ws + Z_OFF);
        gin_init<<<(NN * DD / 8 + 255) / 256, 256, 0, stream>>>(x, eta, z, flags);
        gin_scatter<<<NE / 4, 256, 0, stream>>>(x, ei, z, flags);
        gin_mlp<0, 0><<<256, 512, 0, stream>>>(z, x, W1, b1, W2, b2, gamma, beta, out, flags);
        gin_mlp<1, 0><<<256, 512, 0, stream>>>(z, x, W1, b1, W2, b2, gamma, beta, out, flags);
    }
}

// Round 12
// 136.742 us; speedup vs baseline: 9.0659x; 1.0935x over previous
//
#include <hip/hip_runtime.h>

#define NN 50000
#define NE 800000
#define DD 128

typedef unsigned int u32;
typedef unsigned short u16;
typedef unsigned long long u64;
typedef __attribute__((ext_vector_type(8))) short bf16x8;
typedef __attribute__((ext_vector_type(4))) float f32x4;

__device__ __forceinline__ float bf2f(u16 u) {
    union { float f; u32 i; } v; v.i = ((u32)u) << 16; return v.f;
}
__device__ __forceinline__ u16 f2bf(float f) {
    u32 x = __float_as_uint(f);
    x += 0x7fffu + ((x >> 16) & 1u);
    return (u16)(x >> 16);
}

// ---------------- K0: dtype detect ----------------
__global__ __launch_bounds__(64) void gin_detect(const u32* __restrict__ xw,
                                                 const u32* __restrict__ ew,
                                                 int* __restrict__ flags) {
    int lane = threadIdx.x;
    u32 w = xw[lane];
    u32 e8 = (w >> 7) & 0xFFu;
    bool bfOK = (e8 >= 100u && e8 <= 150u) || ((w & 0xFFFFu) == 0u);
    u64 m1 = __ballot(bfOK);
    bool oddZero = (ew[2 * lane + 1] == 0u);
    u64 m2 = __ballot(oddZero);
    if (lane == 0) {
        flags[0] = (__popcll(m1) >= 56) ? 1 : 0;
        flags[1] = (__popcll(m2) >= 60) ? 1 : 0;
    }
}

// ---------------- x -> bf16 workspace copy ----------------
__global__ __launch_bounds__(256) void gin_tobf(const void* __restrict__ xv,
                                                uint4* __restrict__ xb,
                                                const int* __restrict__ flags) {
    int i = blockIdx.x * 256 + threadIdx.x;     // 16B unit (8 bf16)
    const int nu = NN * DD / 8;
    if (i >= nu) return;
    if (flags[0]) {
        xb[i] = ((const uint4*)xv)[i];
    } else {
        float4 a0 = ((const float4*)xv)[2 * i + 0];
        float4 a1 = ((const float4*)xv)[2 * i + 1];
        uint4 p;
        p.x = (u32)f2bf(a0.x) | ((u32)f2bf(a0.y) << 16);
        p.y = (u32)f2bf(a0.z) | ((u32)f2bf(a0.w) << 16);
        p.z = (u32)f2bf(a1.x) | ((u32)f2bf(a1.y) << 16);
        p.w = (u32)f2bf(a1.z) | ((u32)f2bf(a1.w) << 16);
        xb[i] = p;
    }
}

// ---------------- CSR build ----------------
__global__ __launch_bounds__(256) void gin_zero(u32* __restrict__ deg) {
    int i = blockIdx.x * 256 + threadIdx.x;
    if (i < NN) deg[i] = 0u;
}

// hist: count degree AND record each edge's arrival rank (u16).
__global__ __launch_bounds__(256) void gin_hist(const int* __restrict__ ei,
                                                u32* __restrict__ deg,
                                                u16* __restrict__ rank,
                                                const int* __restrict__ flags) {
    int e = blockIdx.x * 256 + threadIdx.x;
    if (e >= NE) return;
    int d = flags[1] ? ei[2 * (NE + e)] : ei[NE + e];
    rank[e] = (u16)atomicAdd(&deg[d], 1u);
}

#define SCAN_CHUNK 2048
#define NSB ((NN + SCAN_CHUNK - 1) / SCAN_CHUNK)   // 25 blocks

__global__ __launch_bounds__(1024) void gin_scan1(const u32* __restrict__ deg,
                                                  u32* __restrict__ partials) {
    __shared__ u32 red[1024];
    int tid = threadIdx.x;
    int base = blockIdx.x * SCAN_CHUNK + tid * 2;
    u32 a = (base < NN) ? deg[base] : 0u;
    u32 b = (base + 1 < NN) ? deg[base + 1] : 0u;
    red[tid] = a + b;
    __syncthreads();
    for (int off = 512; off > 0; off >>= 1) {
        if (tid < off) red[tid] += red[tid + off];
        __syncthreads();
    }
    if (tid == 0) partials[blockIdx.x] = red[0];
}

__global__ __launch_bounds__(64) void gin_scan2(u32* __restrict__ partials) {
    int lane = threadIdx.x;
    u32 orig = (lane < NSB) ? partials[lane] : 0u;
    u32 v = orig;
    for (int off = 1; off < 64; off <<= 1) {
        u32 t = __shfl_up(v, off);
        if (lane >= off) v += t;
    }
    if (lane < NSB) partials[lane] = v - orig;  // exclusive
}

__global__ __launch_bounds__(1024) void gin_scan3(const u32* __restrict__ deg,
                                                  const u32* __restrict__ partials,
                                                  u32* __restrict__ row_start) {
    __shared__ u32 sc[1024];
    int tid = threadIdx.x;
    int base = blockIdx.x * SCAN_CHUNK + tid * 2;
    u32 a = (base < NN) ? deg[base] : 0u;
    u32 b = (base + 1 < NN) ? deg[base + 1] : 0u;
    u32 ts = a + b;
    sc[tid] = ts;
    __syncthreads();
    for (int off = 1; off < 1024; off <<= 1) {
        u32 v = (tid >= off) ? sc[tid - off] : 0u;
        __syncthreads();
        sc[tid] += v;
        __syncthreads();
    }
    u32 excl = sc[tid] - ts + partials[blockIdx.x];
    if (base < NN) row_start[base] = excl;
    if (base + 1 < NN) row_start[base + 1] = excl + a;
}

// fill: atomic-free. pos = row_start[dst] + rank[e].
__global__ __launch_bounds__(256) void gin_fill(const int* __restrict__ ei,
                                                const u32* __restrict__ row_start,
                                                const u16* __restrict__ rank,
                                                u16* __restrict__ bs,
                                                const int* __restrict__ flags) {
    int e = blockIdx.x * 256 + threadIdx.x;
    if (e >= NE) return;
    int s, d;
    if (flags[1]) { s = ei[2 * e]; d = ei[2 * (NE + e)]; }
    else          { s = ei[e];     d = ei[NE + e]; }
    bs[row_start[d] + (u32)rank[e]] = (u16)s;
}

// ---------------- gather-sum (+init), bf16 rows, 4-edge unroll ----------------
__global__ __launch_bounds__(256) void gin_gather(const u32* __restrict__ xb,
                                                  const u16* __restrict__ bs,
                                                  const u32* __restrict__ row_start,
                                                  const u32* __restrict__ deg,
                                                  const void* __restrict__ etav,
                                                  u32* __restrict__ zb,
                                                  const int* __restrict__ flags) {
    int node = blockIdx.x * 4 + (threadIdx.x >> 6);
    if (node >= NN) return;
    const int lane = threadIdx.x & 63;
    float s = 1.0f + (flags[0] ? bf2f(((const u16*)etav)[0]) : ((const float*)etav)[0]);
    u32 p = xb[(size_t)node * 64 + lane];
    float ax = bf2f((u16)(p & 0xffffu)) * s;
    float ay = bf2f((u16)(p >> 16)) * s;
    u32 jb = row_start[node], je = jb + deg[node];
    u32 j = jb;
    // 4-edge unroll: 4 broadcast index loads, then 4 coalesced row loads in
    // flight (halves the serial latency chain vs 2-unroll).
    for (; j + 3 < je; j += 4) {
        u32 s0 = bs[j], s1 = bs[j + 1], s2 = bs[j + 2], s3 = bs[j + 3];
        u32 p0 = xb[(size_t)s0 * 64 + lane];
        u32 p1 = xb[(size_t)s1 * 64 + lane];
        u32 p2 = xb[(size_t)s2 * 64 + lane];
        u32 p3 = xb[(size_t)s3 * 64 + lane];
        ax += bf2f((u16)(p0 & 0xffffu)) + bf2f((u16)(p1 & 0xffffu))
            + bf2f((u16)(p2 & 0xffffu)) + bf2f((u16)(p3 & 0xffffu));
        ay += bf2f((u16)(p0 >> 16)) + bf2f((u16)(p1 >> 16))
            + bf2f((u16)(p2 >> 16)) + bf2f((u16)(p3 >> 16));
    }
    for (; j < je; ++j) {
        u32 p0 = xb[(size_t)bs[j] * 64 + lane];
        ax += bf2f((u16)(p0 & 0xffffu));
        ay += bf2f((u16)(p0 >> 16));
    }
    zb[(size_t)node * 64 + lane] = (u32)f2bf(ax) | ((u32)f2bf(ay) << 16);
}

// ---------------- fallback: init + atomic scatter (f32 z) ----------------
__global__ __launch_bounds__(256) void gin_init(const void* __restrict__ xv,
                                                const void* __restrict__ etav,
                                                float* __restrict__ z,
                                                const int* __restrict__ flags) {
    int i = blockIdx.x * 256 + threadIdx.x;
    const int n8 = NN * DD / 8;
    if (i >= n8) return;
    const int fbf = flags[0];
    float s = 1.0f + (fbf ? bf2f(((const u16*)etav)[0]) : ((const float*)etav)[0]);
    float4 a, b;
    if (fbf) {
        uint4 p = ((const uint4*)xv)[i];
        a.x = bf2f((u16)(p.x & 0xffffu)); a.y = bf2f((u16)(p.x >> 16));
        a.z = bf2f((u16)(p.y & 0xffffu)); a.w = bf2f((u16)(p.y >> 16));
        b.x = bf2f((u16)(p.z & 0xffffu)); b.y = bf2f((u16)(p.z >> 16));
        b.z = bf2f((u16)(p.w & 0xffffu)); b.w = bf2f((u16)(p.w >> 16));
    } else {
        a = ((const float4*)xv)[2 * i + 0];
        b = ((const float4*)xv)[2 * i + 1];
    }
    a.x *= s; a.y *= s; a.z *= s; a.w *= s;
    b.x *= s; b.y *= s; b.z *= s; b.w *= s;
    ((float4*)z)[2 * i + 0] = a;
    ((float4*)z)[2 * i + 1] = b;
}

__global__ __launch_bounds__(256) void gin_scatter(const void* __restrict__ xv,
                                                   const int* __restrict__ ei,
                                                   float* __restrict__ z,
                                                   const int* __restrict__ flags) {
    int e = blockIdx.x * 4 + (threadIdx.x >> 6);
    if (e >= NE) return;
    const int fbf = flags[0];
    const int f64 = flags[1];
    int lane = threadIdx.x & 63;
    int s, d;
    if (f64) { s = ei[2 * e]; d = ei[2 * (NE + e)]; }
    else     { s = ei[e];     d = ei[NE + e]; }
    float v0, v1;
    if (fbf) {
        u32 p = ((const u32*)((const u16*)xv + (size_t)s * DD))[lane];
        v0 = bf2f((u16)(p & 0xffffu));
        v1 = bf2f((u16)(p >> 16));
    } else {
        float2 p = ((const float2*)((const float*)xv + (size_t)s * DD))[lane];
        v0 = p.x; v1 = p.y;
    }
    float* dst = z + (size_t)d * DD + 2 * lane;
    atomicAdd(dst + 0, v0);
    atomicAdd(dst + 1, v1);
}

// ---------------- MFMA MLP + LN + skip ----------------
// bf16 MFMA (16x16x32), f32 accumulate. C/D: col=lane&15, row=(lane>>4)*4+reg.
// LDS 256B-row bf16 tiles, 16B-unit XOR swizzle (unit ^= row&7), write+read.
// ZBF=1: z AND skip-x are bf16 (xskip points at xb). ZBF=0: f32 z + f32/bf16 x.
#define TRM 64
#define NTM ((NN + TRM - 1) / TRM)

template <int FBF, int ZBF>
__global__ __launch_bounds__(512, 1) void gin_mlp(
    const void* __restrict__ zv, const void* __restrict__ xskip,
    const void* __restrict__ W1, const void* __restrict__ b1,
    const void* __restrict__ W2, const void* __restrict__ b2,
    const void* __restrict__ gamma, const void* __restrict__ beta,
    float* __restrict__ out, const int* __restrict__ flags) {
    if (flags[0] != FBF) return;  // wave-uniform early exit (dud variant)

    __shared__ short s_w1[DD * DD];    // 32 KB bf16, row-major, swizzled
    __shared__ short s_w2[DD * DD];    // 32 KB
    __shared__ short s_zt[TRM * DD];   // 16 KB
    __shared__ short s_h1[TRM * DD];   // 16 KB
    __shared__ float s_h2[TRM * 132];  // 33 KB

    const int tid = threadIdx.x;
    char* w1c = (char*)s_w1;
    char* w2c = (char*)s_w2;
    char* ztc = (char*)s_zt;
    char* h1c = (char*)s_h1;

    // ---- stage weights -> bf16 LDS (once per block) ----
    if (FBF) {
#pragma unroll
        for (int q = 0; q < 4; ++q) {
            int u = tid + q * 512;
            int row = u >> 4, cu = u & 15;
            uint4 a = ((const uint4*)W1)[u];
            uint4 c = ((const uint4*)W2)[u];
            int off = row * 256 + ((cu ^ (row & 7)) << 4);
            *(uint4*)(w1c + off) = a;
            *(uint4*)(w2c + off) = c;
        }
    } else {
#pragma unroll
        for (int q = 0; q < 4; ++q) {
            int u = tid + q * 512;
            int row = u >> 4, cu = u & 15;
            float4 a0 = ((const float4*)W1)[u * 2 + 0];
            float4 a1 = ((const float4*)W1)[u * 2 + 1];
            float4 c0 = ((const float4*)W2)[u * 2 + 0];
            float4 c1 = ((const float4*)W2)[u * 2 + 1];
            uint4 pa, pc;
            pa.x = (u32)f2bf(a0.x) | ((u32)f2bf(a0.y) << 16);
            pa.y = (u32)f2bf(a0.z) | ((u32)f2bf(a0.w) << 16);
            pa.z = (u32)f2bf(a1.x) | ((u32)f2bf(a1.y) << 16);
            pa.w = (u32)f2bf(a1.z) | ((u32)f2bf(a1.w) << 16);
            pc.x = (u32)f2bf(c0.x) | ((u32)f2bf(c0.y) << 16);
            pc.y = (u32)f2bf(c0.z) | ((u32)f2bf(c0.w) << 16);
            pc.z = (u32)f2bf(c1.x) | ((u32)f2bf(c1.y) << 16);
            pc.w = (u32)f2bf(c1.z) | ((u32)f2bf(c1.w) << 16);
            int off = row * 256 + ((cu ^ (row & 7)) << 4);
            *(uint4*)(w1c + off) = pa;
            *(uint4*)(w2c + off) = pc;
        }
    }

    const int lane = tid & 63;
    const int wid = tid >> 6;
    const int lrow = lane & 15;
    const int hi = lane >> 4;
    const int rstrip = wid & 3;
    const int nb = (wid >> 2) * 64;
    const int arow = rstrip * 16 + lrow;

    float b1v[4], b2v[4];
#pragma unroll
    for (int tt = 0; tt < 4; ++tt) {
        int j = nb + tt * 16 + lrow;
        b1v[tt] = FBF ? bf2f(((const u16*)b1)[j]) : ((const float*)b1)[j];
        b2v[tt] = FBF ? bf2f(((const u16*)b2)[j]) : ((const float*)b2)[j];
    }

    const int cg = tid & 31;
    const int rg = tid >> 5;
    const int r0 = rg * 4;
    float gv[4], bev[4];
    if (FBF) {
        uint2 pg = ((const uint2*)gamma)[cg];
        uint2 pe = ((const uint2*)beta)[cg];
        gv[0] = bf2f((u16)(pg.x & 0xffffu)); gv[1] = bf2f((u16)(pg.x >> 16));
        gv[2] = bf2f((u16)(pg.y & 0xffffu)); gv[3] = bf2f((u16)(pg.y >> 16));
        bev[0] = bf2f((u16)(pe.x & 0xffffu)); bev[1] = bf2f((u16)(pe.x >> 16));
        bev[2] = bf2f((u16)(pe.y & 0xffffu)); bev[3] = bf2f((u16)(pe.y >> 16));
    } else {
        float4 t3 = ((const float4*)gamma)[cg];
        float4 t4 = ((const float4*)beta)[cg];
        gv[0] = t3.x; gv[1] = t3.y; gv[2] = t3.z; gv[3] = t3.w;
        bev[0] = t4.x; bev[1] = t4.y; bev[2] = t4.z; bev[3] = t4.w;
    }

    for (int t = blockIdx.x; t < NTM; t += gridDim.x) {
        const int row0 = t * TRM;
        __syncthreads();
        // ---- stage z tile -> bf16 swizzled LDS ----
        if (ZBF) {
#pragma unroll
            for (int q = 0; q < 2; ++q) {
                int u = tid + q * 512;
                int row = u >> 4, cu = u & 15;
                int grow = row0 + row;
                uint4 p = {0u, 0u, 0u, 0u};
                if (grow < NN) p = ((const uint4*)zv)[(size_t)grow * 16 + cu];
                *(uint4*)(ztc + row * 256 + ((cu ^ (row & 7)) << 4)) = p;
            }
        } else {
#pragma unroll
            for (int q = 0; q < 2; ++q) {
                int u = tid + q * 512;
                int row = u >> 4, cu = u & 15;
                int grow = row0 + row;
                float4 a0 = {0.f, 0.f, 0.f, 0.f}, a1 = {0.f, 0.f, 0.f, 0.f};
                if (grow < NN) {
                    a0 = ((const float4*)zv)[(size_t)grow * 32 + cu * 2 + 0];
                    a1 = ((const float4*)zv)[(size_t)grow * 32 + cu * 2 + 1];
                }
                uint4 p;
                p.x = (u32)f2bf(a0.x) | ((u32)f2bf(a0.y) << 16);
                p.y = (u32)f2bf(a0.z) | ((u32)f2bf(a0.w) << 16);
                p.z = (u32)f2bf(a1.x) | ((u32)f2bf(a1.y) << 16);
                p.w = (u32)f2bf(a1.z) | ((u32)f2bf(a1.w) << 16);
                *(uint4*)(ztc + row * 256 + ((cu ^ (row & 7)) << 4)) = p;
            }
        }
        __syncthreads();

        f32x4 acc[4];
        // ---- layer 1 ----
#pragma unroll
        for (int tt = 0; tt < 4; ++tt)
            acc[tt] = (f32x4){b1v[tt], b1v[tt], b1v[tt], b1v[tt]};
#pragma unroll
        for (int c = 0; c < 4; ++c) {
            bf16x8 af = *(const bf16x8*)(ztc + arow * 256 + (((c * 4 + hi) ^ (arow & 7)) << 4));
#pragma unroll
            for (int tt = 0; tt < 4; ++tt) {
                int brow = nb + tt * 16 + lrow;
                bf16x8 bfv = *(const bf16x8*)(w1c + brow * 256 + (((c * 4 + hi) ^ (brow & 7)) << 4));
                acc[tt] = __builtin_amdgcn_mfma_f32_16x16x32_bf16(af, bfv, acc[tt], 0, 0, 0);
            }
        }
#pragma unroll
        for (int tt = 0; tt < 4; ++tt) {
            int j = nb + tt * 16 + lrow;
            int jb2 = j * 2;
            int unit = jb2 >> 4, within = jb2 & 15;
#pragma unroll
            for (int qq = 0; qq < 4; ++qq) {
                int row = rstrip * 16 + hi * 4 + qq;
                u16 hb = f2bf(fmaxf(acc[tt][qq], 0.f));
                *(u16*)(h1c + row * 256 + ((unit ^ (row & 7)) << 4) + within) = hb;
            }
        }
        __syncthreads();
        // ---- layer 2 ----
#pragma unroll
        for (int tt = 0; tt < 4; ++tt)
            acc[tt] = (f32x4){b2v[tt], b2v[tt], b2v[tt], b2v[tt]};
#pragma unroll
        for (int c = 0; c < 4; ++c) {
            bf16x8 af = *(const bf16x8*)(h1c + arow * 256 + (((c * 4 + hi) ^ (arow & 7)) << 4));
#pragma unroll
            for (int tt = 0; tt < 4; ++tt) {
                int brow = nb + tt * 16 + lrow;
                bf16x8 bfv = *(const bf16x8*)(w2c + brow * 256 + (((c * 4 + hi) ^ (brow & 7)) << 4));
                acc[tt] = __builtin_amdgcn_mfma_f32_16x16x32_bf16(af, bfv, acc[tt], 0, 0, 0);
            }
        }
#pragma unroll
        for (int tt = 0; tt < 4; ++tt) {
            int j = nb + tt * 16 + lrow;
#pragma unroll
            for (int qq = 0; qq < 4; ++qq) {
                int row = rstrip * 16 + hi * 4 + qq;
                s_h2[row * 132 + j] = fmaxf(acc[tt][qq], 0.f);
            }
        }
        __syncthreads();
        // ---- LN + skip + store ----
#pragma unroll
        for (int r = 0; r < 4; ++r) {
            const float* hp = &s_h2[(r0 + r) * 132 + 4 * cg];
            float h0 = hp[0], h1 = hp[1], h2 = hp[2], h3 = hp[3];
            float s1 = h0 + h1 + h2 + h3;
            float s2 = h0 * h0 + h1 * h1 + h2 * h2 + h3 * h3;
#pragma unroll
            for (int m = 1; m <= 16; m <<= 1) {
                s1 += __shfl_xor(s1, m);
                s2 += __shfl_xor(s2, m);
            }
            float mean = s1 * (1.0f / DD);
            float var = s2 * (1.0f / DD) - mean * mean;
            float rs = rsqrtf(var + 1e-5f);
            int grow = row0 + r0 + r;
            if (grow < NN) {
                float xi[4];
                if (FBF || ZBF) {   // bf16 skip source (xb in CSR path)
                    uint2 px = ((const uint2*)((const u16*)xskip + (size_t)grow * DD))[cg];
                    xi[0] = bf2f((u16)(px.x & 0xffffu)); xi[1] = bf2f((u16)(px.x >> 16));
                    xi[2] = bf2f((u16)(px.y & 0xffffu)); xi[3] = bf2f((u16)(px.y >> 16));
                } else {
                    float4 px = ((const float4*)((const float*)xskip + (size_t)grow * DD))[cg];
                    xi[0] = px.x; xi[1] = px.y; xi[2] = px.z; xi[3] = px.w;
                }
                float4 o;
                o.x = (h0 - mean) * rs * gv[0] + bev[0] + xi[0];
                o.y = (h1 - mean) * rs * gv[1] + bev[1] + xi[1];
                o.z = (h2 - mean) * rs * gv[2] + bev[2] + xi[2];
                o.w = (h3 - mean) * rs * gv[3] + bev[3] + xi[3];
                ((float4*)(out + (size_t)grow * DD))[cg] = o;
            }
        }
    }
}

extern "C" void kernel_launch(void* const* d_in, const int* in_sizes, int n_in,
                              void* d_out, int out_size, void* d_ws, size_t ws_size,
                              hipStream_t stream) {
    const void* x = d_in[0];
    const int* ei = (const int*)d_in[1];
    const void* W1 = d_in[2];
    const void* b1 = d_in[3];
    const void* W2 = d_in[4];
    const void* b2 = d_in[5];
    const void* eta = d_in[6];
    const void* gamma = d_in[7];
    const void* beta = d_in[8];
    float* out = (float*)d_out;

    const size_t FLAGS_OFF = 0;
    const size_t PART_OFF = 64;
    const size_t Z_OFF = 256;
    const size_t ZB = (size_t)NN * DD * sizeof(float);   // 25,600,000
    const size_t XB_OFF = Z_OFF;                          // bf16 x copy
    const size_t ZBF_OFF = Z_OFF + (size_t)NN * DD * 2;   // bf16 z
    const size_t DEG_OFF = Z_OFF + ZB;
    const size_t DEGB = 200192;
    const size_t RS_OFF = DEG_OFF + DEGB;
    const size_t RSB = 200448;
    const size_t BS_OFF = RS_OFF + RSB;
    const size_t BSB = (size_t)NE * sizeof(u16);         // 1,600,000
    const size_t RK_OFF = BS_OFF + BSB;
    const size_t RKB = (size_t)NE * sizeof(u16);         // 1,600,000
    const size_t TOT = RK_OFF + RKB;                     // 29,200,896

    if (ws_size < Z_OFF + ZB) return;
    int* flags = (int*)((char*)d_ws + FLAGS_OFF);
    u32* partials = (u32*)((char*)d_ws + PART_OFF);

    gin_detect<<<1, 64, 0, stream>>>((const u32*)x, (const u32*)ei, flags);

    if (ws_size >= TOT) {
        u32* xb = (u32*)((char*)d_ws + XB_OFF);
        u32* zb = (u32*)((char*)d_ws + ZBF_OFF);
        u32* deg = (u32*)((char*)d_ws + DEG_OFF);
        u32* row_start = (u32*)((char*)d_ws + RS_OFF);
        u16* bs = (u16*)((char*)d_ws + BS_OFF);
        u16* rank = (u16*)((char*)d_ws + RK_OFF);
        gin_tobf<<<(NN * DD / 8 + 255) / 256, 256, 0, stream>>>(x, (uint4*)xb, flags);
        gin_zero<<<(NN + 255) / 256, 256, 0, stream>>>(deg);
        gin_hist<<<(NE + 255) / 256, 256, 0, stream>>>(ei, deg, rank, flags);
        gin_scan1<<<NSB, 1024, 0, stream>>>(deg, partials);
        gin_scan2<<<1, 64, 0, stream>>>(partials);
        gin_scan3<<<NSB, 1024, 0, stream>>>(deg, partials, row_start);
        gin_fill<<<(NE + 255) / 256, 256, 0, stream>>>(ei, row_start, rank, bs, flags);
        gin_gather<<<(NN + 3) / 4, 256, 0, stream>>>(xb, bs, row_start, deg, eta, zb, flags);
        // skip-x read from xb (bf16, cache-warm) in both variants
        gin_mlp<0, 1><<<256, 512, 0, stream>>>(zb, xb, W1, b1, W2, b2, gamma, beta, out, flags);
        gin_mlp<1, 1><<<256, 512, 0, stream>>>(zb, xb, W1, b1, W2, b2, gamma, beta, out, flags);
    } else {
        float* z = (float*)((char*)d_ws + Z_OFF);
        gin_init<<<(NN * DD / 8 + 255) / 256, 256, 0, stream>>>(x, eta, z, flags);
        gin_scatter<<<NE / 4, 256, 0, stream>>>(x, ei, z, flags);
        gin_mlp<0, 0><<<256, 512, 0, stream>>>(z, x, W1, b1, W2, b2, gamma, beta, out, flags);
        gin_mlp<1, 0><<<256, 512, 0, stream>>>(z, x, W1, b1, W2, b2, gamma, beta, out, flags);
    }
}

// Round 13
// 128.042 us; speedup vs baseline: 9.6819x; 1.0680x over previous
//
#include <hip/hip_runtime.h>

#define NN 50000
#define NE 800000
#define DD 128

typedef unsigned int u32;
typedef unsigned short u16;
typedef unsigned long long u64;
typedef __attribute__((ext_vector_type(8))) short bf16x8;
typedef __attribute__((ext_vector_type(4))) float f32x4;

__device__ __forceinline__ float bf2f(u16 u) {
    union { float f; u32 i; } v; v.i = ((u32)u) << 16; return v.f;
}
__device__ __forceinline__ u16 f2bf(float f) {
    u32 x = __float_as_uint(f);
    x += 0x7fffu + ((x >> 16) & 1u);
    return (u16)(x >> 16);
}

// ---------------- K0: dtype detect ----------------
__global__ __launch_bounds__(64) void gin_detect(const u32* __restrict__ xw,
                                                 const u32* __restrict__ ew,
                                                 int* __restrict__ flags) {
    int lane = threadIdx.x;
    u32 w = xw[lane];
    u32 e8 = (w >> 7) & 0xFFu;
    bool bfOK = (e8 >= 100u && e8 <= 150u) || ((w & 0xFFFFu) == 0u);
    u64 m1 = __ballot(bfOK);
    bool oddZero = (ew[2 * lane + 1] == 0u);
    u64 m2 = __ballot(oddZero);
    if (lane == 0) {
        flags[0] = (__popcll(m1) >= 56) ? 1 : 0;
        flags[1] = (__popcll(m2) >= 60) ? 1 : 0;
    }
}

// ---------------- fused: x -> bf16 copy  +  deg zero ----------------
#define NB_TOBF ((NN * DD / 8) / 256)          // 3125 (exact)
#define NB_ZERO ((NN + 255) / 256)             // 196

__global__ __launch_bounds__(256) void gin_tobf_zero(const void* __restrict__ xv,
                                                     uint4* __restrict__ xb,
                                                     u32* __restrict__ deg,
                                                     const int* __restrict__ flags) {
    int b = blockIdx.x;
    int tid = threadIdx.x;
    if (b < NB_TOBF) {
        int i = b * 256 + tid;                 // 16B unit (8 bf16)
        if (flags[0]) {
            xb[i] = ((const uint4*)xv)[i];
        } else {
            float4 a0 = ((const float4*)xv)[2 * i + 0];
            float4 a1 = ((const float4*)xv)[2 * i + 1];
            uint4 p;
            p.x = (u32)f2bf(a0.x) | ((u32)f2bf(a0.y) << 16);
            p.y = (u32)f2bf(a0.z) | ((u32)f2bf(a0.w) << 16);
            p.z = (u32)f2bf(a1.x) | ((u32)f2bf(a1.y) << 16);
            p.w = (u32)f2bf(a1.z) | ((u32)f2bf(a1.w) << 16);
            xb[i] = p;
        }
    } else {
        int i = (b - NB_TOBF) * 256 + tid;
        if (i < NN) deg[i] = 0u;
    }
}

// hist: degree count + arrival rank (u16) + packed (s,d) u32 for fill.
__global__ __launch_bounds__(256) void gin_hist(const int* __restrict__ ei,
                                                u32* __restrict__ deg,
                                                u16* __restrict__ rank,
                                                u32* __restrict__ pck,
                                                const int* __restrict__ flags) {
    int e = blockIdx.x * 256 + threadIdx.x;
    if (e >= NE) return;
    int s, d;
    if (flags[1]) { s = ei[2 * e]; d = ei[2 * (NE + e)]; }
    else          { s = ei[e];     d = ei[NE + e]; }
    pck[e] = (u32)s | ((u32)d << 16);
    rank[e] = (u16)atomicAdd(&deg[d], 1u);
}

#define SCAN_CHUNK 2048
#define NSB ((NN + SCAN_CHUNK - 1) / SCAN_CHUNK)   // 25 blocks

__global__ __launch_bounds__(1024) void gin_scan1(const u32* __restrict__ deg,
                                                  u32* __restrict__ partials) {
    __shared__ u32 red[1024];
    int tid = threadIdx.x;
    int base = blockIdx.x * SCAN_CHUNK + tid * 2;
    u32 a = (base < NN) ? deg[base] : 0u;
    u32 b = (base + 1 < NN) ? deg[base + 1] : 0u;
    red[tid] = a + b;
    __syncthreads();
    for (int off = 512; off > 0; off >>= 1) {
        if (tid < off) red[tid] += red[tid + off];
        __syncthreads();
    }
    if (tid == 0) partials[blockIdx.x] = red[0];
}

// scan3: block-local scan + self-computed exclusive chunk base (absorbs scan2).
__global__ __launch_bounds__(1024) void gin_scan3(const u32* __restrict__ deg,
                                                  const u32* __restrict__ partials,
                                                  u32* __restrict__ row_start) {
    __shared__ u32 sc[1024];
    __shared__ u32 chunk_base;
    int tid = threadIdx.x;
    if (tid < 64) {
        u32 v = (tid < NSB && tid < blockIdx.x) ? partials[tid] : 0u;
#pragma unroll
        for (int m = 32; m > 0; m >>= 1) v += __shfl_xor(v, m);
        if (tid == 0) chunk_base = v;
    }
    int base = blockIdx.x * SCAN_CHUNK + tid * 2;
    u32 a = (base < NN) ? deg[base] : 0u;
    u32 b = (base + 1 < NN) ? deg[base + 1] : 0u;
    u32 ts = a + b;
    sc[tid] = ts;
    __syncthreads();
    for (int off = 1; off < 1024; off <<= 1) {
        u32 v = (tid >= off) ? sc[tid - off] : 0u;
        __syncthreads();
        sc[tid] += v;
        __syncthreads();
    }
    u32 excl = sc[tid] - ts + chunk_base;
    if (base < NN) row_start[base] = excl;
    if (base + 1 < NN) row_start[base + 1] = excl + a;
}

// fill: atomic-free, reads packed (s,d) + rank (no int64 ei re-read).
__global__ __launch_bounds__(256) void gin_fill(const u32* __restrict__ pck,
                                                const u32* __restrict__ row_start,
                                                const u16* __restrict__ rank,
                                                u16* __restrict__ bs) {
    int e = blockIdx.x * 256 + threadIdx.x;
    if (e >= NE) return;
    u32 p = pck[e];
    u32 s = p & 0xffffu, d = p >> 16;
    bs[row_start[d] + (u32)rank[e]] = (u16)s;
}

// ---------------- gather-sum (+init), bf16 rows, 8-edge unroll ----------------
__global__ __launch_bounds__(256) void gin_gather(const u32* __restrict__ xb,
                                                  const u16* __restrict__ bs,
                                                  const u32* __restrict__ row_start,
                                                  const u32* __restrict__ deg,
                                                  const void* __restrict__ etav,
                                                  u32* __restrict__ zb,
                                                  const int* __restrict__ flags) {
    int node = blockIdx.x * 4 + (threadIdx.x >> 6);
    if (node >= NN) return;
    const int lane = threadIdx.x & 63;
    float s = 1.0f + (flags[0] ? bf2f(((const u16*)etav)[0]) : ((const float*)etav)[0]);
    u32 p = xb[(size_t)node * 64 + lane];
    float ax = bf2f((u16)(p & 0xffffu)) * s;
    float ay = bf2f((u16)(p >> 16)) * s;
    u32 jb = row_start[node], je = jb + deg[node];
    u32 j = jb;
    // 8-edge unroll: 8 row loads in flight (latency-bound chain halved again).
    for (; j + 7 < je; j += 8) {
        u32 i0 = bs[j], i1 = bs[j + 1], i2 = bs[j + 2], i3 = bs[j + 3];
        u32 i4 = bs[j + 4], i5 = bs[j + 5], i6 = bs[j + 6], i7 = bs[j + 7];
        u32 p0 = xb[(size_t)i0 * 64 + lane];
        u32 p1 = xb[(size_t)i1 * 64 + lane];
        u32 p2 = xb[(size_t)i2 * 64 + lane];
        u32 p3 = xb[(size_t)i3 * 64 + lane];
        u32 p4 = xb[(size_t)i4 * 64 + lane];
        u32 p5 = xb[(size_t)i5 * 64 + lane];
        u32 p6 = xb[(size_t)i6 * 64 + lane];
        u32 p7 = xb[(size_t)i7 * 64 + lane];
        ax += bf2f((u16)(p0 & 0xffffu)) + bf2f((u16)(p1 & 0xffffu))
            + bf2f((u16)(p2 & 0xffffu)) + bf2f((u16)(p3 & 0xffffu))
            + bf2f((u16)(p4 & 0xffffu)) + bf2f((u16)(p5 & 0xffffu))
            + bf2f((u16)(p6 & 0xffffu)) + bf2f((u16)(p7 & 0xffffu));
        ay += bf2f((u16)(p0 >> 16)) + bf2f((u16)(p1 >> 16))
            + bf2f((u16)(p2 >> 16)) + bf2f((u16)(p3 >> 16))
            + bf2f((u16)(p4 >> 16)) + bf2f((u16)(p5 >> 16))
            + bf2f((u16)(p6 >> 16)) + bf2f((u16)(p7 >> 16));
    }
    for (; j + 3 < je; j += 4) {
        u32 i0 = bs[j], i1 = bs[j + 1], i2 = bs[j + 2], i3 = bs[j + 3];
        u32 p0 = xb[(size_t)i0 * 64 + lane];
        u32 p1 = xb[(size_t)i1 * 64 + lane];
        u32 p2 = xb[(size_t)i2 * 64 + lane];
        u32 p3 = xb[(size_t)i3 * 64 + lane];
        ax += bf2f((u16)(p0 & 0xffffu)) + bf2f((u16)(p1 & 0xffffu))
            + bf2f((u16)(p2 & 0xffffu)) + bf2f((u16)(p3 & 0xffffu));
        ay += bf2f((u16)(p0 >> 16)) + bf2f((u16)(p1 >> 16))
            + bf2f((u16)(p2 >> 16)) + bf2f((u16)(p3 >> 16));
    }
    for (; j < je; ++j) {
        u32 p0 = xb[(size_t)bs[j] * 64 + lane];
        ax += bf2f((u16)(p0 & 0xffffu));
        ay += bf2f((u16)(p0 >> 16));
    }
    zb[(size_t)node * 64 + lane] = (u32)f2bf(ax) | ((u32)f2bf(ay) << 16);
}

// ---------------- fallback: init + atomic scatter (f32 z) ----------------
__global__ __launch_bounds__(256) void gin_init(const void* __restrict__ xv,
                                                const void* __restrict__ etav,
                                                float* __restrict__ z,
                                                const int* __restrict__ flags) {
    int i = blockIdx.x * 256 + threadIdx.x;
    const int n8 = NN * DD / 8;
    if (i >= n8) return;
    const int fbf = flags[0];
    float s = 1.0f + (fbf ? bf2f(((const u16*)etav)[0]) : ((const float*)etav)[0]);
    float4 a, b;
    if (fbf) {
        uint4 p = ((const uint4*)xv)[i];
        a.x = bf2f((u16)(p.x & 0xffffu)); a.y = bf2f((u16)(p.x >> 16));
        a.z = bf2f((u16)(p.y & 0xffffu)); a.w = bf2f((u16)(p.y >> 16));
        b.x = bf2f((u16)(p.z & 0xffffu)); b.y = bf2f((u16)(p.z >> 16));
        b.z = bf2f((u16)(p.w & 0xffffu)); b.w = bf2f((u16)(p.w >> 16));
    } else {
        a = ((const float4*)xv)[2 * i + 0];
        b = ((const float4*)xv)[2 * i + 1];
    }
    a.x *= s; a.y *= s; a.z *= s; a.w *= s;
    b.x *= s; b.y *= s; b.z *= s; b.w *= s;
    ((float4*)z)[2 * i + 0] = a;
    ((float4*)z)[2 * i + 1] = b;
}

__global__ __launch_bounds__(256) void gin_scatter(const void* __restrict__ xv,
                                                   const int* __restrict__ ei,
                                                   float* __restrict__ z,
                                                   const int* __restrict__ flags) {
    int e = blockIdx.x * 4 + (threadIdx.x >> 6);
    if (e >= NE) return;
    const int fbf = flags[0];
    const int f64 = flags[1];
    int lane = threadIdx.x & 63;
    int s, d;
    if (f64) { s = ei[2 * e]; d = ei[2 * (NE + e)]; }
    else     { s = ei[e];     d = ei[NE + e]; }
    float v0, v1;
    if (fbf) {
        u32 p = ((const u32*)((const u16*)xv + (size_t)s * DD))[lane];
        v0 = bf2f((u16)(p & 0xffffu));
        v1 = bf2f((u16)(p >> 16));
    } else {
        float2 p = ((const float2*)((const float*)xv + (size_t)s * DD))[lane];
        v0 = p.x; v1 = p.y;
    }
    float* dst = z + (size_t)d * DD + 2 * lane;
    atomicAdd(dst + 0, v0);
    atomicAdd(dst + 1, v1);
}

// ---------------- MFMA MLP + LN + skip ----------------
// bf16 MFMA (16x16x32), f32 accumulate. C/D: col=lane&15, row=(lane>>4)*4+reg.
// LDS 256B-row bf16 tiles, 16B-unit XOR swizzle (unit ^= row&7), write+read.
// ZBF=1: z AND skip-x are bf16 (xskip = xb). ZBF=0: f32 z + f32/bf16 x.
#define TRM 64
#define NTM ((NN + TRM - 1) / TRM)

template <int FBF, int ZBF>
__global__ __launch_bounds__(512, 1) void gin_mlp(
    const void* __restrict__ zv, const void* __restrict__ xskip,
    const void* __restrict__ W1, const void* __restrict__ b1,
    const void* __restrict__ W2, const void* __restrict__ b2,
    const void* __restrict__ gamma, const void* __restrict__ beta,
    float* __restrict__ out, const int* __restrict__ flags) {
    if (flags[0] != FBF) return;  // wave-uniform early exit (dud variant)

    __shared__ short s_w1[DD * DD];    // 32 KB bf16, row-major, swizzled
    __shared__ short s_w2[DD * DD];    // 32 KB
    __shared__ short s_zt[TRM * DD];   // 16 KB
    __shared__ short s_h1[TRM * DD];   // 16 KB
    __shared__ float s_h2[TRM * 132];  // 33 KB

    const int tid = threadIdx.x;
    char* w1c = (char*)s_w1;
    char* w2c = (char*)s_w2;
    char* ztc = (char*)s_zt;
    char* h1c = (char*)s_h1;

    if (FBF) {
#pragma unroll
        for (int q = 0; q < 4; ++q) {
            int u = tid + q * 512;
            int row = u >> 4, cu = u & 15;
            uint4 a = ((const uint4*)W1)[u];
            uint4 c = ((const uint4*)W2)[u];
            int off = row * 256 + ((cu ^ (row & 7)) << 4);
            *(uint4*)(w1c + off) = a;
            *(uint4*)(w2c + off) = c;
        }
    } else {
#pragma unroll
        for (int q = 0; q < 4; ++q) {
            int u = tid + q * 512;
            int row = u >> 4, cu = u & 15;
            float4 a0 = ((const float4*)W1)[u * 2 + 0];
            float4 a1 = ((const float4*)W1)[u * 2 + 1];
            float4 c0 = ((const float4*)W2)[u * 2 + 0];
            float4 c1 = ((const float4*)W2)[u * 2 + 1];
            uint4 pa, pc;
            pa.x = (u32)f2bf(a0.x) | ((u32)f2bf(a0.y) << 16);
            pa.y = (u32)f2bf(a0.z) | ((u32)f2bf(a0.w) << 16);
            pa.z = (u32)f2bf(a1.x) | ((u32)f2bf(a1.y) << 16);
            pa.w = (u32)f2bf(a1.z) | ((u32)f2bf(a1.w) << 16);
            pc.x = (u32)f2bf(c0.x) | ((u32)f2bf(c0.y) << 16);
            pc.y = (u32)f2bf(c0.z) | ((u32)f2bf(c0.w) << 16);
            pc.z = (u32)f2bf(c1.x) | ((u32)f2bf(c1.y) << 16);
            pc.w = (u32)f2bf(c1.z) | ((u32)f2bf(c1.w) << 16);
            int off = row * 256 + ((cu ^ (row & 7)) << 4);
            *(uint4*)(w1c + off) = pa;
            *(uint4*)(w2c + off) = pc;
        }
    }

    const int lane = tid & 63;
    const int wid = tid >> 6;
    const int lrow = lane & 15;
    const int hi = lane >> 4;
    const int rstrip = wid & 3;
    const int nb = (wid >> 2) * 64;
    const int arow = rstrip * 16 + lrow;

    float b1v[4], b2v[4];
#pragma unroll
    for (int tt = 0; tt < 4; ++tt) {
        int j = nb + tt * 16 + lrow;
        b1v[tt] = FBF ? bf2f(((const u16*)b1)[j]) : ((const float*)b1)[j];
        b2v[tt] = FBF ? bf2f(((const u16*)b2)[j]) : ((const float*)b2)[j];
    }

    const int cg = tid & 31;
    const int rg = tid >> 5;
    const int r0 = rg * 4;
    float gv[4], bev[4];
    if (FBF) {
        uint2 pg = ((const uint2*)gamma)[cg];
        uint2 pe = ((const uint2*)beta)[cg];
        gv[0] = bf2f((u16)(pg.x & 0xffffu)); gv[1] = bf2f((u16)(pg.x >> 16));
        gv[2] = bf2f((u16)(pg.y & 0xffffu)); gv[3] = bf2f((u16)(pg.y >> 16));
        bev[0] = bf2f((u16)(pe.x & 0xffffu)); bev[1] = bf2f((u16)(pe.x >> 16));
        bev[2] = bf2f((u16)(pe.y & 0xffffu)); bev[3] = bf2f((u16)(pe.y >> 16));
    } else {
        float4 t3 = ((const float4*)gamma)[cg];
        float4 t4 = ((const float4*)beta)[cg];
        gv[0] = t3.x; gv[1] = t3.y; gv[2] = t3.z; gv[3] = t3.w;
        bev[0] = t4.x; bev[1] = t4.y; bev[2] = t4.z; bev[3] = t4.w;
    }

    for (int t = blockIdx.x; t < NTM; t += gridDim.x) {
        const int row0 = t * TRM;
        __syncthreads();
        if (ZBF) {
#pragma unroll
            for (int q = 0; q < 2; ++q) {
                int u = tid + q * 512;
                int row = u >> 4, cu = u & 15;
                int grow = row0 + row;
                uint4 p = {0u, 0u, 0u, 0u};
                if (grow < NN) p = ((const uint4*)zv)[(size_t)grow * 16 + cu];
                *(uint4*)(ztc + row * 256 + ((cu ^ (row & 7)) << 4)) = p;
            }
        } else {
#pragma unroll
            for (int q = 0; q < 2; ++q) {
                int u = tid + q * 512;
                int row = u >> 4, cu = u & 15;
                int grow = row0 + row;
                float4 a0 = {0.f, 0.f, 0.f, 0.f}, a1 = {0.f, 0.f, 0.f, 0.f};
                if (grow < NN) {
                    a0 = ((const float4*)zv)[(size_t)grow * 32 + cu * 2 + 0];
                    a1 = ((const float4*)zv)[(size_t)grow * 32 + cu * 2 + 1];
                }
                uint4 p;
                p.x = (u32)f2bf(a0.x) | ((u32)f2bf(a0.y) << 16);
                p.y = (u32)f2bf(a0.z) | ((u32)f2bf(a0.w) << 16);
                p.z = (u32)f2bf(a1.x) | ((u32)f2bf(a1.y) << 16);
                p.w = (u32)f2bf(a1.z) | ((u32)f2bf(a1.w) << 16);
                *(uint4*)(ztc + row * 256 + ((cu ^ (row & 7)) << 4)) = p;
            }
        }
        __syncthreads();

        f32x4 acc[4];
#pragma unroll
        for (int tt = 0; tt < 4; ++tt)
            acc[tt] = (f32x4){b1v[tt], b1v[tt], b1v[tt], b1v[tt]};
#pragma unroll
        for (int c = 0; c < 4; ++c) {
            bf16x8 af = *(const bf16x8*)(ztc + arow * 256 + (((c * 4 + hi) ^ (arow & 7)) << 4));
#pragma unroll
            for (int tt = 0; tt < 4; ++tt) {
                int brow = nb + tt * 16 + lrow;
                bf16x8 bfv = *(const bf16x8*)(w1c + brow * 256 + (((c * 4 + hi) ^ (brow & 7)) << 4));
                acc[tt] = __builtin_amdgcn_mfma_f32_16x16x32_bf16(af, bfv, acc[tt], 0, 0, 0);
            }
        }
#pragma unroll
        for (int tt = 0; tt < 4; ++tt) {
            int j = nb + tt * 16 + lrow;
            int jb2 = j * 2;
            int unit = jb2 >> 4, within = jb2 & 15;
#pragma unroll
            for (int qq = 0; qq < 4; ++qq) {
                int row = rstrip * 16 + hi * 4 + qq;
                u16 hb = f2bf(fmaxf(acc[tt][qq], 0.f));
                *(u16*)(h1c + row * 256 + ((unit ^ (row & 7)) << 4) + within) = hb;
            }
        }
        __syncthreads();
#pragma unroll
        for (int tt = 0; tt < 4; ++tt)
            acc[tt] = (f32x4){b2v[tt], b2v[tt], b2v[tt], b2v[tt]};
#pragma unroll
        for (int c = 0; c < 4; ++c) {
            bf16x8 af = *(const bf16x8*)(h1c + arow * 256 + (((c * 4 + hi) ^ (arow & 7)) << 4));
#pragma unroll
            for (int tt = 0; tt < 4; ++tt) {
                int brow = nb + tt * 16 + lrow;
                bf16x8 bfv = *(const bf16x8*)(w2c + brow * 256 + (((c * 4 + hi) ^ (brow & 7)) << 4));
                acc[tt] = __builtin_amdgcn_mfma_f32_16x16x32_bf16(af, bfv, acc[tt], 0, 0, 0);
            }
        }
#pragma unroll
        for (int tt = 0; tt < 4; ++tt) {
            int j = nb + tt * 16 + lrow;
#pragma unroll
            for (int qq = 0; qq < 4; ++qq) {
                int row = rstrip * 16 + hi * 4 + qq;
                s_h2[row * 132 + j] = fmaxf(acc[tt][qq], 0.f);
            }
        }
        __syncthreads();
#pragma unroll
        for (int r = 0; r < 4; ++r) {
            const float* hp = &s_h2[(r0 + r) * 132 + 4 * cg];
            float h0 = hp[0], h1 = hp[1], h2 = hp[2], h3 = hp[3];
            float s1 = h0 + h1 + h2 + h3;
            float s2 = h0 * h0 + h1 * h1 + h2 * h2 + h3 * h3;
#pragma unroll
            for (int m = 1; m <= 16; m <<= 1) {
                s1 += __shfl_xor(s1, m);
                s2 += __shfl_xor(s2, m);
            }
            float mean = s1 * (1.0f / DD);
            float var = s2 * (1.0f / DD) - mean * mean;
            float rs = rsqrtf(var + 1e-5f);
            int grow = row0 + r0 + r;
            if (grow < NN) {
                float xi[4];
                if (FBF || ZBF) {
                    uint2 px = ((const uint2*)((const u16*)xskip + (size_t)grow * DD))[cg];
                    xi[0] = bf2f((u16)(px.x & 0xffffu)); xi[1] = bf2f((u16)(px.x >> 16));
                    xi[2] = bf2f((u16)(px.y & 0xffffu)); xi[3] = bf2f((u16)(px.y >> 16));
                } else {
                    float4 px = ((const float4*)((const float*)xskip + (size_t)grow * DD))[cg];
                    xi[0] = px.x; xi[1] = px.y; xi[2] = px.z; xi[3] = px.w;
                }
                float4 o;
                o.x = (h0 - mean) * rs * gv[0] + bev[0] + xi[0];
                o.y = (h1 - mean) * rs * gv[1] + bev[1] + xi[1];
                o.z = (h2 - mean) * rs * gv[2] + bev[2] + xi[2];
                o.w = (h3 - mean) * rs * gv[3] + bev[3] + xi[3];
                ((float4*)(out + (size_t)grow * DD))[cg] = o;
            }
        }
    }
}

extern "C" void kernel_launch(void* const* d_in, const int* in_sizes, int n_in,
                              void* d_out, int out_size, void* d_ws, size_t ws_size,
                              hipStream_t stream) {
    const void* x = d_in[0];
    const int* ei = (const int*)d_in[1];
    const void* W1 = d_in[2];
    const void* b1 = d_in[3];
    const void* W2 = d_in[4];
    const void* b2 = d_in[5];
    const void* eta = d_in[6];
    const void* gamma = d_in[7];
    const void* beta = d_in[8];
    float* out = (float*)d_out;

    const size_t FLAGS_OFF = 0;
    const size_t PART_OFF = 64;
    const size_t Z_OFF = 256;
    const size_t ZB = (size_t)NN * DD * sizeof(float);   // 25,600,000
    const size_t XB_OFF = Z_OFF;                          // bf16 x copy
    const size_t ZBF_OFF = Z_OFF + (size_t)NN * DD * 2;   // bf16 z
    const size_t DEG_OFF = Z_OFF + ZB;
    const size_t DEGB = 200192;
    const size_t RS_OFF = DEG_OFF + DEGB;
    const size_t RSB = 200448;
    const size_t BS_OFF = RS_OFF + RSB;
    const size_t BSB = (size_t)NE * sizeof(u16);         // 1,600,000
    const size_t RK_OFF = BS_OFF + BSB;
    const size_t RKB = (size_t)NE * sizeof(u16);         // 1,600,000
    const size_t PCK_OFF = RK_OFF + RKB;
    const size_t PCKB = (size_t)NE * sizeof(u32);        // 3,200,000
    const size_t TOT = PCK_OFF + PCKB;                   // ~32.4 MB (ws = 256 MiB)

    if (ws_size < Z_OFF + ZB) return;
    int* flags = (int*)((char*)d_ws + FLAGS_OFF);
    u32* partials = (u32*)((char*)d_ws + PART_OFF);

    gin_detect<<<1, 64, 0, stream>>>((const u32*)x, (const u32*)ei, flags);

    if (ws_size >= TOT) {
        u32* xb = (u32*)((char*)d_ws + XB_OFF);
        u32* zb = (u32*)((char*)d_ws + ZBF_OFF);
        u32* deg = (u32*)((char*)d_ws + DEG_OFF);
        u32* row_start = (u32*)((char*)d_ws + RS_OFF);
        u16* bs = (u16*)((char*)d_ws + BS_OFF);
        u16* rank = (u16*)((char*)d_ws + RK_OFF);
        u32* pck = (u32*)((char*)d_ws + PCK_OFF);
        gin_tobf_zero<<<NB_TOBF + NB_ZERO, 256, 0, stream>>>(x, (uint4*)xb, deg, flags);
        gin_hist<<<(NE + 255) / 256, 256, 0, stream>>>(ei, deg, rank, pck, flags);
        gin_scan1<<<NSB, 1024, 0, stream>>>(deg, partials);
        gin_scan3<<<NSB, 1024, 0, stream>>>(deg, partials, row_start);
        gin_fill<<<(NE + 255) / 256, 256, 0, stream>>>(pck, row_start, rank, bs);
        gin_gather<<<(NN + 3) / 4, 256, 0, stream>>>(xb, bs, row_start, deg, eta, zb, flags);
        gin_mlp<0, 1><<<256, 512, 0, stream>>>(zb, xb, W1, b1, W2, b2, gamma, beta, out, flags);
        gin_mlp<1, 1><<<256, 512, 0, stream>>>(zb, xb, W1, b1, W2, b2, gamma, beta, out, flags);
    } else {
        float* z = (float*)((char*)d_ws + Z_OFF);
        gin_init<<<(NN * DD / 8 + 255) / 256, 256, 0, stream>>>(x, eta, z, flags);
        gin_scatter<<<NE / 4, 256, 0, stream>>>(x, ei, z, flags);
        gin_mlp<0, 0><<<256, 512, 0, stream>>>(z, x, W1, b1, W2, b2, gamma, beta, out, flags);
        gin_mlp<1, 0><<<256, 512, 0, stream>>>(z, x, W1, b1, W2, b2, gamma, beta, out, flags);
    }
}

// Round 14
// 127.414 us; speedup vs baseline: 9.7296x; 1.0049x over previous
//
#include <hip/hip_runtime.h>

#define NN 50000
#define NE 800000
#define DD 128

typedef unsigned int u32;
typedef unsigned short u16;
typedef unsigned long long u64;
typedef __attribute__((ext_vector_type(8))) short bf16x8;
typedef __attribute__((ext_vector_type(4))) float f32x4;

__device__ __forceinline__ float bf2f(u16 u) {
    union { float f; u32 i; } v; v.i = ((u32)u) << 16; return v.f;
}
__device__ __forceinline__ u16 f2bf(float f) {
    u32 x = __float_as_uint(f);
    x += 0x7fffu + ((x >> 16) & 1u);
    return (u16)(x >> 16);
}

// ---------------- K0: dtype detect ----------------
__global__ __launch_bounds__(64) void gin_detect(const u32* __restrict__ xw,
                                                 const u32* __restrict__ ew,
                                                 int* __restrict__ flags) {
    int lane = threadIdx.x;
    u32 w = xw[lane];
    u32 e8 = (w >> 7) & 0xFFu;
    bool bfOK = (e8 >= 100u && e8 <= 150u) || ((w & 0xFFFFu) == 0u);
    u64 m1 = __ballot(bfOK);
    bool oddZero = (ew[2 * lane + 1] == 0u);
    u64 m2 = __ballot(oddZero);
    if (lane == 0) {
        flags[0] = (__popcll(m1) >= 56) ? 1 : 0;
        flags[1] = (__popcll(m2) >= 60) ? 1 : 0;
    }
}

// ---------------- fused: x -> bf16 copy  +  deg zero ----------------
#define NB_TOBF ((NN * DD / 8) / 256)          // 3125 (exact)
#define NB_ZERO ((NN + 255) / 256)             // 196

__global__ __launch_bounds__(256) void gin_tobf_zero(const void* __restrict__ xv,
                                                     uint4* __restrict__ xb,
                                                     u32* __restrict__ deg,
                                                     const int* __restrict__ flags) {
    int b = blockIdx.x;
    int tid = threadIdx.x;
    if (b < NB_TOBF) {
        int i = b * 256 + tid;                 // 16B unit (8 bf16)
        if (flags[0]) {
            xb[i] = ((const uint4*)xv)[i];
        } else {
            float4 a0 = ((const float4*)xv)[2 * i + 0];
            float4 a1 = ((const float4*)xv)[2 * i + 1];
            uint4 p;
            p.x = (u32)f2bf(a0.x) | ((u32)f2bf(a0.y) << 16);
            p.y = (u32)f2bf(a0.z) | ((u32)f2bf(a0.w) << 16);
            p.z = (u32)f2bf(a1.x) | ((u32)f2bf(a1.y) << 16);
            p.w = (u32)f2bf(a1.z) | ((u32)f2bf(a1.w) << 16);
            xb[i] = p;
        }
    } else {
        int i = (b - NB_TOBF) * 256 + tid;
        if (i < NN) deg[i] = 0u;
    }
}

// hist: degree count + arrival rank (u16) + packed (s,d) u32 for fill.
__global__ __launch_bounds__(256) void gin_hist(const int* __restrict__ ei,
                                                u32* __restrict__ deg,
                                                u16* __restrict__ rank,
                                                u32* __restrict__ pck,
                                                const int* __restrict__ flags) {
    int e = blockIdx.x * 256 + threadIdx.x;
    if (e >= NE) return;
    int s, d;
    if (flags[1]) { s = ei[2 * e]; d = ei[2 * (NE + e)]; }
    else          { s = ei[e];     d = ei[NE + e]; }
    pck[e] = (u32)s | ((u32)d << 16);
    rank[e] = (u16)atomicAdd(&deg[d], 1u);
}

#define SCAN_CHUNK 2048
#define NSB ((NN + SCAN_CHUNK - 1) / SCAN_CHUNK)   // 25 blocks

__global__ __launch_bounds__(1024) void gin_scan1(const u32* __restrict__ deg,
                                                  u32* __restrict__ partials) {
    __shared__ u32 red[1024];
    int tid = threadIdx.x;
    int base = blockIdx.x * SCAN_CHUNK + tid * 2;
    u32 a = (base < NN) ? deg[base] : 0u;
    u32 b = (base + 1 < NN) ? deg[base + 1] : 0u;
    red[tid] = a + b;
    __syncthreads();
    for (int off = 512; off > 0; off >>= 1) {
        if (tid < off) red[tid] += red[tid + off];
        __syncthreads();
    }
    if (tid == 0) partials[blockIdx.x] = red[0];
}

// scan3: block-local scan + self-computed exclusive chunk base (absorbs scan2).
__global__ __launch_bounds__(1024) void gin_scan3(const u32* __restrict__ deg,
                                                  const u32* __restrict__ partials,
                                                  u32* __restrict__ row_start) {
    __shared__ u32 sc[1024];
    __shared__ u32 chunk_base;
    int tid = threadIdx.x;
    if (tid < 64) {
        u32 v = (tid < NSB && tid < blockIdx.x) ? partials[tid] : 0u;
#pragma unroll
        for (int m = 32; m > 0; m >>= 1) v += __shfl_xor(v, m);
        if (tid == 0) chunk_base = v;
    }
    int base = blockIdx.x * SCAN_CHUNK + tid * 2;
    u32 a = (base < NN) ? deg[base] : 0u;
    u32 b = (base + 1 < NN) ? deg[base + 1] : 0u;
    u32 ts = a + b;
    sc[tid] = ts;
    __syncthreads();
    for (int off = 1; off < 1024; off <<= 1) {
        u32 v = (tid >= off) ? sc[tid - off] : 0u;
        __syncthreads();
        sc[tid] += v;
        __syncthreads();
    }
    u32 excl = sc[tid] - ts + chunk_base;
    if (base < NN) row_start[base] = excl;
    if (base + 1 < NN) row_start[base + 1] = excl + a;
}

// fill: atomic-free, reads packed (s,d) + rank (no int64 ei re-read).
__global__ __launch_bounds__(256) void gin_fill(const u32* __restrict__ pck,
                                                const u32* __restrict__ row_start,
                                                const u16* __restrict__ rank,
                                                u16* __restrict__ bs) {
    int e = blockIdx.x * 256 + threadIdx.x;
    if (e >= NE) return;
    u32 p = pck[e];
    u32 s = p & 0xffffu, d = p >> 16;
    bs[row_start[d] + (u32)rank[e]] = (u16)s;
}

// ---------------- gather-sum (+init), paired half-wave edges ----------------
// Lanes 0-31 process even edges, 32-63 odd edges; each lane loads uint2 (8B,
// 4 bf16 cols). One instruction fetches TWO 256B rows -> 2x rows in flight.
// Self term weighted 0 in the high half; one shfl_xor(32) reduce at the end.
__global__ __launch_bounds__(256) void gin_gather(const u32* __restrict__ xb,
                                                  const u16* __restrict__ bs,
                                                  const u32* __restrict__ row_start,
                                                  const u32* __restrict__ deg,
                                                  const void* __restrict__ etav,
                                                  u32* __restrict__ zb,
                                                  const int* __restrict__ flags) {
    int node = blockIdx.x * 4 + (threadIdx.x >> 6);
    if (node >= NN) return;
    const int lane = threadIdx.x & 63;
    const int h = lane >> 5;       // half: 0 = even edge, 1 = odd edge
    const int ll = lane & 31;      // covers cols 4*ll .. 4*ll+3
    float s = 1.0f + (flags[0] ? bf2f(((const u16*)etav)[0]) : ((const float*)etav)[0]);
    float w = h ? 0.f : s;         // self term counted once (low half)

    uint2 sp = ((const uint2*)(xb + (size_t)node * 64))[ll];
    float a0 = bf2f((u16)(sp.x & 0xffffu)) * w;
    float a1 = bf2f((u16)(sp.x >> 16)) * w;
    float a2 = bf2f((u16)(sp.y & 0xffffu)) * w;
    float a3 = bf2f((u16)(sp.y >> 16)) * w;

#define ACC2(P) \
    a0 += bf2f((u16)((P).x & 0xffffu)); a1 += bf2f((u16)((P).x >> 16)); \
    a2 += bf2f((u16)((P).y & 0xffffu)); a3 += bf2f((u16)((P).y >> 16));

    u32 jb = row_start[node], je = jb + deg[node];
    u32 j = jb;
    for (; j + 15 < je; j += 16) {   // 8 pair loads = 16 rows in flight
        u32 i0 = bs[j + 0 + h],  i1 = bs[j + 2 + h],  i2 = bs[j + 4 + h],  i3 = bs[j + 6 + h];
        u32 i4 = bs[j + 8 + h],  i5 = bs[j + 10 + h], i6 = bs[j + 12 + h], i7 = bs[j + 14 + h];
        uint2 p0 = ((const uint2*)(xb + (size_t)i0 * 64))[ll];
        uint2 p1 = ((const uint2*)(xb + (size_t)i1 * 64))[ll];
        uint2 p2 = ((const uint2*)(xb + (size_t)i2 * 64))[ll];
        uint2 p3 = ((const uint2*)(xb + (size_t)i3 * 64))[ll];
        uint2 p4 = ((const uint2*)(xb + (size_t)i4 * 64))[ll];
        uint2 p5 = ((const uint2*)(xb + (size_t)i5 * 64))[ll];
        uint2 p6 = ((const uint2*)(xb + (size_t)i6 * 64))[ll];
        uint2 p7 = ((const uint2*)(xb + (size_t)i7 * 64))[ll];
        ACC2(p0) ACC2(p1) ACC2(p2) ACC2(p3) ACC2(p4) ACC2(p5) ACC2(p6) ACC2(p7)
    }
    for (; j + 3 < je; j += 4) {     // 2 pair loads
        u32 i0 = bs[j + 0 + h], i1 = bs[j + 2 + h];
        uint2 p0 = ((const uint2*)(xb + (size_t)i0 * 64))[ll];
        uint2 p1 = ((const uint2*)(xb + (size_t)i1 * 64))[ll];
        ACC2(p0) ACC2(p1)
    }
    for (; j + 1 < je; j += 2) {     // 1 pair
        u32 i0 = bs[j + h];
        uint2 p0 = ((const uint2*)(xb + (size_t)i0 * 64))[ll];
        ACC2(p0)
    }
    if (j < je && h == 0) {          // odd tail edge (low half only)
        u32 i0 = bs[j];
        uint2 p0 = ((const uint2*)(xb + (size_t)i0 * 64))[ll];
        ACC2(p0)
    }
#undef ACC2
    // cross-half reduce
    a0 += __shfl_xor(a0, 32);
    a1 += __shfl_xor(a1, 32);
    a2 += __shfl_xor(a2, 32);
    a3 += __shfl_xor(a3, 32);
    if (h == 0) {
        uint2 o;
        o.x = (u32)f2bf(a0) | ((u32)f2bf(a1) << 16);
        o.y = (u32)f2bf(a2) | ((u32)f2bf(a3) << 16);
        ((uint2*)(zb + (size_t)node * 64))[ll] = o;
    }
}

// ---------------- fallback: init + atomic scatter (f32 z) ----------------
__global__ __launch_bounds__(256) void gin_init(const void* __restrict__ xv,
                                                const void* __restrict__ etav,
                                                float* __restrict__ z,
                                                const int* __restrict__ flags) {
    int i = blockIdx.x * 256 + threadIdx.x;
    const int n8 = NN * DD / 8;
    if (i >= n8) return;
    const int fbf = flags[0];
    float s = 1.0f + (fbf ? bf2f(((const u16*)etav)[0]) : ((const float*)etav)[0]);
    float4 a, b;
    if (fbf) {
        uint4 p = ((const uint4*)xv)[i];
        a.x = bf2f((u16)(p.x & 0xffffu)); a.y = bf2f((u16)(p.x >> 16));
        a.z = bf2f((u16)(p.y & 0xffffu)); a.w = bf2f((u16)(p.y >> 16));
        b.x = bf2f((u16)(p.z & 0xffffu)); b.y = bf2f((u16)(p.z >> 16));
        b.z = bf2f((u16)(p.w & 0xffffu)); b.w = bf2f((u16)(p.w >> 16));
    } else {
        a = ((const float4*)xv)[2 * i + 0];
        b = ((const float4*)xv)[2 * i + 1];
    }
    a.x *= s; a.y *= s; a.z *= s; a.w *= s;
    b.x *= s; b.y *= s; b.z *= s; b.w *= s;
    ((float4*)z)[2 * i + 0] = a;
    ((float4*)z)[2 * i + 1] = b;
}

__global__ __launch_bounds__(256) void gin_scatter(const void* __restrict__ xv,
                                                   const int* __restrict__ ei,
                                                   float* __restrict__ z,
                                                   const int* __restrict__ flags) {
    int e = blockIdx.x * 4 + (threadIdx.x >> 6);
    if (e >= NE) return;
    const int fbf = flags[0];
    const int f64 = flags[1];
    int lane = threadIdx.x & 63;
    int s, d;
    if (f64) { s = ei[2 * e]; d = ei[2 * (NE + e)]; }
    else     { s = ei[e];     d = ei[NE + e]; }
    float v0, v1;
    if (fbf) {
        u32 p = ((const u32*)((const u16*)xv + (size_t)s * DD))[lane];
        v0 = bf2f((u16)(p & 0xffffu));
        v1 = bf2f((u16)(p >> 16));
    } else {
        float2 p = ((const float2*)((const float*)xv + (size_t)s * DD))[lane];
        v0 = p.x; v1 = p.y;
    }
    float* dst = z + (size_t)d * DD + 2 * lane;
    atomicAdd(dst + 0, v0);
    atomicAdd(dst + 1, v1);
}

// ---------------- MFMA MLP + LN + skip ----------------
// bf16 MFMA (16x16x32), f32 accumulate. C/D: col=lane&15, row=(lane>>4)*4+reg.
// LDS 256B-row bf16 tiles, 16B-unit XOR swizzle (unit ^= row&7), write+read.
// ZBF=1: z AND skip-x are bf16 (xskip = xb). ZBF=0: f32 z + f32/bf16 x.
#define TRM 64
#define NTM ((NN + TRM - 1) / TRM)

template <int FBF, int ZBF>
__global__ __launch_bounds__(512, 1) void gin_mlp(
    const void* __restrict__ zv, const void* __restrict__ xskip,
    const void* __restrict__ W1, const void* __restrict__ b1,
    const void* __restrict__ W2, const void* __restrict__ b2,
    const void* __restrict__ gamma, const void* __restrict__ beta,
    float* __restrict__ out, const int* __restrict__ flags) {
    if (flags[0] != FBF) return;  // wave-uniform early exit (dud variant)

    __shared__ short s_w1[DD * DD];    // 32 KB bf16, row-major, swizzled
    __shared__ short s_w2[DD * DD];    // 32 KB
    __shared__ short s_zt[TRM * DD];   // 16 KB
    __shared__ short s_h1[TRM * DD];   // 16 KB
    __shared__ float s_h2[TRM * 132];  // 33 KB

    const int tid = threadIdx.x;
    char* w1c = (char*)s_w1;
    char* w2c = (char*)s_w2;
    char* ztc = (char*)s_zt;
    char* h1c = (char*)s_h1;

    if (FBF) {
#pragma unroll
        for (int q = 0; q < 4; ++q) {
            int u = tid + q * 512;
            int row = u >> 4, cu = u & 15;
            uint4 a = ((const uint4*)W1)[u];
            uint4 c = ((const uint4*)W2)[u];
            int off = row * 256 + ((cu ^ (row & 7)) << 4);
            *(uint4*)(w1c + off) = a;
            *(uint4*)(w2c + off) = c;
        }
    } else {
#pragma unroll
        for (int q = 0; q < 4; ++q) {
            int u = tid + q * 512;
            int row = u >> 4, cu = u & 15;
            float4 a0 = ((const float4*)W1)[u * 2 + 0];
            float4 a1 = ((const float4*)W1)[u * 2 + 1];
            float4 c0 = ((const float4*)W2)[u * 2 + 0];
            float4 c1 = ((const float4*)W2)[u * 2 + 1];
            uint4 pa, pc;
            pa.x = (u32)f2bf(a0.x) | ((u32)f2bf(a0.y) << 16);
            pa.y = (u32)f2bf(a0.z) | ((u32)f2bf(a0.w) << 16);
            pa.z = (u32)f2bf(a1.x) | ((u32)f2bf(a1.y) << 16);
            pa.w = (u32)f2bf(a1.z) | ((u32)f2bf(a1.w) << 16);
            pc.x = (u32)f2bf(c0.x) | ((u32)f2bf(c0.y) << 16);
            pc.y = (u32)f2bf(c0.z) | ((u32)f2bf(c0.w) << 16);
            pc.z = (u32)f2bf(c1.x) | ((u32)f2bf(c1.y) << 16);
            pc.w = (u32)f2bf(c1.z) | ((u32)f2bf(c1.w) << 16);
            int off = row * 256 + ((cu ^ (row & 7)) << 4);
            *(uint4*)(w1c + off) = pa;
            *(uint4*)(w2c + off) = pc;
        }
    }

    const int lane = tid & 63;
    const int wid = tid >> 6;
    const int lrow = lane & 15;
    const int hi = lane >> 4;
    const int rstrip = wid & 3;
    const int nb = (wid >> 2) * 64;
    const int arow = rstrip * 16 + lrow;

    float b1v[4], b2v[4];
#pragma unroll
    for (int tt = 0; tt < 4; ++tt) {
        int j = nb + tt * 16 + lrow;
        b1v[tt] = FBF ? bf2f(((const u16*)b1)[j]) : ((const float*)b1)[j];
        b2v[tt] = FBF ? bf2f(((const u16*)b2)[j]) : ((const float*)b2)[j];
    }

    const int cg = tid & 31;
    const int rg = tid >> 5;
    const int r0 = rg * 4;
    float gv[4], bev[4];
    if (FBF) {
        uint2 pg = ((const uint2*)gamma)[cg];
        uint2 pe = ((const uint2*)beta)[cg];
        gv[0] = bf2f((u16)(pg.x & 0xffffu)); gv[1] = bf2f((u16)(pg.x >> 16));
        gv[2] = bf2f((u16)(pg.y & 0xffffu)); gv[3] = bf2f((u16)(pg.y >> 16));
        bev[0] = bf2f((u16)(pe.x & 0xffffu)); bev[1] = bf2f((u16)(pe.x >> 16));
        bev[2] = bf2f((u16)(pe.y & 0xffffu)); bev[3] = bf2f((u16)(pe.y >> 16));
    } else {
        float4 t3 = ((const float4*)gamma)[cg];
        float4 t4 = ((const float4*)beta)[cg];
        gv[0] = t3.x; gv[1] = t3.y; gv[2] = t3.z; gv[3] = t3.w;
        bev[0] = t4.x; bev[1] = t4.y; bev[2] = t4.z; bev[3] = t4.w;
    }

    for (int t = blockIdx.x; t < NTM; t += gridDim.x) {
        const int row0 = t * TRM;
        __syncthreads();
        if (ZBF) {
#pragma unroll
            for (int q = 0; q < 2; ++q) {
                int u = tid + q * 512;
                int row = u >> 4, cu = u & 15;
                int grow = row0 + row;
                uint4 p = {0u, 0u, 0u, 0u};
                if (grow < NN) p = ((const uint4*)zv)[(size_t)grow * 16 + cu];
                *(uint4*)(ztc + row * 256 + ((cu ^ (row & 7)) << 4)) = p;
            }
        } else {
#pragma unroll
            for (int q = 0; q < 2; ++q) {
                int u = tid + q * 512;
                int row = u >> 4, cu = u & 15;
                int grow = row0 + row;
                float4 a0 = {0.f, 0.f, 0.f, 0.f}, a1 = {0.f, 0.f, 0.f, 0.f};
                if (grow < NN) {
                    a0 = ((const float4*)zv)[(size_t)grow * 32 + cu * 2 + 0];
                    a1 = ((const float4*)zv)[(size_t)grow * 32 + cu * 2 + 1];
                }
                uint4 p;
                p.x = (u32)f2bf(a0.x) | ((u32)f2bf(a0.y) << 16);
                p.y = (u32)f2bf(a0.z) | ((u32)f2bf(a0.w) << 16);
                p.z = (u32)f2bf(a1.x) | ((u32)f2bf(a1.y) << 16);
                p.w = (u32)f2bf(a1.z) | ((u32)f2bf(a1.w) << 16);
                *(uint4*)(ztc + row * 256 + ((cu ^ (row & 7)) << 4)) = p;
            }
        }
        __syncthreads();

        f32x4 acc[4];
#pragma unroll
        for (int tt = 0; tt < 4; ++tt)
            acc[tt] = (f32x4){b1v[tt], b1v[tt], b1v[tt], b1v[tt]};
#pragma unroll
        for (int c = 0; c < 4; ++c) {
            bf16x8 af = *(const bf16x8*)(ztc + arow * 256 + (((c * 4 + hi) ^ (arow & 7)) << 4));
#pragma unroll
            for (int tt = 0; tt < 4; ++tt) {
                int brow = nb + tt * 16 + lrow;
                bf16x8 bfv = *(const bf16x8*)(w1c + brow * 256 + (((c * 4 + hi) ^ (brow & 7)) << 4));
                acc[tt] = __builtin_amdgcn_mfma_f32_16x16x32_bf16(af, bfv, acc[tt], 0, 0, 0);
            }
        }
#pragma unroll
        for (int tt = 0; tt < 4; ++tt) {
            int j = nb + tt * 16 + lrow;
            int jb2 = j * 2;
            int unit = jb2 >> 4, within = jb2 & 15;
#pragma unroll
            for (int qq = 0; qq < 4; ++qq) {
                int row = rstrip * 16 + hi * 4 + qq;
                u16 hb = f2bf(fmaxf(acc[tt][qq], 0.f));
                *(u16*)(h1c + row * 256 + ((unit ^ (row & 7)) << 4) + within) = hb;
            }
        }
        __syncthreads();
#pragma unroll
        for (int tt = 0; tt < 4; ++tt)
            acc[tt] = (f32x4){b2v[tt], b2v[tt], b2v[tt], b2v[tt]};
#pragma unroll
        for (int c = 0; c < 4; ++c) {
            bf16x8 af = *(const bf16x8*)(h1c + arow * 256 + (((c * 4 + hi) ^ (arow & 7)) << 4));
#pragma unroll
            for (int tt = 0; tt < 4; ++tt) {
                int brow = nb + tt * 16 + lrow;
                bf16x8 bfv = *(const bf16x8*)(w2c + brow * 256 + (((c * 4 + hi) ^ (brow & 7)) << 4));
                acc[tt] = __builtin_amdgcn_mfma_f32_16x16x32_bf16(af, bfv, acc[tt], 0, 0, 0);
            }
        }
#pragma unroll
        for (int tt = 0; tt < 4; ++tt) {
            int j = nb + tt * 16 + lrow;
#pragma unroll
            for (int qq = 0; qq < 4; ++qq) {
                int row = rstrip * 16 + hi * 4 + qq;
                s_h2[row * 132 + j] = fmaxf(acc[tt][qq], 0.f);
            }
        }
        __syncthreads();
#pragma unroll
        for (int r = 0; r < 4; ++r) {
            const float* hp = &s_h2[(r0 + r) * 132 + 4 * cg];
            float h0 = hp[0], h1 = hp[1], h2 = hp[2], h3 = hp[3];
            float s1 = h0 + h1 + h2 + h3;
            float s2 = h0 * h0 + h1 * h1 + h2 * h2 + h3 * h3;
#pragma unroll
            for (int m = 1; m <= 16; m <<= 1) {
                s1 += __shfl_xor(s1, m);
                s2 += __shfl_xor(s2, m);
            }
            float mean = s1 * (1.0f / DD);
            float var = s2 * (1.0f / DD) - mean * mean;
            float rs = rsqrtf(var + 1e-5f);
            int grow = row0 + r0 + r;
            if (grow < NN) {
                float xi[4];
                if (FBF || ZBF) {
                    uint2 px = ((const uint2*)((const u16*)xskip + (size_t)grow * DD))[cg];
                    xi[0] = bf2f((u16)(px.x & 0xffffu)); xi[1] = bf2f((u16)(px.x >> 16));
                    xi[2] = bf2f((u16)(px.y & 0xffffu)); xi[3] = bf2f((u16)(px.y >> 16));
                } else {
                    float4 px = ((const float4*)((const float*)xskip + (size_t)grow * DD))[cg];
                    xi[0] = px.x; xi[1] = px.y; xi[2] = px.z; xi[3] = px.w;
                }
                float4 o;
                o.x = (h0 - mean) * rs * gv[0] + bev[0] + xi[0];
                o.y = (h1 - mean) * rs * gv[1] + bev[1] + xi[1];
                o.z = (h2 - mean) * rs * gv[2] + bev[2] + xi[2];
                o.w = (h3 - mean) * rs * gv[3] + bev[3] + xi[3];
                ((float4*)(out + (size_t)grow * DD))[cg] = o;
            }
        }
    }
}

extern "C" void kernel_launch(void* const* d_in, const int* in_sizes, int n_in,
                              void* d_out, int out_size, void* d_ws, size_t ws_size,
                              hipStream_t stream) {
    const void* x = d_in[0];
    const int* ei = (const int*)d_in[1];
    const void* W1 = d_in[2];
    const void* b1 = d_in[3];
    const void* W2 = d_in[4];
    const void* b2 = d_in[5];
    const void* eta = d_in[6];
    const void* gamma = d_in[7];
    const void* beta = d_in[8];
    float* out = (float*)d_out;

    const size_t FLAGS_OFF = 0;
    const size_t PART_OFF = 64;
    const size_t Z_OFF = 256;
    const size_t ZB = (size_t)NN * DD * sizeof(float);   // 25,600,000
    const size_t XB_OFF = Z_OFF;                          // bf16 x copy
    const size_t ZBF_OFF = Z_OFF + (size_t)NN * DD * 2;   // bf16 z
    const size_t DEG_OFF = Z_OFF + ZB;
    const size_t DEGB = 200192;
    const size_t RS_OFF = DEG_OFF + DEGB;
    const size_t RSB = 200448;
    const size_t BS_OFF = RS_OFF + RSB;
    const size_t BSB = (size_t)NE * sizeof(u16);         // 1,600,000
    const size_t RK_OFF = BS_OFF + BSB;
    const size_t RKB = (size_t)NE * sizeof(u16);         // 1,600,000
    const size_t PCK_OFF = RK_OFF + RKB;
    const size_t PCKB = (size_t)NE * sizeof(u32);        // 3,200,000
    const size_t TOT = PCK_OFF + PCKB;                   // ~32.4 MB (ws = 256 MiB)

    if (ws_size < Z_OFF + ZB) return;
    int* flags = (int*)((char*)d_ws + FLAGS_OFF);
    u32* partials = (u32*)((char*)d_ws + PART_OFF);

    gin_detect<<<1, 64, 0, stream>>>((const u32*)x, (const u32*)ei, flags);

    if (ws_size >= TOT) {
        u32* xb = (u32*)((char*)d_ws + XB_OFF);
        u32* zb = (u32*)((char*)d_ws + ZBF_OFF);
        u32* deg = (u32*)((char*)d_ws + DEG_OFF);
        u32* row_start = (u32*)((char*)d_ws + RS_OFF);
        u16* bs = (u16*)((char*)d_ws + BS_OFF);
        u16* rank = (u16*)((char*)d_ws + RK_OFF);
        u32* pck = (u32*)((char*)d_ws + PCK_OFF);
        gin_tobf_zero<<<NB_TOBF + NB_ZERO, 256, 0, stream>>>(x, (uint4*)xb, deg, flags);
        gin_hist<<<(NE + 255) / 256, 256, 0, stream>>>(ei, deg, rank, pck, flags);
        gin_scan1<<<NSB, 1024, 0, stream>>>(deg, partials);
        gin_scan3<<<NSB, 1024, 0, stream>>>(deg, partials, row_start);
        gin_fill<<<(NE + 255) / 256, 256, 0, stream>>>(pck, row_start, rank, bs);
        gin_gather<<<(NN + 3) / 4, 256, 0, stream>>>(xb, bs, row_start, deg, eta, zb, flags);
        gin_mlp<0, 1><<<256, 512, 0, stream>>>(zb, xb, W1, b1, W2, b2, gamma, beta, out, flags);
        gin_mlp<1, 1><<<256, 512, 0, stream>>>(zb, xb, W1, b1, W2, b2, gamma, beta, out, flags);
    } else {
        float* z = (float*)((char*)d_ws + Z_OFF);
        gin_init<<<(NN * DD / 8 + 255) / 256, 256, 0, stream>>>(x, eta, z, flags);
        gin_scatter<<<NE / 4, 256, 0, stream>>>(x, ei, z, flags);
        gin_mlp<0, 0><<<256, 512, 0, stream>>>(z, x, W1, b1, W2, b2, gamma, beta, out, flags);
        gin_mlp<1, 0><<<256, 512, 0, stream>>>(z, x, W1, b1, W2, b2, gamma, beta, out, flags);
    }
}